// Round 1
// baseline (3885.200 us; speedup 1.0000x reference)
//
#include <hip/hip_runtime.h>
#include <hip/hip_bf16.h>
#include <math.h>

// Problem constants
#define T_LEN 2048
#define C_DIM 2048
#define NH 16
#define HD 128
#define RANK 64
#define W_LOCAL 512
#define QKV_LD 6144
#define SCALE 0.08838834764831845f    // 1/sqrt(128)
#define SCALE_G 0.17677669529663687f  // scale * 128/64
#define LOG1E4_OVER_64 0.14391156831212787f

// ---------------------------------------------------------------------------
// Generic fp32 GEMM:  C[m,n] = act( sum_k A[m*lda+k] * B[n*ldb+k] )
// A: (M,K) row-major stride lda;  B: (N,K) row-major stride ldb (i.e. B^T mul)
// BM=BN=128, BK=16, 256 threads, 8x8 per thread. M,N %128==0, K%16==0.
// ---------------------------------------------------------------------------
#define BM 128
#define BN 128
#define BK 16

__device__ __forceinline__ float gelu_exact(float v) {
    return 0.5f * v * (1.0f + erff(v * 0.70710678118654752f));
}

__global__ __launch_bounds__(256)
void gemm_nt(const float* __restrict__ A, const float* __restrict__ B,
             float* __restrict__ C, int M, int N, int K,
             int lda, int ldb, int ldc, int act) {
    __shared__ float As[BK][BM];
    __shared__ float Bs[BK][BN];
    const int tid = threadIdx.x;
    const int bm = blockIdx.y * BM;
    const int bn = blockIdx.x * BN;
    const int ty = tid >> 4;   // 0..15 (m)
    const int tx = tid & 15;   // 0..15 (n)

    float acc[8][8];
#pragma unroll
    for (int i = 0; i < 8; ++i)
#pragma unroll
        for (int j = 0; j < 8; ++j) acc[i][j] = 0.f;

    for (int k0 = 0; k0 < K; k0 += BK) {
        // load A tile: 128 rows x 16 k, as float4 along k
#pragma unroll
        for (int l = tid; l < (BM * BK) / 4; l += 256) {
            int row = l >> 2, c4 = (l & 3) << 2;
            float4 v = *(const float4*)(A + (size_t)(bm + row) * lda + k0 + c4);
            As[c4 + 0][row] = v.x; As[c4 + 1][row] = v.y;
            As[c4 + 2][row] = v.z; As[c4 + 3][row] = v.w;
        }
#pragma unroll
        for (int l = tid; l < (BN * BK) / 4; l += 256) {
            int row = l >> 2, c4 = (l & 3) << 2;
            float4 v = *(const float4*)(B + (size_t)(bn + row) * ldb + k0 + c4);
            Bs[c4 + 0][row] = v.x; Bs[c4 + 1][row] = v.y;
            Bs[c4 + 2][row] = v.z; Bs[c4 + 3][row] = v.w;
        }
        __syncthreads();
#pragma unroll
        for (int kk = 0; kk < BK; ++kk) {
            float a[8], b[8];
#pragma unroll
            for (int i = 0; i < 8; ++i) a[i] = As[kk][ty * 8 + i];
#pragma unroll
            for (int j = 0; j < 8; ++j) b[j] = Bs[kk][tx * 8 + j];
#pragma unroll
            for (int i = 0; i < 8; ++i)
#pragma unroll
                for (int j = 0; j < 8; ++j) acc[i][j] += a[i] * b[j];
        }
        __syncthreads();
    }
#pragma unroll
    for (int i = 0; i < 8; ++i) {
        size_t rowoff = (size_t)(bm + ty * 8 + i) * ldc + bn + tx * 8;
#pragma unroll
        for (int j = 0; j < 8; ++j) {
            float v = acc[i][j];
            if (act == 1) v = gelu_exact(v);
            C[rowoff + j] = v;
        }
    }
}

// ---------------------------------------------------------------------------
// RoPE in-place on q (cols 0..2047) and k (cols 2048..4095) of qkv.
// Mixed scheme: rotate is interleaved-pairs, tables are concat-style:
//   out[2i]   = x[2i]  *cos(t*invf[(2i)%64])   - x[2i+1]*sin(t*invf[(2i)%64])
//   out[2i+1] = x[2i+1]*cos(t*invf[(2i+1)%64]) + x[2i]  *sin(t*invf[(2i+1)%64])
// invf[j] = 10000^(-j/64)
// ---------------------------------------------------------------------------
__global__ void rope_kernel(float* __restrict__ qkv) {
    const int t = blockIdx.x;
    float* row = qkv + (size_t)t * QKV_LD;
    const float tf = (float)t;
    for (int p = threadIdx.x; p < 2048; p += blockDim.x) {
        int c = p * 2;              // even col, q if c<2048 else k; pair same head
        int d0 = c & 127;           // head-local dim (even)
        int j0 = d0 & 63;
        int j1 = j0 + 1;            // d0 even => (d0+1)&63 == j0+1
        float inv0 = expf(-(float)j0 * LOG1E4_OVER_64);
        float inv1 = expf(-(float)j1 * LOG1E4_OVER_64);
        float s0, c0, s1, c1;
        sincosf(tf * inv0, &s0, &c0);
        sincosf(tf * inv1, &s1, &c1);
        float x0 = row[c], x1 = row[c + 1];
        row[c]     = x0 * c0 - x1 * s0;
        row[c + 1] = x1 * c1 + x0 * s1;
    }
}

// ---------------------------------------------------------------------------
// Gate: gate[t] = (sigmoid(sum_i h_info[t,i]*w2[i]) > 0.75) ? 1 : 0
// one wave per token
// ---------------------------------------------------------------------------
__global__ void gate_kernel(const float* __restrict__ h_info,
                            const float* __restrict__ w2,
                            float* __restrict__ gate) {
    const int t = blockIdx.x;
    const int lane = threadIdx.x;  // 64
    float s = 0.f;
    for (int i = lane; i < 512; i += 64) s += h_info[(size_t)t * 512 + i] * w2[i];
#pragma unroll
    for (int off = 32; off > 0; off >>= 1) s += __shfl_down(s, off);
    if (lane == 0) {
        float sig = 1.f / (1.f + expf(-s));
        gate[t] = (sig > 0.75f) ? 1.f : 0.f;
    }
}

// ---------------------------------------------------------------------------
// k_r[h,s,r] = sum_d k[s, 2048+h*128+d] * pk[r,d];  same for v_r with pv.
// grid (T/4, H), 256 threads = 4 s-values x 64 r
// ---------------------------------------------------------------------------
__global__ void kvr_kernel(const float* __restrict__ qkv,
                           const float* __restrict__ pk,
                           const float* __restrict__ pv,
                           float* __restrict__ kr, float* __restrict__ vr) {
    const int h = blockIdx.y;
    const int s = blockIdx.x * 4 + (threadIdx.x >> 6);
    const int r = threadIdx.x & 63;
    const float* krow = qkv + (size_t)s * QKV_LD + 2048 + h * HD;
    const float* vrow = qkv + (size_t)s * QKV_LD + 4096 + h * HD;
    float ak = 0.f, av = 0.f;
#pragma unroll 4
    for (int d = 0; d < HD; ++d) {
        float pkd = pk[r * HD + d], pvd = pv[r * HD + d];
        ak += krow[d] * pkd;
        av += vrow[d] * pvd;
    }
    kr[((size_t)h * T_LEN + s) * RANK + r] = ak;
    vr[((size_t)h * T_LEN + s) * RANK + r] = av;
}

// ---------------------------------------------------------------------------
// Fused local + (gated) global attention; one block per (t,h), 512 threads.
// Writes ctx[t, h*128+d] into the q region of qkv (stride QKV_LD).
// ---------------------------------------------------------------------------
__device__ __forceinline__ float block_reduce_max512(float v, float* red, int tid) {
    red[tid] = v; __syncthreads();
    for (int s = 256; s > 0; s >>= 1) {
        if (tid < s) red[tid] = fmaxf(red[tid], red[tid + s]);
        __syncthreads();
    }
    float r = red[0]; __syncthreads();
    return r;
}
__device__ __forceinline__ float block_reduce_sum512(float v, float* red, int tid) {
    red[tid] = v; __syncthreads();
    for (int s = 256; s > 0; s >>= 1) {
        if (tid < s) red[tid] = red[tid] + red[tid + s];
        __syncthreads();
    }
    float r = red[0]; __syncthreads();
    return r;
}

__global__ __launch_bounds__(512)
void attn_kernel(float* __restrict__ qkv, const float* __restrict__ kr,
                 const float* __restrict__ vr, const float* __restrict__ pk,
                 const float* __restrict__ uo, const float* __restrict__ gate) {
    __shared__ float sq[128];
    __shared__ float ss[512];
    __shared__ float red[512];
    __shared__ float ctxl[128];
    __shared__ float qr[64];
    __shared__ float cgr[64];
    __shared__ float sg[2048];

    const int t = blockIdx.x, h = blockIdx.y;
    const int tid = threadIdx.x;

    const float* qrow = qkv + (size_t)t * QKV_LD + h * HD;
    if (tid < 128) sq[tid] = qrow[tid];
    __syncthreads();

    // ---- local attention over window [s_lo, t] ----
    const int s_lo = (t >= W_LOCAL - 1) ? t - (W_LOCAL - 1) : 0;
    const int n_s = t - s_lo + 1;
    float score = -INFINITY;
    if (tid < n_s) {
        const float* krow = qkv + (size_t)(s_lo + tid) * QKV_LD + 2048 + h * HD;
        float acc = 0.f;
#pragma unroll
        for (int d = 0; d < HD; d += 4) {
            float4 k4 = *(const float4*)(krow + d);
            acc += sq[d] * k4.x + sq[d + 1] * k4.y + sq[d + 2] * k4.z + sq[d + 3] * k4.w;
        }
        score = acc * SCALE;
    }
    float mx = block_reduce_max512(score, red, tid);
    float p = (tid < n_s) ? expf(score - mx) : 0.f;
    ss[tid] = p;
    float psum = block_reduce_sum512(p, red, tid);

    // ctx_local: d = tid&127, 4 s-partitions
    {
        const int d = tid & 127, part = tid >> 7;
        float partial = 0.f;
        for (int j = part; j < n_s; j += 4) {
            partial += ss[j] * qkv[(size_t)(s_lo + j) * QKV_LD + 4096 + h * HD + d];
        }
        red[tid] = partial;
        __syncthreads();
        if (tid < 128) {
            ctxl[tid] = (red[tid] + red[tid + 128] + red[tid + 256] + red[tid + 384]) / psum;
        }
        __syncthreads();
    }

    const bool g = gate[t] > 0.5f;   // block-uniform
    if (!g) {
        if (tid < 128) qkv[(size_t)t * QKV_LD + h * HD + tid] = ctxl[tid];
        return;
    }

    // ---- global low-rank attention (no mask) ----
    if (tid < 64) {
        float acc = 0.f;
#pragma unroll 4
        for (int d = 0; d < HD; ++d) acc += sq[d] * pk[tid * HD + d];
        qr[tid] = acc;
    }
    __syncthreads();

    const float* krh = kr + (size_t)h * T_LEN * RANK;
    const float* vrh = vr + (size_t)h * T_LEN * RANK;
    float lmax = -INFINITY;
    for (int s = tid; s < T_LEN; s += 512) {
        const float* krr = krh + (size_t)s * RANK;
        float acc = 0.f;
#pragma unroll
        for (int r = 0; r < RANK; r += 4) {
            float4 k4 = *(const float4*)(krr + r);
            acc += qr[r] * k4.x + qr[r + 1] * k4.y + qr[r + 2] * k4.z + qr[r + 3] * k4.w;
        }
        float sc = acc * SCALE_G;
        sg[s] = sc;
        lmax = fmaxf(lmax, sc);
    }
    float gmx = block_reduce_max512(lmax, red, tid);
    float lsum = 0.f;
    for (int s = tid; s < T_LEN; s += 512) {
        float pp = expf(sg[s] - gmx);
        sg[s] = pp;
        lsum += pp;
    }
    float gsum = block_reduce_sum512(lsum, red, tid);

    // ctx_g_r: r = tid&63, 8 s-partitions
    {
        const int r = tid & 63, part = tid >> 6;
        float pacc = 0.f;
        for (int s = part; s < T_LEN; s += 8) pacc += sg[s] * vrh[(size_t)s * RANK + r];
        red[tid] = pacc;
        __syncthreads();
        if (tid < 64) {
            float c = 0.f;
#pragma unroll
            for (int pp = 0; pp < 8; ++pp) c += red[pp * 64 + tid];
            cgr[tid] = c / gsum;
        }
        __syncthreads();
    }

    if (tid < 128) {
        float cg = 0.f;
#pragma unroll
        for (int r = 0; r < RANK; ++r) cg += cgr[r] * uo[tid * RANK + r];
        qkv[(size_t)t * QKV_LD + h * HD + tid] = ctxl[tid] + cg;
    }
}

// ---------------------------------------------------------------------------
extern "C" void kernel_launch(void* const* d_in, const int* in_sizes, int n_in,
                              void* d_out, int out_size, void* d_ws, size_t ws_size,
                              hipStream_t stream) {
    const float* x     = (const float*)d_in[0];
    const float* w_qkv = (const float*)d_in[1];
    const float* w_o   = (const float*)d_in[2];
    const float* pk    = (const float*)d_in[3];
    const float* pv    = (const float*)d_in[4];
    const float* uo    = (const float*)d_in[5];
    const float* w1    = (const float*)d_in[6];
    const float* w2    = (const float*)d_in[7];
    float* out = (float*)d_out;

    float* ws = (float*)d_ws;
    float* qkv   = ws;                      // 2048*6144 = 12,582,912
    float* hinfo = qkv + (size_t)12582912;  // 2048*512  =  1,048,576
    float* gatep = hinfo + (size_t)1048576; // 2048
    float* krp   = gatep + (size_t)2048;    // 16*2048*64 = 2,097,152
    float* vrp   = krp + (size_t)2097152;   // 2,097,152
    // total ~71.3 MB; ctx overlaps q region of qkv (stride 6144)

    // 1) qkv = x @ w_qkv^T
    gemm_nt<<<dim3(6144 / BN, 2048 / BM), 256, 0, stream>>>(
        x, w_qkv, qkv, 2048, 6144, 2048, 2048, 2048, QKV_LD, 0);
    // 2) h_info = gelu(x @ w1^T)
    gemm_nt<<<dim3(512 / BN, 2048 / BM), 256, 0, stream>>>(
        x, w1, hinfo, 2048, 512, 2048, 2048, 2048, 512, 1);
    // 3) RoPE in place on q,k
    rope_kernel<<<T_LEN, 256, 0, stream>>>(qkv);
    // 4) gate
    gate_kernel<<<T_LEN, 64, 0, stream>>>(hinfo, w2, gatep);
    // 5) k_r, v_r
    kvr_kernel<<<dim3(T_LEN / 4, NH), 256, 0, stream>>>(qkv, pk, pv, krp, vrp);
    // 6) fused attention -> ctx (over q region)
    attn_kernel<<<dim3(T_LEN, NH), 512, 0, stream>>>(qkv, krp, vrp, pk, uo, gatep);
    // 7) out = ctx @ w_o^T
    gemm_nt<<<dim3(2048 / BN, 2048 / BM), 256, 0, stream>>>(
        qkv, w_o, out, 2048, 2048, 2048, QKV_LD, 2048, 2048, 0);
}

// Round 2
// 1869.465 us; speedup vs baseline: 2.0782x; 2.0782x over previous
//
#include <hip/hip_runtime.h>
#include <hip/hip_bf16.h>
#include <math.h>

// Problem constants
#define T_LEN 2048
#define C_DIM 2048
#define NH 16
#define HD 128
#define RANK 64
#define W_LOCAL 512
#define QKV_LD 6144
#define SCALE 0.08838834764831845f    // 1/sqrt(128)
#define SCALE_G 0.17677669529663687f  // scale * 128/64
#define LOG1E4_OVER_64 0.14391156831212787f

typedef __bf16 bf16_t;
typedef __bf16 bf16x8 __attribute__((ext_vector_type(8)));
typedef __bf16 bf16x4 __attribute__((ext_vector_type(4)));
typedef float f32x4 __attribute__((ext_vector_type(4)));

// ---------------------------------------------------------------------------
// Generic fp32 GEMM:  C[m,n] = act( sum_k A[m*lda+k] * B[n*ldb+k] )
// ---------------------------------------------------------------------------
#define BM 128
#define BN 128
#define BK 16

__device__ __forceinline__ float gelu_exact(float v) {
    return 0.5f * v * (1.0f + erff(v * 0.70710678118654752f));
}

__global__ __launch_bounds__(256)
void gemm_nt(const float* __restrict__ A, const float* __restrict__ B,
             float* __restrict__ C, int M, int N, int K,
             int lda, int ldb, int ldc, int act) {
    __shared__ float As[BK][BM];
    __shared__ float Bs[BK][BN];
    const int tid = threadIdx.x;
    const int bm = blockIdx.y * BM;
    const int bn = blockIdx.x * BN;
    const int ty = tid >> 4;
    const int tx = tid & 15;

    float acc[8][8];
#pragma unroll
    for (int i = 0; i < 8; ++i)
#pragma unroll
        for (int j = 0; j < 8; ++j) acc[i][j] = 0.f;

    for (int k0 = 0; k0 < K; k0 += BK) {
#pragma unroll
        for (int l = tid; l < (BM * BK) / 4; l += 256) {
            int row = l >> 2, c4 = (l & 3) << 2;
            float4 v = *(const float4*)(A + (size_t)(bm + row) * lda + k0 + c4);
            As[c4 + 0][row] = v.x; As[c4 + 1][row] = v.y;
            As[c4 + 2][row] = v.z; As[c4 + 3][row] = v.w;
        }
#pragma unroll
        for (int l = tid; l < (BN * BK) / 4; l += 256) {
            int row = l >> 2, c4 = (l & 3) << 2;
            float4 v = *(const float4*)(B + (size_t)(bn + row) * ldb + k0 + c4);
            Bs[c4 + 0][row] = v.x; Bs[c4 + 1][row] = v.y;
            Bs[c4 + 2][row] = v.z; Bs[c4 + 3][row] = v.w;
        }
        __syncthreads();
#pragma unroll
        for (int kk = 0; kk < BK; ++kk) {
            float a[8], b[8];
#pragma unroll
            for (int i = 0; i < 8; ++i) a[i] = As[kk][ty * 8 + i];
#pragma unroll
            for (int j = 0; j < 8; ++j) b[j] = Bs[kk][tx * 8 + j];
#pragma unroll
            for (int i = 0; i < 8; ++i)
#pragma unroll
                for (int j = 0; j < 8; ++j) acc[i][j] += a[i] * b[j];
        }
        __syncthreads();
    }
#pragma unroll
    for (int i = 0; i < 8; ++i) {
        size_t rowoff = (size_t)(bm + ty * 8 + i) * ldc + bn + tx * 8;
#pragma unroll
        for (int j = 0; j < 8; ++j) {
            float v = acc[i][j];
            if (act == 1) v = gelu_exact(v);
            C[rowoff + j] = v;
        }
    }
}

// ---------------------------------------------------------------------------
// RoPE in-place on q and k of qkv (mixed interleaved-rotate / concat-tables)
// ---------------------------------------------------------------------------
__global__ void rope_kernel(float* __restrict__ qkv) {
    const int t = blockIdx.x;
    float* row = qkv + (size_t)t * QKV_LD;
    const float tf = (float)t;
    for (int p = threadIdx.x; p < 2048; p += blockDim.x) {
        int c = p * 2;
        int d0 = c & 127;
        int j0 = d0 & 63;
        int j1 = j0 + 1;
        float inv0 = expf(-(float)j0 * LOG1E4_OVER_64);
        float inv1 = expf(-(float)j1 * LOG1E4_OVER_64);
        float s0, c0, s1, c1;
        sincosf(tf * inv0, &s0, &c0);
        sincosf(tf * inv1, &s1, &c1);
        float x0 = row[c], x1 = row[c + 1];
        row[c]     = x0 * c0 - x1 * s0;
        row[c + 1] = x1 * c1 + x0 * s1;
    }
}

// ---------------------------------------------------------------------------
// Gate: gate[t] = (sigmoid(h_info[t,:] @ w2) > 0.75)
// ---------------------------------------------------------------------------
__global__ void gate_kernel(const float* __restrict__ h_info,
                            const float* __restrict__ w2,
                            float* __restrict__ gate) {
    const int t = blockIdx.x;
    const int lane = threadIdx.x;
    float s = 0.f;
    for (int i = lane; i < 512; i += 64) s += h_info[(size_t)t * 512 + i] * w2[i];
#pragma unroll
    for (int off = 32; off > 0; off >>= 1) s += __shfl_down(s, off);
    if (lane == 0) {
        float sig = 1.f / (1.f + expf(-s));
        gate[t] = (sig > 0.75f) ? 1.f : 0.f;
    }
}

// ---------------------------------------------------------------------------
// k_r, v_r (fp32) and q_r (bf16, into dead h_info buffer) per (h,s,r)
// Must run BEFORE local_attn overwrites the q region with ctx.
// ---------------------------------------------------------------------------
__global__ void kvr_kernel(const float* __restrict__ qkv,
                           const float* __restrict__ pk,
                           const float* __restrict__ pv,
                           float* __restrict__ kr, float* __restrict__ vr,
                           bf16_t* __restrict__ qr) {
    const int h = blockIdx.y;
    const int s = blockIdx.x * 4 + (threadIdx.x >> 6);
    const int r = threadIdx.x & 63;
    const float* qrow = qkv + (size_t)s * QKV_LD + h * HD;
    const float* krow = qrow + 2048;
    const float* vrow = qrow + 4096;
    float ak = 0.f, av = 0.f, aq = 0.f;
#pragma unroll 4
    for (int d = 0; d < HD; ++d) {
        float pkd = pk[r * HD + d], pvd = pv[r * HD + d];
        ak += krow[d] * pkd;
        av += vrow[d] * pvd;
        aq += qrow[d] * pkd;
    }
    size_t idx = ((size_t)h * T_LEN + s) * RANK + r;
    kr[idx] = ak;
    vr[idx] = av;
    qr[idx] = (bf16_t)aq;
}

// ---------------------------------------------------------------------------
// MFMA bf16 flash local attention.
// Block = (64 q-rows, 1 head), 256 threads (4 waves x 16 q-rows).
// K-tiles of 64 covering [t0-512, t0+63]; online softmax; writes ctx into
// the q region of qkv (only this block reads those q rows; reads precede).
// MFMA 16x16x32 layouts (m89/m91-verified):
//   A: lane holds A[m=lane&15][k=quad*8+j];  B: lane holds B[k=quad*8+j][n=lane&15]
//   C/D: lane holds D[row=quad*4+reg][col=lane&15]
// ---------------------------------------------------------------------------
#define QTI 64
#define KTI 64
#define QS_LD 136   // 128 + 8 pad (keeps 16B alignment, breaks bank stride)
#define VT_LD 68    // V^T rows padded to 68 (8B-aligned rows; b64 frag reads)
#define PS_LD 72

__global__ __launch_bounds__(256)
void local_attn_kernel(float* __restrict__ qkv) {
    __shared__ bf16_t Qs[QTI * QS_LD];
    __shared__ bf16_t Ks[KTI * QS_LD];
    __shared__ bf16_t Vt[HD * VT_LD];
    __shared__ bf16_t Ps[4][16 * PS_LD];

    const int h = blockIdx.y;
    const int t0 = blockIdx.x * QTI;
    const int tid = threadIdx.x;
    const int wave = tid >> 6, lane = tid & 63;
    const int quad = lane >> 4, l16 = lane & 15;

    // stage Q (scale folded in) -> bf16 LDS
#pragma unroll
    for (int i = 0; i < 8; ++i) {
        int gid = i * 256 + tid;
        int row = gid >> 5, c4 = (gid & 31) << 2;
        const float4 v = *(const float4*)(qkv + (size_t)(t0 + row) * QKV_LD + h * HD + c4);
        bf16x4 p;
        p[0] = (bf16_t)(v.x * SCALE); p[1] = (bf16_t)(v.y * SCALE);
        p[2] = (bf16_t)(v.z * SCALE); p[3] = (bf16_t)(v.w * SCALE);
        *(bf16x4*)&Qs[row * QS_LD + c4] = p;
    }

    f32x4 o[8];
#pragma unroll
    for (int d8 = 0; d8 < 8; ++d8) o[d8] = (f32x4){0.f, 0.f, 0.f, 0.f};
    float m_i[4] = {-1e30f, -1e30f, -1e30f, -1e30f};
    float l_i[4] = {0.f, 0.f, 0.f, 0.f};

    __syncthreads();

    for (int kt = 0; kt < 9; ++kt) {
        const int sbase = t0 - 512 + kt * KTI;
        if (sbase < 0) continue;           // uniform per block
        __syncthreads();                   // previous tile's compute done
        // stage K (row-major) and V (transposed) -> bf16 LDS
#pragma unroll
        for (int i = 0; i < 8; ++i) {
            int gid = i * 256 + tid;
            int row = gid >> 5, c4 = (gid & 31) << 2;
            const float* base = qkv + (size_t)(sbase + row) * QKV_LD + h * HD + c4;
            const float4 kv = *(const float4*)(base + 2048);
            bf16x4 pk4;
            pk4[0] = (bf16_t)kv.x; pk4[1] = (bf16_t)kv.y;
            pk4[2] = (bf16_t)kv.z; pk4[3] = (bf16_t)kv.w;
            *(bf16x4*)&Ks[row * QS_LD + c4] = pk4;
            const float4 vv = *(const float4*)(base + 4096);
            Vt[(c4 + 0) * VT_LD + row] = (bf16_t)vv.x;
            Vt[(c4 + 1) * VT_LD + row] = (bf16_t)vv.y;
            Vt[(c4 + 2) * VT_LD + row] = (bf16_t)vv.z;
            Vt[(c4 + 3) * VT_LD + row] = (bf16_t)vv.w;
        }
        __syncthreads();

        // S = Q K^T  (wave's 16 q-rows x 64 k-cols)
        f32x4 sacc[4];
#pragma unroll
        for (int nt = 0; nt < 4; ++nt) sacc[nt] = (f32x4){0.f, 0.f, 0.f, 0.f};
#pragma unroll
        for (int ks = 0; ks < 4; ++ks) {
            bf16x8 a = *(const bf16x8*)&Qs[(wave * 16 + l16) * QS_LD + ks * 32 + quad * 8];
#pragma unroll
            for (int nt = 0; nt < 4; ++nt) {
                bf16x8 b = *(const bf16x8*)&Ks[(nt * 16 + l16) * QS_LD + ks * 32 + quad * 8];
                sacc[nt] = __builtin_amdgcn_mfma_f32_16x16x32_bf16(a, b, sacc[nt], 0, 0, 0);
            }
        }

        // mask: valid iff t-511 <= s <= t  (sentinel -1e30; self-correcting)
#pragma unroll
        for (int nt = 0; nt < 4; ++nt) {
            int s_g = sbase + nt * 16 + l16;
#pragma unroll
            for (int r = 0; r < 4; ++r) {
                int t_g = t0 + wave * 16 + quad * 4 + r;
                bool valid = (s_g <= t_g) && (s_g + W_LOCAL > t_g);
                if (!valid) sacc[nt][r] = -1e30f;
            }
        }

        // online softmax per row (rows live in quad*4+r; cols across l16)
#pragma unroll
        for (int r = 0; r < 4; ++r) {
            float mx = fmaxf(fmaxf(sacc[0][r], sacc[1][r]), fmaxf(sacc[2][r], sacc[3][r]));
            mx = fmaxf(mx, __shfl_xor(mx, 1));
            mx = fmaxf(mx, __shfl_xor(mx, 2));
            mx = fmaxf(mx, __shfl_xor(mx, 4));
            mx = fmaxf(mx, __shfl_xor(mx, 8));
            float mnew = fmaxf(m_i[r], mx);
            float alpha = __expf(m_i[r] - mnew);
            m_i[r] = mnew;
            float rs = 0.f;
#pragma unroll
            for (int nt = 0; nt < 4; ++nt) {
                float p = __expf(sacc[nt][r] - mnew);
                sacc[nt][r] = p;
                rs += p;
            }
            rs += __shfl_xor(rs, 1);
            rs += __shfl_xor(rs, 2);
            rs += __shfl_xor(rs, 4);
            rs += __shfl_xor(rs, 8);
            l_i[r] = l_i[r] * alpha + rs;
#pragma unroll
            for (int d8 = 0; d8 < 8; ++d8) o[d8][r] *= alpha;
        }

        // P: C-layout -> A-layout via wave-private LDS (bf16)
#pragma unroll
        for (int r = 0; r < 4; ++r)
#pragma unroll
            for (int nt = 0; nt < 4; ++nt)
                Ps[wave][(quad * 4 + r) * PS_LD + nt * 16 + l16] = (bf16_t)sacc[nt][r];

        // O += P V
#pragma unroll
        for (int ks2 = 0; ks2 < 2; ++ks2) {
            bf16x8 a = *(const bf16x8*)&Ps[wave][l16 * PS_LD + ks2 * 32 + quad * 8];
#pragma unroll
            for (int d8 = 0; d8 < 8; ++d8) {
                const bf16_t* vb = &Vt[(d8 * 16 + l16) * VT_LD + ks2 * 32 + quad * 8];
                bf16x4 b0 = *(const bf16x4*)vb;
                bf16x4 b1 = *(const bf16x4*)(vb + 4);
                bf16x8 b;
                b[0] = b0[0]; b[1] = b0[1]; b[2] = b0[2]; b[3] = b0[3];
                b[4] = b1[0]; b[5] = b1[1]; b[6] = b1[2]; b[7] = b1[3];
                o[d8] = __builtin_amdgcn_mfma_f32_16x16x32_bf16(a, b, o[d8], 0, 0, 0);
            }
        }
    }

    // normalize and write ctx into q region
#pragma unroll
    for (int r = 0; r < 4; ++r) {
        float inv = 1.0f / l_i[r];
        size_t rowoff = (size_t)(t0 + wave * 16 + quad * 4 + r) * QKV_LD + h * HD;
#pragma unroll
        for (int d8 = 0; d8 < 8; ++d8)
            qkv[rowoff + d8 * 16 + l16] = o[d8][r] * inv;
    }
}

// ---------------------------------------------------------------------------
// Gated global low-rank branch; early-exits when gate==0 (expected common).
// Adds into ctx (q region). Runs after local_attn.
// ---------------------------------------------------------------------------
__device__ __forceinline__ float block_reduce_max512(float v, float* red, int tid) {
    red[tid] = v; __syncthreads();
    for (int s = 256; s > 0; s >>= 1) {
        if (tid < s) red[tid] = fmaxf(red[tid], red[tid + s]);
        __syncthreads();
    }
    float r = red[0]; __syncthreads();
    return r;
}
__device__ __forceinline__ float block_reduce_sum512(float v, float* red, int tid) {
    red[tid] = v; __syncthreads();
    for (int s = 256; s > 0; s >>= 1) {
        if (tid < s) red[tid] = red[tid] + red[tid + s];
        __syncthreads();
    }
    float r = red[0]; __syncthreads();
    return r;
}

__global__ __launch_bounds__(512)
void global_attn_kernel(float* __restrict__ qkv, const float* __restrict__ kr,
                        const float* __restrict__ vr, const bf16_t* __restrict__ qr,
                        const float* __restrict__ uo, const float* __restrict__ gate) {
    const int t = blockIdx.x, h = blockIdx.y;
    if (gate[t] <= 0.5f) return;

    __shared__ float qrs[64];
    __shared__ float red[512];
    __shared__ float cgr[64];
    __shared__ float sg[2048];
    const int tid = threadIdx.x;

    if (tid < 64) qrs[tid] = (float)qr[((size_t)h * T_LEN + t) * RANK + tid];
    __syncthreads();

    const float* krh = kr + (size_t)h * T_LEN * RANK;
    const float* vrh = vr + (size_t)h * T_LEN * RANK;
    float lmax = -INFINITY;
    for (int s = tid; s < T_LEN; s += 512) {
        const float* krr = krh + (size_t)s * RANK;
        float acc = 0.f;
#pragma unroll
        for (int r = 0; r < RANK; r += 4) {
            float4 k4 = *(const float4*)(krr + r);
            acc += qrs[r] * k4.x + qrs[r + 1] * k4.y + qrs[r + 2] * k4.z + qrs[r + 3] * k4.w;
        }
        float sc = acc * SCALE_G;
        sg[s] = sc;
        lmax = fmaxf(lmax, sc);
    }
    float gmx = block_reduce_max512(lmax, red, tid);
    float lsum = 0.f;
    for (int s = tid; s < T_LEN; s += 512) {
        float pp = expf(sg[s] - gmx);
        sg[s] = pp;
        lsum += pp;
    }
    float gsum = block_reduce_sum512(lsum, red, tid);

    {
        const int r = tid & 63, part = tid >> 6;
        float pacc = 0.f;
        for (int s = part; s < T_LEN; s += 8) pacc += sg[s] * vrh[(size_t)s * RANK + r];
        red[tid] = pacc;
        __syncthreads();
        if (tid < 64) {
            float c = 0.f;
#pragma unroll
            for (int pp = 0; pp < 8; ++pp) c += red[pp * 64 + tid];
            cgr[tid] = c / gsum;
        }
        __syncthreads();
    }

    if (tid < 128) {
        float cg = 0.f;
#pragma unroll
        for (int r = 0; r < RANK; ++r) cg += cgr[r] * uo[tid * RANK + r];
        qkv[(size_t)t * QKV_LD + h * HD + tid] += cg;
    }
}

// ---------------------------------------------------------------------------
extern "C" void kernel_launch(void* const* d_in, const int* in_sizes, int n_in,
                              void* d_out, int out_size, void* d_ws, size_t ws_size,
                              hipStream_t stream) {
    const float* x     = (const float*)d_in[0];
    const float* w_qkv = (const float*)d_in[1];
    const float* w_o   = (const float*)d_in[2];
    const float* pk    = (const float*)d_in[3];
    const float* pv    = (const float*)d_in[4];
    const float* uo    = (const float*)d_in[5];
    const float* w1    = (const float*)d_in[6];
    const float* w2    = (const float*)d_in[7];
    float* out = (float*)d_out;

    float* ws = (float*)d_ws;
    float* qkv   = ws;                      // 2048*6144 fp32
    float* hinfo = qkv + (size_t)12582912;  // 2048*512 fp32 (reused as qr bf16)
    float* gatep = hinfo + (size_t)1048576; // 2048
    float* krp   = gatep + (size_t)2048;    // 16*2048*64
    float* vrp   = krp + (size_t)2097152;
    bf16_t* qrp  = (bf16_t*)hinfo;          // 16*2048*64 bf16 == 4 MB (exact fit)

    // 1) qkv = x @ w_qkv^T
    gemm_nt<<<dim3(6144 / BN, 2048 / BM), 256, 0, stream>>>(
        x, w_qkv, qkv, 2048, 6144, 2048, 2048, 2048, QKV_LD, 0);
    // 2) h_info = gelu(x @ w1^T)
    gemm_nt<<<dim3(512 / BN, 2048 / BM), 256, 0, stream>>>(
        x, w1, hinfo, 2048, 512, 2048, 2048, 2048, 512, 1);
    // 3) RoPE in place
    rope_kernel<<<T_LEN, 256, 0, stream>>>(qkv);
    // 4) gate (reads hinfo before kvr overwrites it with qr)
    gate_kernel<<<T_LEN, 64, 0, stream>>>(hinfo, w2, gatep);
    // 5) k_r, v_r, q_r
    kvr_kernel<<<dim3(T_LEN / 4, NH), 256, 0, stream>>>(qkv, pk, pv, krp, vrp, qrp);
    // 6) MFMA flash local attention -> ctx (over q region)
    local_attn_kernel<<<dim3(T_LEN / QTI, NH), 256, 0, stream>>>(qkv);
    // 7) gated global branch (adds into ctx)
    global_attn_kernel<<<dim3(T_LEN, NH), 512, 0, stream>>>(qkv, krp, vrp, qrp, uo, gatep);
    // 8) out = ctx @ w_o^T
    gemm_nt<<<dim3(2048 / BN, 2048 / BM), 256, 0, stream>>>(
        qkv, w_o, out, 2048, 2048, 2048, QKV_LD, 2048, 2048, 0);
}

// Round 3
// 1023.844 us; speedup vs baseline: 3.7947x; 1.8259x over previous
//
#include <hip/hip_runtime.h>
#include <hip/hip_bf16.h>
#include <math.h>

// Problem constants
#define T_LEN 2048
#define C_DIM 2048
#define NH 16
#define HD 128
#define RANK 64
#define W_LOCAL 512
#define QKV_LD 6144
#define SCALE 0.08838834764831845f    // 1/sqrt(128)
#define SCALE_G 0.17677669529663687f  // scale * 128/64
#define LOG1E4_OVER_64 0.14391156831212787f

typedef __bf16 bf16_t;
typedef __bf16 bf16x8 __attribute__((ext_vector_type(8)));
typedef __bf16 bf16x4 __attribute__((ext_vector_type(4)));
typedef float f32x4 __attribute__((ext_vector_type(4)));

// ---------------------------------------------------------------------------
// async 16B global -> LDS (gfx950). LDS dst must be wave-uniform base +
// lane*16; our lane->lds mapping satisfies this exactly.
// ---------------------------------------------------------------------------
__device__ __forceinline__ void async_copy16(const bf16_t* g, bf16_t* l) {
    __builtin_amdgcn_global_load_lds(
        (const __attribute__((address_space(1))) unsigned int*)g,
        (__attribute__((address_space(3))) unsigned int*)l, 16, 0, 0);
}

// ---------------------------------------------------------------------------
// fp32 -> bf16 conversion, 8 elems/thread. cols must be %8, ld_in arbitrary.
// ---------------------------------------------------------------------------
__global__ __launch_bounds__(256)
void conv_f32_bf16(const float* __restrict__ in, bf16_t* __restrict__ out,
                   int ld_in, int cols, int rows) {
    int per_row = cols >> 3;
    int idx = blockIdx.x * 256 + threadIdx.x;
    if (idx >= rows * per_row) return;
    int row = idx / per_row, c = (idx - row * per_row) << 3;
    const float* p = in + (size_t)row * ld_in + c;
    float4 v0 = *(const float4*)p;
    float4 v1 = *(const float4*)(p + 4);
    bf16x8 o;
    o[0] = (bf16_t)v0.x; o[1] = (bf16_t)v0.y; o[2] = (bf16_t)v0.z; o[3] = (bf16_t)v0.w;
    o[4] = (bf16_t)v1.x; o[5] = (bf16_t)v1.y; o[6] = (bf16_t)v1.z; o[7] = (bf16_t)v1.w;
    *(bf16x8*)(out + (size_t)row * cols + c) = o;
}

// ---------------------------------------------------------------------------
// bf16 MFMA GEMM (m97 recipe): C[m,n] = sum_k A[m,k]*B[n,k], fp32 out.
// 128x128 tile, BK=32, 256 thr = 4 waves, each wave 64x64 (4x4 MFMA tiles).
// M,N %128==0, K%32==0. A ld=lda bf16, B ld=ldb bf16, C ld=ldc fp32.
// ---------------------------------------------------------------------------
#define GBK 32

__global__ __launch_bounds__(256)
void gemm_bf16_nt(const bf16_t* __restrict__ A, const bf16_t* __restrict__ B,
                  float* __restrict__ C, int K, int lda, int ldb, int ldc) {
    __shared__ bf16_t As[128 * GBK];
    __shared__ bf16_t Bs[128 * GBK];
    const int tid = threadIdx.x;
    const int wave = tid >> 6, lane = tid & 63;
    const int quad = lane >> 4, l16 = lane & 15;
    const int bm = blockIdx.y * 128, bn = blockIdx.x * 128;
    const int wm = (wave >> 1) * 64, wn = (wave & 1) * 64;
    const int lrow = lane >> 2;          // 0..15
    const int lkb = (lane & 3) * 8;      // k-elem offset (16B)

    f32x4 acc[4][4];
#pragma unroll
    for (int i = 0; i < 4; ++i)
#pragma unroll
        for (int j = 0; j < 4; ++j) acc[i][j] = (f32x4){0.f, 0.f, 0.f, 0.f};

    const bf16_t* gA = A + (size_t)(bm + wave * 16 + lrow) * lda + lkb;
    const bf16_t* gB = B + (size_t)(bn + wave * 16 + lrow) * ldb + lkb;
    bf16_t* lA = &As[(wave * 16 + lrow) * GBK + lkb];  // == wavebase + lane*16B
    bf16_t* lB = &Bs[(wave * 16 + lrow) * GBK + lkb];

    for (int k0 = 0; k0 < K; k0 += GBK) {
        __syncthreads();
        async_copy16(gA + k0, lA);
        async_copy16(gA + (size_t)64 * lda + k0, lA + 64 * GBK);
        async_copy16(gB + k0, lB);
        async_copy16(gB + (size_t)64 * ldb + k0, lB + 64 * GBK);
        __syncthreads();

        bf16x8 a[4], b[4];
#pragma unroll
        for (int mt = 0; mt < 4; ++mt)
            a[mt] = *(const bf16x8*)&As[(wm + mt * 16 + l16) * GBK + quad * 8];
#pragma unroll
        for (int nt = 0; nt < 4; ++nt)
            b[nt] = *(const bf16x8*)&Bs[(wn + nt * 16 + l16) * GBK + quad * 8];
#pragma unroll
        for (int mt = 0; mt < 4; ++mt)
#pragma unroll
            for (int nt = 0; nt < 4; ++nt)
                acc[mt][nt] = __builtin_amdgcn_mfma_f32_16x16x32_bf16(a[mt], b[nt], acc[mt][nt], 0, 0, 0);
    }

#pragma unroll
    for (int mt = 0; mt < 4; ++mt)
#pragma unroll
        for (int r = 0; r < 4; ++r) {
            int row = bm + wm + mt * 16 + quad * 4 + r;
            float* crow = C + (size_t)row * ldc + bn + wn;
#pragma unroll
            for (int nt = 0; nt < 4; ++nt)
                crow[nt * 16 + l16] = acc[mt][nt][r];
        }
}

// ---------------------------------------------------------------------------
// fp32 GEMM (kept for the gate-critical info MLP): C = act(A @ B^T)
// ---------------------------------------------------------------------------
#define BM 128
#define BN 128
#define BK 16

__device__ __forceinline__ float gelu_exact(float v) {
    return 0.5f * v * (1.0f + erff(v * 0.70710678118654752f));
}

__global__ __launch_bounds__(256)
void gemm_nt(const float* __restrict__ A, const float* __restrict__ B,
             float* __restrict__ C, int M, int N, int K,
             int lda, int ldb, int ldc, int act) {
    __shared__ float As[BK][BM];
    __shared__ float Bs[BK][BN];
    const int tid = threadIdx.x;
    const int bm = blockIdx.y * BM;
    const int bn = blockIdx.x * BN;
    const int ty = tid >> 4;
    const int tx = tid & 15;

    float acc[8][8];
#pragma unroll
    for (int i = 0; i < 8; ++i)
#pragma unroll
        for (int j = 0; j < 8; ++j) acc[i][j] = 0.f;

    for (int k0 = 0; k0 < K; k0 += BK) {
#pragma unroll
        for (int l = tid; l < (BM * BK) / 4; l += 256) {
            int row = l >> 2, c4 = (l & 3) << 2;
            float4 v = *(const float4*)(A + (size_t)(bm + row) * lda + k0 + c4);
            As[c4 + 0][row] = v.x; As[c4 + 1][row] = v.y;
            As[c4 + 2][row] = v.z; As[c4 + 3][row] = v.w;
        }
#pragma unroll
        for (int l = tid; l < (BN * BK) / 4; l += 256) {
            int row = l >> 2, c4 = (l & 3) << 2;
            float4 v = *(const float4*)(B + (size_t)(bn + row) * ldb + k0 + c4);
            Bs[c4 + 0][row] = v.x; Bs[c4 + 1][row] = v.y;
            Bs[c4 + 2][row] = v.z; Bs[c4 + 3][row] = v.w;
        }
        __syncthreads();
#pragma unroll
        for (int kk = 0; kk < BK; ++kk) {
            float a[8], b[8];
#pragma unroll
            for (int i = 0; i < 8; ++i) a[i] = As[kk][ty * 8 + i];
#pragma unroll
            for (int j = 0; j < 8; ++j) b[j] = Bs[kk][tx * 8 + j];
#pragma unroll
            for (int i = 0; i < 8; ++i)
#pragma unroll
                for (int j = 0; j < 8; ++j) acc[i][j] += a[i] * b[j];
        }
        __syncthreads();
    }
#pragma unroll
    for (int i = 0; i < 8; ++i) {
        size_t rowoff = (size_t)(bm + ty * 8 + i) * ldc + bn + tx * 8;
#pragma unroll
        for (int j = 0; j < 8; ++j) {
            float v = acc[i][j];
            if (act == 1) v = gelu_exact(v);
            C[rowoff + j] = v;
        }
    }
}

// ---------------------------------------------------------------------------
// RoPE in-place (mixed interleaved-rotate / concat-tables)
// ---------------------------------------------------------------------------
__global__ void rope_kernel(float* __restrict__ qkv) {
    const int t = blockIdx.x;
    float* row = qkv + (size_t)t * QKV_LD;
    const float tf = (float)t;
    for (int p = threadIdx.x; p < 2048; p += blockDim.x) {
        int c = p * 2;
        int d0 = c & 127;
        int j0 = d0 & 63;
        int j1 = j0 + 1;
        float inv0 = expf(-(float)j0 * LOG1E4_OVER_64);
        float inv1 = expf(-(float)j1 * LOG1E4_OVER_64);
        float s0, c0, s1, c1;
        sincosf(tf * inv0, &s0, &c0);
        sincosf(tf * inv1, &s1, &c1);
        float x0 = row[c], x1 = row[c + 1];
        row[c]     = x0 * c0 - x1 * s0;
        row[c + 1] = x1 * c1 + x0 * s1;
    }
}

// ---------------------------------------------------------------------------
// Gate (fp32 path, exact)
// ---------------------------------------------------------------------------
__global__ void gate_kernel(const float* __restrict__ h_info,
                            const float* __restrict__ w2,
                            float* __restrict__ gate) {
    const int t = blockIdx.x;
    const int lane = threadIdx.x;
    float s = 0.f;
    for (int i = lane; i < 512; i += 64) s += h_info[(size_t)t * 512 + i] * w2[i];
#pragma unroll
    for (int off = 32; off > 0; off >>= 1) s += __shfl_down(s, off);
    if (lane == 0) {
        float sig = 1.f / (1.f + expf(-s));
        gate[t] = (sig > 0.75f) ? 1.f : 0.f;
    }
}

// ---------------------------------------------------------------------------
// k_r, v_r (fp32) and q_r (bf16) — before local_attn overwrites q with ctx
// ---------------------------------------------------------------------------
__global__ void kvr_kernel(const float* __restrict__ qkv,
                           const float* __restrict__ pk,
                           const float* __restrict__ pv,
                           float* __restrict__ kr, float* __restrict__ vr,
                           bf16_t* __restrict__ qr) {
    const int h = blockIdx.y;
    const int s = blockIdx.x * 4 + (threadIdx.x >> 6);
    const int r = threadIdx.x & 63;
    const float* qrow = qkv + (size_t)s * QKV_LD + h * HD;
    const float* krow = qrow + 2048;
    const float* vrow = qrow + 4096;
    float ak = 0.f, av = 0.f, aq = 0.f;
#pragma unroll 4
    for (int d = 0; d < HD; ++d) {
        float pkd = pk[r * HD + d], pvd = pv[r * HD + d];
        ak += krow[d] * pkd;
        av += vrow[d] * pvd;
        aq += qrow[d] * pkd;
    }
    size_t idx = ((size_t)h * T_LEN + s) * RANK + r;
    kr[idx] = ak;
    vr[idx] = av;
    qr[idx] = (bf16_t)aq;
}

// ---------------------------------------------------------------------------
// MFMA bf16 flash local attention (unchanged from R2, verified)
// ---------------------------------------------------------------------------
#define QTI 64
#define KTI 64
#define QS_LD 136
#define VT_LD 68
#define PS_LD 72

__global__ __launch_bounds__(256)
void local_attn_kernel(float* __restrict__ qkv) {
    __shared__ bf16_t Qs[QTI * QS_LD];
    __shared__ bf16_t Ks[KTI * QS_LD];
    __shared__ bf16_t Vt[HD * VT_LD];
    __shared__ bf16_t Ps[4][16 * PS_LD];

    const int h = blockIdx.y;
    const int t0 = blockIdx.x * QTI;
    const int tid = threadIdx.x;
    const int wave = tid >> 6, lane = tid & 63;
    const int quad = lane >> 4, l16 = lane & 15;

#pragma unroll
    for (int i = 0; i < 8; ++i) {
        int gid = i * 256 + tid;
        int row = gid >> 5, c4 = (gid & 31) << 2;
        const float4 v = *(const float4*)(qkv + (size_t)(t0 + row) * QKV_LD + h * HD + c4);
        bf16x4 p;
        p[0] = (bf16_t)(v.x * SCALE); p[1] = (bf16_t)(v.y * SCALE);
        p[2] = (bf16_t)(v.z * SCALE); p[3] = (bf16_t)(v.w * SCALE);
        *(bf16x4*)&Qs[row * QS_LD + c4] = p;
    }

    f32x4 o[8];
#pragma unroll
    for (int d8 = 0; d8 < 8; ++d8) o[d8] = (f32x4){0.f, 0.f, 0.f, 0.f};
    float m_i[4] = {-1e30f, -1e30f, -1e30f, -1e30f};
    float l_i[4] = {0.f, 0.f, 0.f, 0.f};

    __syncthreads();

    for (int kt = 0; kt < 9; ++kt) {
        const int sbase = t0 - 512 + kt * KTI;
        if (sbase < 0) continue;
        __syncthreads();
#pragma unroll
        for (int i = 0; i < 8; ++i) {
            int gid = i * 256 + tid;
            int row = gid >> 5, c4 = (gid & 31) << 2;
            const float* base = qkv + (size_t)(sbase + row) * QKV_LD + h * HD + c4;
            const float4 kv = *(const float4*)(base + 2048);
            bf16x4 pk4;
            pk4[0] = (bf16_t)kv.x; pk4[1] = (bf16_t)kv.y;
            pk4[2] = (bf16_t)kv.z; pk4[3] = (bf16_t)kv.w;
            *(bf16x4*)&Ks[row * QS_LD + c4] = pk4;
            const float4 vv = *(const float4*)(base + 4096);
            Vt[(c4 + 0) * VT_LD + row] = (bf16_t)vv.x;
            Vt[(c4 + 1) * VT_LD + row] = (bf16_t)vv.y;
            Vt[(c4 + 2) * VT_LD + row] = (bf16_t)vv.z;
            Vt[(c4 + 3) * VT_LD + row] = (bf16_t)vv.w;
        }
        __syncthreads();

        f32x4 sacc[4];
#pragma unroll
        for (int nt = 0; nt < 4; ++nt) sacc[nt] = (f32x4){0.f, 0.f, 0.f, 0.f};
#pragma unroll
        for (int ks = 0; ks < 4; ++ks) {
            bf16x8 a = *(const bf16x8*)&Qs[(wave * 16 + l16) * QS_LD + ks * 32 + quad * 8];
#pragma unroll
            for (int nt = 0; nt < 4; ++nt) {
                bf16x8 b = *(const bf16x8*)&Ks[(nt * 16 + l16) * QS_LD + ks * 32 + quad * 8];
                sacc[nt] = __builtin_amdgcn_mfma_f32_16x16x32_bf16(a, b, sacc[nt], 0, 0, 0);
            }
        }

#pragma unroll
        for (int nt = 0; nt < 4; ++nt) {
            int s_g = sbase + nt * 16 + l16;
#pragma unroll
            for (int r = 0; r < 4; ++r) {
                int t_g = t0 + wave * 16 + quad * 4 + r;
                bool valid = (s_g <= t_g) && (s_g + W_LOCAL > t_g);
                if (!valid) sacc[nt][r] = -1e30f;
            }
        }

#pragma unroll
        for (int r = 0; r < 4; ++r) {
            float mx = fmaxf(fmaxf(sacc[0][r], sacc[1][r]), fmaxf(sacc[2][r], sacc[3][r]));
            mx = fmaxf(mx, __shfl_xor(mx, 1));
            mx = fmaxf(mx, __shfl_xor(mx, 2));
            mx = fmaxf(mx, __shfl_xor(mx, 4));
            mx = fmaxf(mx, __shfl_xor(mx, 8));
            float mnew = fmaxf(m_i[r], mx);
            float alpha = __expf(m_i[r] - mnew);
            m_i[r] = mnew;
            float rs = 0.f;
#pragma unroll
            for (int nt = 0; nt < 4; ++nt) {
                float p = __expf(sacc[nt][r] - mnew);
                sacc[nt][r] = p;
                rs += p;
            }
            rs += __shfl_xor(rs, 1);
            rs += __shfl_xor(rs, 2);
            rs += __shfl_xor(rs, 4);
            rs += __shfl_xor(rs, 8);
            l_i[r] = l_i[r] * alpha + rs;
#pragma unroll
            for (int d8 = 0; d8 < 8; ++d8) o[d8][r] *= alpha;
        }

#pragma unroll
        for (int r = 0; r < 4; ++r)
#pragma unroll
            for (int nt = 0; nt < 4; ++nt)
                Ps[wave][(quad * 4 + r) * PS_LD + nt * 16 + l16] = (bf16_t)sacc[nt][r];

#pragma unroll
        for (int ks2 = 0; ks2 < 2; ++ks2) {
            bf16x8 a = *(const bf16x8*)&Ps[wave][l16 * PS_LD + ks2 * 32 + quad * 8];
#pragma unroll
            for (int d8 = 0; d8 < 8; ++d8) {
                const bf16_t* vb = &Vt[(d8 * 16 + l16) * VT_LD + ks2 * 32 + quad * 8];
                bf16x4 b0 = *(const bf16x4*)vb;
                bf16x4 b1 = *(const bf16x4*)(vb + 4);
                bf16x8 b;
                b[0] = b0[0]; b[1] = b0[1]; b[2] = b0[2]; b[3] = b0[3];
                b[4] = b1[0]; b[5] = b1[1]; b[6] = b1[2]; b[7] = b1[3];
                o[d8] = __builtin_amdgcn_mfma_f32_16x16x32_bf16(a, b, o[d8], 0, 0, 0);
            }
        }
    }

#pragma unroll
    for (int r = 0; r < 4; ++r) {
        float inv = 1.0f / l_i[r];
        size_t rowoff = (size_t)(t0 + wave * 16 + quad * 4 + r) * QKV_LD + h * HD;
#pragma unroll
        for (int d8 = 0; d8 < 8; ++d8)
            qkv[rowoff + d8 * 16 + l16] = o[d8][r] * inv;
    }
}

// ---------------------------------------------------------------------------
// Gated global low-rank branch (early-exit when gate==0)
// ---------------------------------------------------------------------------
__device__ __forceinline__ float block_reduce_max512(float v, float* red, int tid) {
    red[tid] = v; __syncthreads();
    for (int s = 256; s > 0; s >>= 1) {
        if (tid < s) red[tid] = fmaxf(red[tid], red[tid + s]);
        __syncthreads();
    }
    float r = red[0]; __syncthreads();
    return r;
}
__device__ __forceinline__ float block_reduce_sum512(float v, float* red, int tid) {
    red[tid] = v; __syncthreads();
    for (int s = 256; s > 0; s >>= 1) {
        if (tid < s) red[tid] = red[tid] + red[tid + s];
        __syncthreads();
    }
    float r = red[0]; __syncthreads();
    return r;
}

__global__ __launch_bounds__(512)
void global_attn_kernel(float* __restrict__ qkv, const float* __restrict__ kr,
                        const float* __restrict__ vr, const bf16_t* __restrict__ qr,
                        const float* __restrict__ uo, const float* __restrict__ gate) {
    const int t = blockIdx.x, h = blockIdx.y;
    if (gate[t] <= 0.5f) return;

    __shared__ float qrs[64];
    __shared__ float red[512];
    __shared__ float cgr[64];
    __shared__ float sg[2048];
    const int tid = threadIdx.x;

    if (tid < 64) qrs[tid] = (float)qr[((size_t)h * T_LEN + t) * RANK + tid];
    __syncthreads();

    const float* krh = kr + (size_t)h * T_LEN * RANK;
    const float* vrh = vr + (size_t)h * T_LEN * RANK;
    float lmax = -INFINITY;
    for (int s = tid; s < T_LEN; s += 512) {
        const float* krr = krh + (size_t)s * RANK;
        float acc = 0.f;
#pragma unroll
        for (int r = 0; r < RANK; r += 4) {
            float4 k4 = *(const float4*)(krr + r);
            acc += qrs[r] * k4.x + qrs[r + 1] * k4.y + qrs[r + 2] * k4.z + qrs[r + 3] * k4.w;
        }
        float sc = acc * SCALE_G;
        sg[s] = sc;
        lmax = fmaxf(lmax, sc);
    }
    float gmx = block_reduce_max512(lmax, red, tid);
    float lsum = 0.f;
    for (int s = tid; s < T_LEN; s += 512) {
        float pp = expf(sg[s] - gmx);
        sg[s] = pp;
        lsum += pp;
    }
    float gsum = block_reduce_sum512(lsum, red, tid);

    {
        const int r = tid & 63, part = tid >> 6;
        float pacc = 0.f;
        for (int s = part; s < T_LEN; s += 8) pacc += sg[s] * vrh[(size_t)s * RANK + r];
        red[tid] = pacc;
        __syncthreads();
        if (tid < 64) {
            float c = 0.f;
#pragma unroll
            for (int pp = 0; pp < 8; ++pp) c += red[pp * 64 + tid];
            cgr[tid] = c / gsum;
        }
        __syncthreads();
    }

    if (tid < 128) {
        float cg = 0.f;
#pragma unroll
        for (int r = 0; r < RANK; ++r) cg += cgr[r] * uo[tid * RANK + r];
        qkv[(size_t)t * QKV_LD + h * HD + tid] += cg;
    }
}

// ---------------------------------------------------------------------------
extern "C" void kernel_launch(void* const* d_in, const int* in_sizes, int n_in,
                              void* d_out, int out_size, void* d_ws, size_t ws_size,
                              hipStream_t stream) {
    const float* x     = (const float*)d_in[0];
    const float* w_qkv = (const float*)d_in[1];
    const float* w_o   = (const float*)d_in[2];
    const float* pk    = (const float*)d_in[3];
    const float* pv    = (const float*)d_in[4];
    const float* uo    = (const float*)d_in[5];
    const float* w1    = (const float*)d_in[6];
    const float* w2    = (const float*)d_in[7];
    float* out = (float*)d_out;

    // Workspace layout (floats), with lifetime-based aliasing (~88 MB):
    float* ws = (float*)d_ws;
    float* qkv   = ws;                        // 12,582,912 f (qkv; q-region becomes ctx)
    float* hinfo = qkv + (size_t)12582912;    // 1,048,576 f (h_info; later qr bf16)
    float* gatep = hinfo + (size_t)1048576;   // 2048 f
    bf16_t* xb   = (bf16_t*)(gatep + 2048);   // 2048*2048 bf16 (x; later ctx_bf)
    float* wqbf  = gatep + 2048 + 2097152;    // 6,291,456 f region:
    bf16_t* wqb  = (bf16_t*)wqbf;             //   w_qkv bf16 (6144*2048)
    float* krp   = wqbf;                      //   later: kr (16*2048*64 f)
    float* vrp   = wqbf + (size_t)2097152;    //   later: vr (16*2048*64 f)
    bf16_t* wob  = (bf16_t*)krp;              //   later still: w_o bf16 (2048*2048)
    bf16_t* qrp  = (bf16_t*)hinfo;            // qr bf16 (16*2048*64)
    bf16_t* cxb  = xb;                        // ctx bf16 (2048*2048)

    // 1) convert x, w_qkv to bf16
    conv_f32_bf16<<<2048, 256, 0, stream>>>(x, xb, 2048, 2048, 2048);
    conv_f32_bf16<<<6144, 256, 0, stream>>>(w_qkv, wqb, 2048, 2048, 6144);
    // 2) qkv = x @ w_qkv^T  (bf16 MFMA, fp32 out, ldc=6144)
    gemm_bf16_nt<<<dim3(48, 16), 256, 0, stream>>>(xb, wqb, qkv, 2048, 2048, 2048, QKV_LD);
    // 3) h_info = gelu(x @ w1^T)  (fp32 — gate-critical)
    gemm_nt<<<dim3(4, 16), 256, 0, stream>>>(x, w1, hinfo, 2048, 512, 2048, 2048, 2048, 512, 1);
    // 4) RoPE in place
    rope_kernel<<<T_LEN, 256, 0, stream>>>(qkv);
    // 5) gate (before hinfo is reused as qr)
    gate_kernel<<<T_LEN, 64, 0, stream>>>(hinfo, w2, gatep);
    // 6) k_r, v_r, q_r  (kr/vr overwrite dead wqb region)
    kvr_kernel<<<dim3(T_LEN / 4, NH), 256, 0, stream>>>(qkv, pk, pv, krp, vrp, qrp);
    // 7) flash local attention -> ctx (over q region)
    local_attn_kernel<<<dim3(T_LEN / QTI, NH), 256, 0, stream>>>(qkv);
    // 8) gated global branch (adds into ctx)
    global_attn_kernel<<<dim3(T_LEN, NH), 512, 0, stream>>>(qkv, krp, vrp, qrp, uo, gatep);
    // 9) convert ctx -> bf16 (into dead xb), w_o -> bf16 (into dead kr)
    conv_f32_bf16<<<2048, 256, 0, stream>>>(qkv, cxb, QKV_LD, 2048, 2048);
    conv_f32_bf16<<<2048, 256, 0, stream>>>(w_o, wob, 2048, 2048, 2048);
    // 10) out = ctx @ w_o^T  (bf16 MFMA)
    gemm_bf16_nt<<<dim3(16, 16), 256, 0, stream>>>(cxb, wob, out, 2048, 2048, 2048, 2048);
}

// Round 4
// 685.029 us; speedup vs baseline: 5.6716x; 1.4946x over previous
//
#include <hip/hip_runtime.h>
#include <hip/hip_bf16.h>
#include <math.h>

// Problem constants
#define T_LEN 2048
#define C_DIM 2048
#define NH 16
#define HD 128
#define RANK 64
#define W_LOCAL 512
#define QKV_LD 6144
#define SCALE 0.08838834764831845f    // 1/sqrt(128)
#define SCALE_G 0.17677669529663687f  // scale * 128/64
#define LOG1E4_OVER_64 0.14391156831212787f

typedef __bf16 bf16_t;
typedef __bf16 bf16x8 __attribute__((ext_vector_type(8)));
typedef __bf16 bf16x4 __attribute__((ext_vector_type(4)));
typedef float f32x4 __attribute__((ext_vector_type(4)));

// ---------------------------------------------------------------------------
// async 16B global -> LDS (gfx950)
// ---------------------------------------------------------------------------
__device__ __forceinline__ void async_copy16(const bf16_t* g, bf16_t* l) {
    __builtin_amdgcn_global_load_lds(
        (const __attribute__((address_space(1))) unsigned int*)g,
        (__attribute__((address_space(3))) unsigned int*)l, 16, 0, 0);
}

// ---------------------------------------------------------------------------
// fp32 -> bf16 conversion, 8 elems/thread
// ---------------------------------------------------------------------------
__global__ __launch_bounds__(256)
void conv_f32_bf16(const float* __restrict__ in, bf16_t* __restrict__ out,
                   int ld_in, int cols, int rows) {
    int per_row = cols >> 3;
    int idx = blockIdx.x * 256 + threadIdx.x;
    if (idx >= rows * per_row) return;
    int row = idx / per_row, c = (idx - row * per_row) << 3;
    const float* p = in + (size_t)row * ld_in + c;
    float4 v0 = *(const float4*)p;
    float4 v1 = *(const float4*)(p + 4);
    bf16x8 o;
    o[0] = (bf16_t)v0.x; o[1] = (bf16_t)v0.y; o[2] = (bf16_t)v0.z; o[3] = (bf16_t)v0.w;
    o[4] = (bf16_t)v1.x; o[5] = (bf16_t)v1.y; o[6] = (bf16_t)v1.z; o[7] = (bf16_t)v1.w;
    *(bf16x8*)(out + (size_t)row * cols + c) = o;
}

// ---------------------------------------------------------------------------
// bf16 MFMA GEMM (m97 recipe)
// ---------------------------------------------------------------------------
#define GBK 32

__global__ __launch_bounds__(256)
void gemm_bf16_nt(const bf16_t* __restrict__ A, const bf16_t* __restrict__ B,
                  float* __restrict__ C, int K, int lda, int ldb, int ldc) {
    __shared__ bf16_t As[128 * GBK];
    __shared__ bf16_t Bs[128 * GBK];
    const int tid = threadIdx.x;
    const int wave = tid >> 6, lane = tid & 63;
    const int quad = lane >> 4, l16 = lane & 15;
    const int bm = blockIdx.y * 128, bn = blockIdx.x * 128;
    const int wm = (wave >> 1) * 64, wn = (wave & 1) * 64;
    const int lrow = lane >> 2;
    const int lkb = (lane & 3) * 8;

    f32x4 acc[4][4];
#pragma unroll
    for (int i = 0; i < 4; ++i)
#pragma unroll
        for (int j = 0; j < 4; ++j) acc[i][j] = (f32x4){0.f, 0.f, 0.f, 0.f};

    const bf16_t* gA = A + (size_t)(bm + wave * 16 + lrow) * lda + lkb;
    const bf16_t* gB = B + (size_t)(bn + wave * 16 + lrow) * ldb + lkb;
    bf16_t* lA = &As[(wave * 16 + lrow) * GBK + lkb];
    bf16_t* lB = &Bs[(wave * 16 + lrow) * GBK + lkb];

    for (int k0 = 0; k0 < K; k0 += GBK) {
        __syncthreads();
        async_copy16(gA + k0, lA);
        async_copy16(gA + (size_t)64 * lda + k0, lA + 64 * GBK);
        async_copy16(gB + k0, lB);
        async_copy16(gB + (size_t)64 * ldb + k0, lB + 64 * GBK);
        __syncthreads();

        bf16x8 a[4], b[4];
#pragma unroll
        for (int mt = 0; mt < 4; ++mt)
            a[mt] = *(const bf16x8*)&As[(wm + mt * 16 + l16) * GBK + quad * 8];
#pragma unroll
        for (int nt = 0; nt < 4; ++nt)
            b[nt] = *(const bf16x8*)&Bs[(wn + nt * 16 + l16) * GBK + quad * 8];
#pragma unroll
        for (int mt = 0; mt < 4; ++mt)
#pragma unroll
            for (int nt = 0; nt < 4; ++nt)
                acc[mt][nt] = __builtin_amdgcn_mfma_f32_16x16x32_bf16(a[mt], b[nt], acc[mt][nt], 0, 0, 0);
    }

#pragma unroll
    for (int mt = 0; mt < 4; ++mt)
#pragma unroll
        for (int r = 0; r < 4; ++r) {
            int row = bm + wm + mt * 16 + quad * 4 + r;
            float* crow = C + (size_t)row * ldc + bn + wn;
#pragma unroll
            for (int nt = 0; nt < 4; ++nt)
                crow[nt * 16 + l16] = acc[mt][nt][r];
        }
}

// ---------------------------------------------------------------------------
// fp32 GEMM (gate-critical info MLP)
// ---------------------------------------------------------------------------
#define BM 128
#define BN 128
#define BK 16

__device__ __forceinline__ float gelu_exact(float v) {
    return 0.5f * v * (1.0f + erff(v * 0.70710678118654752f));
}

__global__ __launch_bounds__(256)
void gemm_nt(const float* __restrict__ A, const float* __restrict__ B,
             float* __restrict__ C, int M, int N, int K,
             int lda, int ldb, int ldc, int act) {
    __shared__ float As[BK][BM];
    __shared__ float Bs[BK][BN];
    const int tid = threadIdx.x;
    const int bm = blockIdx.y * BM;
    const int bn = blockIdx.x * BN;
    const int ty = tid >> 4;
    const int tx = tid & 15;

    float acc[8][8];
#pragma unroll
    for (int i = 0; i < 8; ++i)
#pragma unroll
        for (int j = 0; j < 8; ++j) acc[i][j] = 0.f;

    for (int k0 = 0; k0 < K; k0 += BK) {
#pragma unroll
        for (int l = tid; l < (BM * BK) / 4; l += 256) {
            int row = l >> 2, c4 = (l & 3) << 2;
            float4 v = *(const float4*)(A + (size_t)(bm + row) * lda + k0 + c4);
            As[c4 + 0][row] = v.x; As[c4 + 1][row] = v.y;
            As[c4 + 2][row] = v.z; As[c4 + 3][row] = v.w;
        }
#pragma unroll
        for (int l = tid; l < (BN * BK) / 4; l += 256) {
            int row = l >> 2, c4 = (l & 3) << 2;
            float4 v = *(const float4*)(B + (size_t)(bn + row) * ldb + k0 + c4);
            Bs[c4 + 0][row] = v.x; Bs[c4 + 1][row] = v.y;
            Bs[c4 + 2][row] = v.z; Bs[c4 + 3][row] = v.w;
        }
        __syncthreads();
#pragma unroll
        for (int kk = 0; kk < BK; ++kk) {
            float a[8], b[8];
#pragma unroll
            for (int i = 0; i < 8; ++i) a[i] = As[kk][ty * 8 + i];
#pragma unroll
            for (int j = 0; j < 8; ++j) b[j] = Bs[kk][tx * 8 + j];
#pragma unroll
            for (int i = 0; i < 8; ++i)
#pragma unroll
                for (int j = 0; j < 8; ++j) acc[i][j] += a[i] * b[j];
        }
        __syncthreads();
    }
#pragma unroll
    for (int i = 0; i < 8; ++i) {
        size_t rowoff = (size_t)(bm + ty * 8 + i) * ldc + bn + tx * 8;
#pragma unroll
        for (int j = 0; j < 8; ++j) {
            float v = acc[i][j];
            if (act == 1) v = gelu_exact(v);
            C[rowoff + j] = v;
        }
    }
}

// ---------------------------------------------------------------------------
// RoPE tables: tab[t*128 + j] = cos(t*invf[j]), tab[t*128 + 64 + j] = sin(...)
// ---------------------------------------------------------------------------
__global__ __launch_bounds__(256)
void rope_table_kernel(float* __restrict__ tab) {
    int idx = blockIdx.x * 256 + threadIdx.x;   // 2048*64
    int t = idx >> 6, j = idx & 63;
    float inv = expf(-(float)j * LOG1E4_OVER_64);
    float s, c;
    sincosf((float)t * inv, &s, &c);
    tab[t * 128 + j] = c;
    tab[t * 128 + 64 + j] = s;
}

// RoPE apply on cols [0,4096) of qkv (q and k regions), 8 elems/thread.
__global__ __launch_bounds__(256)
void rope_apply_kernel(float* __restrict__ qkv, const float* __restrict__ tab) {
    int idx = blockIdx.x * 256 + threadIdx.x;   // 2048 rows * 512 thr/row
    int t = idx >> 9;
    int c = (idx & 511) << 3;
    float* row = qkv + (size_t)t * QKV_LD + c;
    const float* tr = tab + t * 128;
    float4 a = *(const float4*)row;
    float4 b = *(const float4*)(row + 4);
    float xs[8] = {a.x, a.y, a.z, a.w, b.x, b.y, b.z, b.w};
    int d0 = c & 127;
    float ys[8];
#pragma unroll
    for (int m = 0; m < 4; ++m) {
        int j0 = (d0 + 2 * m) & 63;
        float c0 = tr[j0], s0 = tr[64 + j0];
        float c1 = tr[j0 + 1], s1 = tr[64 + j0 + 1];
        float x0 = xs[2 * m], x1 = xs[2 * m + 1];
        ys[2 * m]     = x0 * c0 - x1 * s0;
        ys[2 * m + 1] = x1 * c1 + x0 * s1;
    }
    *(float4*)row       = make_float4(ys[0], ys[1], ys[2], ys[3]);
    *(float4*)(row + 4) = make_float4(ys[4], ys[5], ys[6], ys[7]);
}

// ---------------------------------------------------------------------------
// Gate (fp32 path, exact)
// ---------------------------------------------------------------------------
__global__ void gate_kernel(const float* __restrict__ h_info,
                            const float* __restrict__ w2,
                            float* __restrict__ gate) {
    const int t = blockIdx.x;
    const int lane = threadIdx.x;
    float s = 0.f;
    for (int i = lane; i < 512; i += 64) s += h_info[(size_t)t * 512 + i] * w2[i];
#pragma unroll
    for (int off = 32; off > 0; off >>= 1) s += __shfl_down(s, off);
    if (lane == 0) {
        float sig = 1.f / (1.f + expf(-s));
        gate[t] = (sig > 0.75f) ? 1.f : 0.f;
    }
}

// ---------------------------------------------------------------------------
// MFMA kvr: per block (64 s x head h): kr = K pk^T, vr = V pv^T, qr = Q pk^T.
// Stages K/V/Q tiles + pk/pv in LDS as bf16 (LD=136: 2-way-free banks).
// ---------------------------------------------------------------------------
#define KV_LD 136

__global__ __launch_bounds__(256)
void kvr_mfma_kernel(const float* __restrict__ qkv,
                     const float* __restrict__ pk, const float* __restrict__ pv,
                     float* __restrict__ kr, float* __restrict__ vr,
                     bf16_t* __restrict__ qr) {
    __shared__ bf16_t Kt[64 * KV_LD];
    __shared__ bf16_t Vt[64 * KV_LD];
    __shared__ bf16_t Qt[64 * KV_LD];
    __shared__ bf16_t Pk[64 * KV_LD];
    __shared__ bf16_t Pv[64 * KV_LD];

    const int h = blockIdx.y;
    const int s0 = blockIdx.x * 64;
    const int tid = threadIdx.x;
    const int wave = tid >> 6, lane = tid & 63;
    const int quad = lane >> 4, l16 = lane & 15;

#pragma unroll
    for (int i = 0; i < 8; ++i) {
        int gid = i * 256 + tid;              // 2048 float4 slots = 64 rows x 32
        int row = gid >> 5, c = (gid & 31) << 2;
        const float* base = qkv + (size_t)(s0 + row) * QKV_LD + h * HD + c;
        float4 vq = *(const float4*)base;
        float4 vk = *(const float4*)(base + 2048);
        float4 vv = *(const float4*)(base + 4096);
        bf16x4 pq, pkk, pvv;
        pq[0] = (bf16_t)vq.x; pq[1] = (bf16_t)vq.y; pq[2] = (bf16_t)vq.z; pq[3] = (bf16_t)vq.w;
        pkk[0] = (bf16_t)vk.x; pkk[1] = (bf16_t)vk.y; pkk[2] = (bf16_t)vk.z; pkk[3] = (bf16_t)vk.w;
        pvv[0] = (bf16_t)vv.x; pvv[1] = (bf16_t)vv.y; pvv[2] = (bf16_t)vv.z; pvv[3] = (bf16_t)vv.w;
        *(bf16x4*)&Qt[row * KV_LD + c] = pq;
        *(bf16x4*)&Kt[row * KV_LD + c] = pkk;
        *(bf16x4*)&Vt[row * KV_LD + c] = pvv;
        // pk, pv: 64x128
        float4 wk = *(const float4*)(pk + (size_t)row * HD + c);
        float4 wv = *(const float4*)(pv + (size_t)row * HD + c);
        bf16x4 qk4, qv4;
        qk4[0] = (bf16_t)wk.x; qk4[1] = (bf16_t)wk.y; qk4[2] = (bf16_t)wk.z; qk4[3] = (bf16_t)wk.w;
        qv4[0] = (bf16_t)wv.x; qv4[1] = (bf16_t)wv.y; qv4[2] = (bf16_t)wv.z; qv4[3] = (bf16_t)wv.w;
        *(bf16x4*)&Pk[row * KV_LD + c] = qk4;
        *(bf16x4*)&Pv[row * KV_LD + c] = qv4;
    }
    __syncthreads();

    f32x4 ak[4], av[4], aq[4];
#pragma unroll
    for (int nt = 0; nt < 4; ++nt) {
        ak[nt] = (f32x4){0.f, 0.f, 0.f, 0.f};
        av[nt] = (f32x4){0.f, 0.f, 0.f, 0.f};
        aq[nt] = (f32x4){0.f, 0.f, 0.f, 0.f};
    }

#pragma unroll
    for (int ks = 0; ks < 4; ++ks) {
        const int ao = (wave * 16 + l16) * KV_LD + ks * 32 + quad * 8;
        bf16x8 a_k = *(const bf16x8*)&Kt[ao];
        bf16x8 a_v = *(const bf16x8*)&Vt[ao];
        bf16x8 a_q = *(const bf16x8*)&Qt[ao];
#pragma unroll
        for (int nt = 0; nt < 4; ++nt) {
            const int bo = (nt * 16 + l16) * KV_LD + ks * 32 + quad * 8;
            bf16x8 bk = *(const bf16x8*)&Pk[bo];
            bf16x8 bv = *(const bf16x8*)&Pv[bo];
            ak[nt] = __builtin_amdgcn_mfma_f32_16x16x32_bf16(a_k, bk, ak[nt], 0, 0, 0);
            av[nt] = __builtin_amdgcn_mfma_f32_16x16x32_bf16(a_v, bv, av[nt], 0, 0, 0);
            aq[nt] = __builtin_amdgcn_mfma_f32_16x16x32_bf16(a_q, bk, aq[nt], 0, 0, 0);
        }
    }

#pragma unroll
    for (int nt = 0; nt < 4; ++nt)
#pragma unroll
        for (int r = 0; r < 4; ++r) {
            int s = s0 + wave * 16 + quad * 4 + r;
            size_t idx = ((size_t)h * T_LEN + s) * RANK + nt * 16 + l16;
            kr[idx] = ak[nt][r];
            vr[idx] = av[nt][r];
            qr[idx] = (bf16_t)aq[nt][r];
        }
}

// ---------------------------------------------------------------------------
// MFMA bf16 flash local attention (unchanged, verified)
// ---------------------------------------------------------------------------
#define QTI 64
#define KTI 64
#define QS_LD 136
#define VT_LD 68
#define PS_LD 72

__global__ __launch_bounds__(256)
void local_attn_kernel(float* __restrict__ qkv) {
    __shared__ bf16_t Qs[QTI * QS_LD];
    __shared__ bf16_t Ks[KTI * QS_LD];
    __shared__ bf16_t Vt[HD * VT_LD];
    __shared__ bf16_t Ps[4][16 * PS_LD];

    const int h = blockIdx.y;
    const int t0 = blockIdx.x * QTI;
    const int tid = threadIdx.x;
    const int wave = tid >> 6, lane = tid & 63;
    const int quad = lane >> 4, l16 = lane & 15;

#pragma unroll
    for (int i = 0; i < 8; ++i) {
        int gid = i * 256 + tid;
        int row = gid >> 5, c4 = (gid & 31) << 2;
        const float4 v = *(const float4*)(qkv + (size_t)(t0 + row) * QKV_LD + h * HD + c4);
        bf16x4 p;
        p[0] = (bf16_t)(v.x * SCALE); p[1] = (bf16_t)(v.y * SCALE);
        p[2] = (bf16_t)(v.z * SCALE); p[3] = (bf16_t)(v.w * SCALE);
        *(bf16x4*)&Qs[row * QS_LD + c4] = p;
    }

    f32x4 o[8];
#pragma unroll
    for (int d8 = 0; d8 < 8; ++d8) o[d8] = (f32x4){0.f, 0.f, 0.f, 0.f};
    float m_i[4] = {-1e30f, -1e30f, -1e30f, -1e30f};
    float l_i[4] = {0.f, 0.f, 0.f, 0.f};

    __syncthreads();

    for (int kt = 0; kt < 9; ++kt) {
        const int sbase = t0 - 512 + kt * KTI;
        if (sbase < 0) continue;
        __syncthreads();
#pragma unroll
        for (int i = 0; i < 8; ++i) {
            int gid = i * 256 + tid;
            int row = gid >> 5, c4 = (gid & 31) << 2;
            const float* base = qkv + (size_t)(sbase + row) * QKV_LD + h * HD + c4;
            const float4 kv = *(const float4*)(base + 2048);
            bf16x4 pk4;
            pk4[0] = (bf16_t)kv.x; pk4[1] = (bf16_t)kv.y;
            pk4[2] = (bf16_t)kv.z; pk4[3] = (bf16_t)kv.w;
            *(bf16x4*)&Ks[row * QS_LD + c4] = pk4;
            const float4 vv = *(const float4*)(base + 4096);
            Vt[(c4 + 0) * VT_LD + row] = (bf16_t)vv.x;
            Vt[(c4 + 1) * VT_LD + row] = (bf16_t)vv.y;
            Vt[(c4 + 2) * VT_LD + row] = (bf16_t)vv.z;
            Vt[(c4 + 3) * VT_LD + row] = (bf16_t)vv.w;
        }
        __syncthreads();

        f32x4 sacc[4];
#pragma unroll
        for (int nt = 0; nt < 4; ++nt) sacc[nt] = (f32x4){0.f, 0.f, 0.f, 0.f};
#pragma unroll
        for (int ks = 0; ks < 4; ++ks) {
            bf16x8 a = *(const bf16x8*)&Qs[(wave * 16 + l16) * QS_LD + ks * 32 + quad * 8];
#pragma unroll
            for (int nt = 0; nt < 4; ++nt) {
                bf16x8 b = *(const bf16x8*)&Ks[(nt * 16 + l16) * QS_LD + ks * 32 + quad * 8];
                sacc[nt] = __builtin_amdgcn_mfma_f32_16x16x32_bf16(a, b, sacc[nt], 0, 0, 0);
            }
        }

#pragma unroll
        for (int nt = 0; nt < 4; ++nt) {
            int s_g = sbase + nt * 16 + l16;
#pragma unroll
            for (int r = 0; r < 4; ++r) {
                int t_g = t0 + wave * 16 + quad * 4 + r;
                bool valid = (s_g <= t_g) && (s_g + W_LOCAL > t_g);
                if (!valid) sacc[nt][r] = -1e30f;
            }
        }

#pragma unroll
        for (int r = 0; r < 4; ++r) {
            float mx = fmaxf(fmaxf(sacc[0][r], sacc[1][r]), fmaxf(sacc[2][r], sacc[3][r]));
            mx = fmaxf(mx, __shfl_xor(mx, 1));
            mx = fmaxf(mx, __shfl_xor(mx, 2));
            mx = fmaxf(mx, __shfl_xor(mx, 4));
            mx = fmaxf(mx, __shfl_xor(mx, 8));
            float mnew = fmaxf(m_i[r], mx);
            float alpha = __expf(m_i[r] - mnew);
            m_i[r] = mnew;
            float rs = 0.f;
#pragma unroll
            for (int nt = 0; nt < 4; ++nt) {
                float p = __expf(sacc[nt][r] - mnew);
                sacc[nt][r] = p;
                rs += p;
            }
            rs += __shfl_xor(rs, 1);
            rs += __shfl_xor(rs, 2);
            rs += __shfl_xor(rs, 4);
            rs += __shfl_xor(rs, 8);
            l_i[r] = l_i[r] * alpha + rs;
#pragma unroll
            for (int d8 = 0; d8 < 8; ++d8) o[d8][r] *= alpha;
        }

#pragma unroll
        for (int r = 0; r < 4; ++r)
#pragma unroll
            for (int nt = 0; nt < 4; ++nt)
                Ps[wave][(quad * 4 + r) * PS_LD + nt * 16 + l16] = (bf16_t)sacc[nt][r];

#pragma unroll
        for (int ks2 = 0; ks2 < 2; ++ks2) {
            bf16x8 a = *(const bf16x8*)&Ps[wave][l16 * PS_LD + ks2 * 32 + quad * 8];
#pragma unroll
            for (int d8 = 0; d8 < 8; ++d8) {
                const bf16_t* vb = &Vt[(d8 * 16 + l16) * VT_LD + ks2 * 32 + quad * 8];
                bf16x4 b0 = *(const bf16x4*)vb;
                bf16x4 b1 = *(const bf16x4*)(vb + 4);
                bf16x8 b;
                b[0] = b0[0]; b[1] = b0[1]; b[2] = b0[2]; b[3] = b0[3];
                b[4] = b1[0]; b[5] = b1[1]; b[6] = b1[2]; b[7] = b1[3];
                o[d8] = __builtin_amdgcn_mfma_f32_16x16x32_bf16(a, b, o[d8], 0, 0, 0);
            }
        }
    }

#pragma unroll
    for (int r = 0; r < 4; ++r) {
        float inv = 1.0f / l_i[r];
        size_t rowoff = (size_t)(t0 + wave * 16 + quad * 4 + r) * QKV_LD + h * HD;
#pragma unroll
        for (int d8 = 0; d8 < 8; ++d8)
            qkv[rowoff + d8 * 16 + l16] = o[d8][r] * inv;
    }
}

// ---------------------------------------------------------------------------
// Gated global low-rank branch (early-exit when gate==0)
// ---------------------------------------------------------------------------
__device__ __forceinline__ float block_reduce_max512(float v, float* red, int tid) {
    red[tid] = v; __syncthreads();
    for (int s = 256; s > 0; s >>= 1) {
        if (tid < s) red[tid] = fmaxf(red[tid], red[tid + s]);
        __syncthreads();
    }
    float r = red[0]; __syncthreads();
    return r;
}
__device__ __forceinline__ float block_reduce_sum512(float v, float* red, int tid) {
    red[tid] = v; __syncthreads();
    for (int s = 256; s > 0; s >>= 1) {
        if (tid < s) red[tid] = red[tid] + red[tid + s];
        __syncthreads();
    }
    float r = red[0]; __syncthreads();
    return r;
}

__global__ __launch_bounds__(512)
void global_attn_kernel(float* __restrict__ qkv, const float* __restrict__ kr,
                        const float* __restrict__ vr, const bf16_t* __restrict__ qr,
                        const float* __restrict__ uo, const float* __restrict__ gate) {
    const int t = blockIdx.x, h = blockIdx.y;
    if (gate[t] <= 0.5f) return;

    __shared__ float qrs[64];
    __shared__ float red[512];
    __shared__ float cgr[64];
    __shared__ float sg[2048];
    const int tid = threadIdx.x;

    if (tid < 64) qrs[tid] = (float)qr[((size_t)h * T_LEN + t) * RANK + tid];
    __syncthreads();

    const float* krh = kr + (size_t)h * T_LEN * RANK;
    const float* vrh = vr + (size_t)h * T_LEN * RANK;
    float lmax = -INFINITY;
    for (int s = tid; s < T_LEN; s += 512) {
        const float* krr = krh + (size_t)s * RANK;
        float acc = 0.f;
#pragma unroll
        for (int r = 0; r < RANK; r += 4) {
            float4 k4 = *(const float4*)(krr + r);
            acc += qrs[r] * k4.x + qrs[r + 1] * k4.y + qrs[r + 2] * k4.z + qrs[r + 3] * k4.w;
        }
        float sc = acc * SCALE_G;
        sg[s] = sc;
        lmax = fmaxf(lmax, sc);
    }
    float gmx = block_reduce_max512(lmax, red, tid);
    float lsum = 0.f;
    for (int s = tid; s < T_LEN; s += 512) {
        float pp = expf(sg[s] - gmx);
        sg[s] = pp;
        lsum += pp;
    }
    float gsum = block_reduce_sum512(lsum, red, tid);

    {
        const int r = tid & 63, part = tid >> 6;
        float pacc = 0.f;
        for (int s = part; s < T_LEN; s += 8) pacc += sg[s] * vrh[(size_t)s * RANK + r];
        red[tid] = pacc;
        __syncthreads();
        if (tid < 64) {
            float c = 0.f;
#pragma unroll
            for (int pp = 0; pp < 8; ++pp) c += red[pp * 64 + tid];
            cgr[tid] = c / gsum;
        }
        __syncthreads();
    }

    if (tid < 128) {
        float cg = 0.f;
#pragma unroll
        for (int r = 0; r < RANK; ++r) cg += cgr[r] * uo[tid * RANK + r];
        qkv[(size_t)t * QKV_LD + h * HD + tid] += cg;
    }
}

// ---------------------------------------------------------------------------
extern "C" void kernel_launch(void* const* d_in, const int* in_sizes, int n_in,
                              void* d_out, int out_size, void* d_ws, size_t ws_size,
                              hipStream_t stream) {
    const float* x     = (const float*)d_in[0];
    const float* w_qkv = (const float*)d_in[1];
    const float* w_o   = (const float*)d_in[2];
    const float* pk    = (const float*)d_in[3];
    const float* pv    = (const float*)d_in[4];
    const float* uo    = (const float*)d_in[5];
    const float* w1    = (const float*)d_in[6];
    const float* w2    = (const float*)d_in[7];
    float* out = (float*)d_out;

    // Workspace layout (floats), lifetime-aliased (~88 MB, same as R3):
    float* ws = (float*)d_ws;
    float* qkv   = ws;                        // 12,582,912 f
    float* hinfo = qkv + (size_t)12582912;    // 1,048,576 f (later qr bf16)
    float* gatep = hinfo + (size_t)1048576;   // 2048 f
    bf16_t* xb   = (bf16_t*)(gatep + 2048);   // 2048*2048 bf16 (later ctx_bf)
    float* wqbf  = gatep + 2048 + 2097152;    // 6,291,456 f region:
    bf16_t* wqb  = (bf16_t*)wqbf;             //   w_qkv bf16 (6144*2048)
    float* krp   = wqbf;                      //   later: kr (2,097,152 f)
    float* vrp   = wqbf + (size_t)2097152;    //   later: vr (2,097,152 f)
    float* tabp  = wqbf + (size_t)4194304;    //   later: rope tables (262,144 f)
    bf16_t* wob  = (bf16_t*)krp;              //   later still: w_o bf16
    bf16_t* qrp  = (bf16_t*)hinfo;            // qr bf16
    bf16_t* cxb  = xb;                        // ctx bf16

    // 1) convert x, w_qkv to bf16
    conv_f32_bf16<<<2048, 256, 0, stream>>>(x, xb, 2048, 2048, 2048);
    conv_f32_bf16<<<6144, 256, 0, stream>>>(w_qkv, wqb, 2048, 2048, 6144);
    // 2) qkv = x @ w_qkv^T  (bf16 MFMA)
    gemm_bf16_nt<<<dim3(48, 16), 256, 0, stream>>>(xb, wqb, qkv, 2048, 2048, 2048, QKV_LD);
    // 3) h_info = gelu(x @ w1^T)  (fp32 — gate-critical)
    gemm_nt<<<dim3(4, 16), 256, 0, stream>>>(x, w1, hinfo, 2048, 512, 2048, 2048, 2048, 512, 1);
    // 4) RoPE: table (aliases dead wqb tail — must follow qkv gemm), then apply
    rope_table_kernel<<<512, 256, 0, stream>>>(tabp);
    rope_apply_kernel<<<4096, 256, 0, stream>>>(qkv, tabp);
    // 5) gate (before hinfo reused as qr)
    gate_kernel<<<T_LEN, 64, 0, stream>>>(hinfo, w2, gatep);
    // 6) k_r, v_r, q_r via MFMA (kr/vr overwrite dead wqb region)
    kvr_mfma_kernel<<<dim3(T_LEN / 64, NH), 256, 0, stream>>>(qkv, pk, pv, krp, vrp, qrp);
    // 7) flash local attention -> ctx (over q region)
    local_attn_kernel<<<dim3(T_LEN / QTI, NH), 256, 0, stream>>>(qkv);
    // 8) gated global branch (adds into ctx)
    global_attn_kernel<<<dim3(T_LEN, NH), 512, 0, stream>>>(qkv, krp, vrp, qrp, uo, gatep);
    // 9) convert ctx -> bf16, w_o -> bf16
    conv_f32_bf16<<<2048, 256, 0, stream>>>(qkv, cxb, QKV_LD, 2048, 2048);
    conv_f32_bf16<<<2048, 256, 0, stream>>>(w_o, wob, 2048, 2048, 2048);
    // 10) out = ctx @ w_o^T  (bf16 MFMA)
    gemm_bf16_nt<<<dim3(16, 16), 256, 0, stream>>>(cxb, wob, out, 2048, 2048, 2048, 2048);
}

// Round 5
// 440.091 us; speedup vs baseline: 8.8282x; 1.5566x over previous
//
#include <hip/hip_runtime.h>
#include <hip/hip_bf16.h>
#include <math.h>

// Problem constants
#define T_LEN 2048
#define C_DIM 2048
#define NH 16
#define HD 128
#define RANK 64
#define W_LOCAL 512
#define QKV_LD 6144
#define SCALE 0.08838834764831845f    // 1/sqrt(128)
#define SCALE_G 0.17677669529663687f  // scale * 128/64
#define LOG1E4_OVER_64 0.14391156831212787f

typedef __bf16 bf16_t;
typedef __bf16 bf16x8 __attribute__((ext_vector_type(8)));
typedef __bf16 bf16x4 __attribute__((ext_vector_type(4)));
typedef float f32x4 __attribute__((ext_vector_type(4)));

// ---------------------------------------------------------------------------
// async 16B global -> LDS (gfx950)
// ---------------------------------------------------------------------------
__device__ __forceinline__ void async_copy16(const bf16_t* g, bf16_t* l) {
    __builtin_amdgcn_global_load_lds(
        (const __attribute__((address_space(1))) unsigned int*)g,
        (__attribute__((address_space(3))) unsigned int*)l, 16, 0, 0);
}

// ---------------------------------------------------------------------------
// fp32 -> bf16 conversion, 8 elems/thread
// ---------------------------------------------------------------------------
__global__ __launch_bounds__(256)
void conv_f32_bf16(const float* __restrict__ in, bf16_t* __restrict__ out,
                   int ld_in, int cols, int rows) {
    int per_row = cols >> 3;
    int idx = blockIdx.x * 256 + threadIdx.x;
    if (idx >= rows * per_row) return;
    int row = idx / per_row, c = (idx - row * per_row) << 3;
    const float* p = in + (size_t)row * ld_in + c;
    float4 v0 = *(const float4*)p;
    float4 v1 = *(const float4*)(p + 4);
    bf16x8 o;
    o[0] = (bf16_t)v0.x; o[1] = (bf16_t)v0.y; o[2] = (bf16_t)v0.z; o[3] = (bf16_t)v0.w;
    o[4] = (bf16_t)v1.x; o[5] = (bf16_t)v1.y; o[6] = (bf16_t)v1.z; o[7] = (bf16_t)v1.w;
    *(bf16x8*)(out + (size_t)row * cols + c) = o;
}

// ---------------------------------------------------------------------------
// bf16 MFMA GEMM (m97 recipe)
// ---------------------------------------------------------------------------
#define GBK 32

__global__ __launch_bounds__(256)
void gemm_bf16_nt(const bf16_t* __restrict__ A, const bf16_t* __restrict__ B,
                  float* __restrict__ C, int K, int lda, int ldb, int ldc) {
    __shared__ bf16_t As[128 * GBK];
    __shared__ bf16_t Bs[128 * GBK];
    const int tid = threadIdx.x;
    const int wave = tid >> 6, lane = tid & 63;
    const int quad = lane >> 4, l16 = lane & 15;
    const int bm = blockIdx.y * 128, bn = blockIdx.x * 128;
    const int wm = (wave >> 1) * 64, wn = (wave & 1) * 64;
    const int lrow = lane >> 2;
    const int lkb = (lane & 3) * 8;

    f32x4 acc[4][4];
#pragma unroll
    for (int i = 0; i < 4; ++i)
#pragma unroll
        for (int j = 0; j < 4; ++j) acc[i][j] = (f32x4){0.f, 0.f, 0.f, 0.f};

    const bf16_t* gA = A + (size_t)(bm + wave * 16 + lrow) * lda + lkb;
    const bf16_t* gB = B + (size_t)(bn + wave * 16 + lrow) * ldb + lkb;
    bf16_t* lA = &As[(wave * 16 + lrow) * GBK + lkb];
    bf16_t* lB = &Bs[(wave * 16 + lrow) * GBK + lkb];

    for (int k0 = 0; k0 < K; k0 += GBK) {
        __syncthreads();
        async_copy16(gA + k0, lA);
        async_copy16(gA + (size_t)64 * lda + k0, lA + 64 * GBK);
        async_copy16(gB + k0, lB);
        async_copy16(gB + (size_t)64 * ldb + k0, lB + 64 * GBK);
        __syncthreads();

        bf16x8 a[4], b[4];
#pragma unroll
        for (int mt = 0; mt < 4; ++mt)
            a[mt] = *(const bf16x8*)&As[(wm + mt * 16 + l16) * GBK + quad * 8];
#pragma unroll
        for (int nt = 0; nt < 4; ++nt)
            b[nt] = *(const bf16x8*)&Bs[(wn + nt * 16 + l16) * GBK + quad * 8];
#pragma unroll
        for (int mt = 0; mt < 4; ++mt)
#pragma unroll
            for (int nt = 0; nt < 4; ++nt)
                acc[mt][nt] = __builtin_amdgcn_mfma_f32_16x16x32_bf16(a[mt], b[nt], acc[mt][nt], 0, 0, 0);
    }

#pragma unroll
    for (int mt = 0; mt < 4; ++mt)
#pragma unroll
        for (int r = 0; r < 4; ++r) {
            int row = bm + wm + mt * 16 + quad * 4 + r;
            float* crow = C + (size_t)row * ldc + bn + wn;
#pragma unroll
            for (int nt = 0; nt < 4; ++nt)
                crow[nt * 16 + l16] = acc[mt][nt][r];
        }
}

// ---------------------------------------------------------------------------
// fp32 split-K GEMM for the gate-critical info MLP.
// M=2048, N=512, K=2048 split into 4 slices of 512. Grid (4,16,4) = 256
// blocks. Partials: Cpart[s][m][n] (ldc=512). Padded LDS (+4) kills the
// 4-way staging-store bank conflicts of R4's gemm_nt.
// ---------------------------------------------------------------------------
#define BM 128
#define BN 128
#define BK 16

__device__ __forceinline__ float gelu_exact(float v) {
    return 0.5f * v * (1.0f + erff(v * 0.70710678118654752f));
}

__global__ __launch_bounds__(256)
void info_gemm_splitk(const float* __restrict__ A, const float* __restrict__ B,
                      float* __restrict__ Cpart) {
    __shared__ float As[BK][BM + 4];
    __shared__ float Bs[BK][BN + 4];
    const int tid = threadIdx.x;
    const int bm = blockIdx.y * BM;
    const int bn = blockIdx.x * BN;
    const int ks = blockIdx.z;              // K-slice 0..3
    const int ty = tid >> 4;
    const int tx = tid & 15;

    float acc[8][8];
#pragma unroll
    for (int i = 0; i < 8; ++i)
#pragma unroll
        for (int j = 0; j < 8; ++j) acc[i][j] = 0.f;

    const int kbeg = ks * 512, kend = kbeg + 512;
    for (int k0 = kbeg; k0 < kend; k0 += BK) {
#pragma unroll
        for (int l = tid; l < (BM * BK) / 4; l += 256) {
            int row = l >> 2, c4 = (l & 3) << 2;
            float4 v = *(const float4*)(A + (size_t)(bm + row) * 2048 + k0 + c4);
            As[c4 + 0][row] = v.x; As[c4 + 1][row] = v.y;
            As[c4 + 2][row] = v.z; As[c4 + 3][row] = v.w;
        }
#pragma unroll
        for (int l = tid; l < (BN * BK) / 4; l += 256) {
            int row = l >> 2, c4 = (l & 3) << 2;
            float4 v = *(const float4*)(B + (size_t)(bn + row) * 2048 + k0 + c4);
            Bs[c4 + 0][row] = v.x; Bs[c4 + 1][row] = v.y;
            Bs[c4 + 2][row] = v.z; Bs[c4 + 3][row] = v.w;
        }
        __syncthreads();
#pragma unroll
        for (int kk = 0; kk < BK; ++kk) {
            float a[8], b[8];
#pragma unroll
            for (int i = 0; i < 8; ++i) a[i] = As[kk][ty * 8 + i];
#pragma unroll
            for (int j = 0; j < 8; ++j) b[j] = Bs[kk][tx * 8 + j];
#pragma unroll
            for (int i = 0; i < 8; ++i)
#pragma unroll
                for (int j = 0; j < 8; ++j) acc[i][j] += a[i] * b[j];
        }
        __syncthreads();
    }
    float* cp = Cpart + (size_t)ks * 2048 * 512;
#pragma unroll
    for (int i = 0; i < 8; ++i) {
        size_t rowoff = (size_t)(bm + ty * 8 + i) * 512 + bn + tx * 8;
#pragma unroll
        for (int j = 0; j < 8; ++j) cp[rowoff + j] = acc[i][j];
    }
}

// reduce 4 partials + gelu -> h_info. Fixed order (deterministic).
__global__ __launch_bounds__(256)
void info_reduce_kernel(const float* __restrict__ Cpart, float* __restrict__ h) {
    int idx = blockIdx.x * 256 + threadIdx.x;   // over 1048576/4 float4s
    const f32x4* p = (const f32x4*)Cpart;
    f32x4 a = p[idx];
    f32x4 b = p[idx + 262144];
    f32x4 c = p[idx + 524288];
    f32x4 d = p[idx + 786432];
    f32x4 r;
#pragma unroll
    for (int i = 0; i < 4; ++i) r[i] = gelu_exact(((a[i] + b[i]) + c[i]) + d[i]);
    ((f32x4*)h)[idx] = r;
}

// ---------------------------------------------------------------------------
// RoPE tables: tab[t*128 + j] = cos(t*invf[j]), tab[t*128 + 64 + j] = sin(...)
// ---------------------------------------------------------------------------
__global__ __launch_bounds__(256)
void rope_table_kernel(float* __restrict__ tab) {
    int idx = blockIdx.x * 256 + threadIdx.x;   // 2048*64
    int t = idx >> 6, j = idx & 63;
    float inv = expf(-(float)j * LOG1E4_OVER_64);
    float s, c;
    sincosf((float)t * inv, &s, &c);
    tab[t * 128 + j] = c;
    tab[t * 128 + 64 + j] = s;
}

// RoPE apply on cols [0,4096) of qkv (q and k regions), 8 elems/thread.
__global__ __launch_bounds__(256)
void rope_apply_kernel(float* __restrict__ qkv, const float* __restrict__ tab) {
    int idx = blockIdx.x * 256 + threadIdx.x;   // 2048 rows * 512 thr/row
    int t = idx >> 9;
    int c = (idx & 511) << 3;
    float* row = qkv + (size_t)t * QKV_LD + c;
    const float* tr = tab + t * 128;
    float4 a = *(const float4*)row;
    float4 b = *(const float4*)(row + 4);
    float xs[8] = {a.x, a.y, a.z, a.w, b.x, b.y, b.z, b.w};
    int d0 = c & 127;
    float ys[8];
#pragma unroll
    for (int m = 0; m < 4; ++m) {
        int j0 = (d0 + 2 * m) & 63;
        float c0 = tr[j0], s0 = tr[64 + j0];
        float c1 = tr[j0 + 1], s1 = tr[64 + j0 + 1];
        float x0 = xs[2 * m], x1 = xs[2 * m + 1];
        ys[2 * m]     = x0 * c0 - x1 * s0;
        ys[2 * m + 1] = x1 * c1 + x0 * s1;
    }
    *(float4*)row       = make_float4(ys[0], ys[1], ys[2], ys[3]);
    *(float4*)(row + 4) = make_float4(ys[4], ys[5], ys[6], ys[7]);
}

// ---------------------------------------------------------------------------
// Gate (fp32 path, exact)
// ---------------------------------------------------------------------------
__global__ void gate_kernel(const float* __restrict__ h_info,
                            const float* __restrict__ w2,
                            float* __restrict__ gate) {
    const int t = blockIdx.x;
    const int lane = threadIdx.x;
    float s = 0.f;
    for (int i = lane; i < 512; i += 64) s += h_info[(size_t)t * 512 + i] * w2[i];
#pragma unroll
    for (int off = 32; off > 0; off >>= 1) s += __shfl_down(s, off);
    if (lane == 0) {
        float sig = 1.f / (1.f + expf(-s));
        gate[t] = (sig > 0.75f) ? 1.f : 0.f;
    }
}

// ---------------------------------------------------------------------------
// MFMA kvr: per block (64 s x head h): kr = K pk^T, vr = V pv^T, qr = Q pk^T.
// ---------------------------------------------------------------------------
#define KV_LD 136

__global__ __launch_bounds__(256)
void kvr_mfma_kernel(const float* __restrict__ qkv,
                     const float* __restrict__ pk, const float* __restrict__ pv,
                     float* __restrict__ kr, float* __restrict__ vr,
                     bf16_t* __restrict__ qr) {
    __shared__ bf16_t Kt[64 * KV_LD];
    __shared__ bf16_t Vt[64 * KV_LD];
    __shared__ bf16_t Qt[64 * KV_LD];
    __shared__ bf16_t Pk[64 * KV_LD];
    __shared__ bf16_t Pv[64 * KV_LD];

    const int h = blockIdx.y;
    const int s0 = blockIdx.x * 64;
    const int tid = threadIdx.x;
    const int wave = tid >> 6, lane = tid & 63;
    const int quad = lane >> 4, l16 = lane & 15;

#pragma unroll
    for (int i = 0; i < 8; ++i) {
        int gid = i * 256 + tid;
        int row = gid >> 5, c = (gid & 31) << 2;
        const float* base = qkv + (size_t)(s0 + row) * QKV_LD + h * HD + c;
        float4 vq = *(const float4*)base;
        float4 vk = *(const float4*)(base + 2048);
        float4 vv = *(const float4*)(base + 4096);
        bf16x4 pq, pkk, pvv;
        pq[0] = (bf16_t)vq.x; pq[1] = (bf16_t)vq.y; pq[2] = (bf16_t)vq.z; pq[3] = (bf16_t)vq.w;
        pkk[0] = (bf16_t)vk.x; pkk[1] = (bf16_t)vk.y; pkk[2] = (bf16_t)vk.z; pkk[3] = (bf16_t)vk.w;
        pvv[0] = (bf16_t)vv.x; pvv[1] = (bf16_t)vv.y; pvv[2] = (bf16_t)vv.z; pvv[3] = (bf16_t)vv.w;
        *(bf16x4*)&Qt[row * KV_LD + c] = pq;
        *(bf16x4*)&Kt[row * KV_LD + c] = pkk;
        *(bf16x4*)&Vt[row * KV_LD + c] = pvv;
        float4 wk = *(const float4*)(pk + (size_t)row * HD + c);
        float4 wv = *(const float4*)(pv + (size_t)row * HD + c);
        bf16x4 qk4, qv4;
        qk4[0] = (bf16_t)wk.x; qk4[1] = (bf16_t)wk.y; qk4[2] = (bf16_t)wk.z; qk4[3] = (bf16_t)wk.w;
        qv4[0] = (bf16_t)wv.x; qv4[1] = (bf16_t)wv.y; qv4[2] = (bf16_t)wv.z; qv4[3] = (bf16_t)wv.w;
        *(bf16x4*)&Pk[row * KV_LD + c] = qk4;
        *(bf16x4*)&Pv[row * KV_LD + c] = qv4;
    }
    __syncthreads();

    f32x4 ak[4], av[4], aq[4];
#pragma unroll
    for (int nt = 0; nt < 4; ++nt) {
        ak[nt] = (f32x4){0.f, 0.f, 0.f, 0.f};
        av[nt] = (f32x4){0.f, 0.f, 0.f, 0.f};
        aq[nt] = (f32x4){0.f, 0.f, 0.f, 0.f};
    }

#pragma unroll
    for (int ks = 0; ks < 4; ++ks) {
        const int ao = (wave * 16 + l16) * KV_LD + ks * 32 + quad * 8;
        bf16x8 a_k = *(const bf16x8*)&Kt[ao];
        bf16x8 a_v = *(const bf16x8*)&Vt[ao];
        bf16x8 a_q = *(const bf16x8*)&Qt[ao];
#pragma unroll
        for (int nt = 0; nt < 4; ++nt) {
            const int bo = (nt * 16 + l16) * KV_LD + ks * 32 + quad * 8;
            bf16x8 bk = *(const bf16x8*)&Pk[bo];
            bf16x8 bv = *(const bf16x8*)&Pv[bo];
            ak[nt] = __builtin_amdgcn_mfma_f32_16x16x32_bf16(a_k, bk, ak[nt], 0, 0, 0);
            av[nt] = __builtin_amdgcn_mfma_f32_16x16x32_bf16(a_v, bv, av[nt], 0, 0, 0);
            aq[nt] = __builtin_amdgcn_mfma_f32_16x16x32_bf16(a_q, bk, aq[nt], 0, 0, 0);
        }
    }

#pragma unroll
    for (int nt = 0; nt < 4; ++nt)
#pragma unroll
        for (int r = 0; r < 4; ++r) {
            int s = s0 + wave * 16 + quad * 4 + r;
            size_t idx = ((size_t)h * T_LEN + s) * RANK + nt * 16 + l16;
            kr[idx] = ak[nt][r];
            vr[idx] = av[nt][r];
            qr[idx] = (bf16_t)aq[nt][r];
        }
}

// ---------------------------------------------------------------------------
// MFMA bf16 flash local attention (unchanged, verified)
// ---------------------------------------------------------------------------
#define QTI 64
#define KTI 64
#define QS_LD 136
#define VT_LD 68
#define PS_LD 72

__global__ __launch_bounds__(256)
void local_attn_kernel(float* __restrict__ qkv) {
    __shared__ bf16_t Qs[QTI * QS_LD];
    __shared__ bf16_t Ks[KTI * QS_LD];
    __shared__ bf16_t Vt[HD * VT_LD];
    __shared__ bf16_t Ps[4][16 * PS_LD];

    const int h = blockIdx.y;
    const int t0 = blockIdx.x * QTI;
    const int tid = threadIdx.x;
    const int wave = tid >> 6, lane = tid & 63;
    const int quad = lane >> 4, l16 = lane & 15;

#pragma unroll
    for (int i = 0; i < 8; ++i) {
        int gid = i * 256 + tid;
        int row = gid >> 5, c4 = (gid & 31) << 2;
        const float4 v = *(const float4*)(qkv + (size_t)(t0 + row) * QKV_LD + h * HD + c4);
        bf16x4 p;
        p[0] = (bf16_t)(v.x * SCALE); p[1] = (bf16_t)(v.y * SCALE);
        p[2] = (bf16_t)(v.z * SCALE); p[3] = (bf16_t)(v.w * SCALE);
        *(bf16x4*)&Qs[row * QS_LD + c4] = p;
    }

    f32x4 o[8];
#pragma unroll
    for (int d8 = 0; d8 < 8; ++d8) o[d8] = (f32x4){0.f, 0.f, 0.f, 0.f};
    float m_i[4] = {-1e30f, -1e30f, -1e30f, -1e30f};
    float l_i[4] = {0.f, 0.f, 0.f, 0.f};

    __syncthreads();

    for (int kt = 0; kt < 9; ++kt) {
        const int sbase = t0 - 512 + kt * KTI;
        if (sbase < 0) continue;
        __syncthreads();
#pragma unroll
        for (int i = 0; i < 8; ++i) {
            int gid = i * 256 + tid;
            int row = gid >> 5, c4 = (gid & 31) << 2;
            const float* base = qkv + (size_t)(sbase + row) * QKV_LD + h * HD + c4;
            const float4 kv = *(const float4*)(base + 2048);
            bf16x4 pk4;
            pk4[0] = (bf16_t)kv.x; pk4[1] = (bf16_t)kv.y;
            pk4[2] = (bf16_t)kv.z; pk4[3] = (bf16_t)kv.w;
            *(bf16x4*)&Ks[row * QS_LD + c4] = pk4;
            const float4 vv = *(const float4*)(base + 4096);
            Vt[(c4 + 0) * VT_LD + row] = (bf16_t)vv.x;
            Vt[(c4 + 1) * VT_LD + row] = (bf16_t)vv.y;
            Vt[(c4 + 2) * VT_LD + row] = (bf16_t)vv.z;
            Vt[(c4 + 3) * VT_LD + row] = (bf16_t)vv.w;
        }
        __syncthreads();

        f32x4 sacc[4];
#pragma unroll
        for (int nt = 0; nt < 4; ++nt) sacc[nt] = (f32x4){0.f, 0.f, 0.f, 0.f};
#pragma unroll
        for (int ks = 0; ks < 4; ++ks) {
            bf16x8 a = *(const bf16x8*)&Qs[(wave * 16 + l16) * QS_LD + ks * 32 + quad * 8];
#pragma unroll
            for (int nt = 0; nt < 4; ++nt) {
                bf16x8 b = *(const bf16x8*)&Ks[(nt * 16 + l16) * QS_LD + ks * 32 + quad * 8];
                sacc[nt] = __builtin_amdgcn_mfma_f32_16x16x32_bf16(a, b, sacc[nt], 0, 0, 0);
            }
        }

#pragma unroll
        for (int nt = 0; nt < 4; ++nt) {
            int s_g = sbase + nt * 16 + l16;
#pragma unroll
            for (int r = 0; r < 4; ++r) {
                int t_g = t0 + wave * 16 + quad * 4 + r;
                bool valid = (s_g <= t_g) && (s_g + W_LOCAL > t_g);
                if (!valid) sacc[nt][r] = -1e30f;
            }
        }

#pragma unroll
        for (int r = 0; r < 4; ++r) {
            float mx = fmaxf(fmaxf(sacc[0][r], sacc[1][r]), fmaxf(sacc[2][r], sacc[3][r]));
            mx = fmaxf(mx, __shfl_xor(mx, 1));
            mx = fmaxf(mx, __shfl_xor(mx, 2));
            mx = fmaxf(mx, __shfl_xor(mx, 4));
            mx = fmaxf(mx, __shfl_xor(mx, 8));
            float mnew = fmaxf(m_i[r], mx);
            float alpha = __expf(m_i[r] - mnew);
            m_i[r] = mnew;
            float rs = 0.f;
#pragma unroll
            for (int nt = 0; nt < 4; ++nt) {
                float p = __expf(sacc[nt][r] - mnew);
                sacc[nt][r] = p;
                rs += p;
            }
            rs += __shfl_xor(rs, 1);
            rs += __shfl_xor(rs, 2);
            rs += __shfl_xor(rs, 4);
            rs += __shfl_xor(rs, 8);
            l_i[r] = l_i[r] * alpha + rs;
#pragma unroll
            for (int d8 = 0; d8 < 8; ++d8) o[d8][r] *= alpha;
        }

#pragma unroll
        for (int r = 0; r < 4; ++r)
#pragma unroll
            for (int nt = 0; nt < 4; ++nt)
                Ps[wave][(quad * 4 + r) * PS_LD + nt * 16 + l16] = (bf16_t)sacc[nt][r];

#pragma unroll
        for (int ks2 = 0; ks2 < 2; ++ks2) {
            bf16x8 a = *(const bf16x8*)&Ps[wave][l16 * PS_LD + ks2 * 32 + quad * 8];
#pragma unroll
            for (int d8 = 0; d8 < 8; ++d8) {
                const bf16_t* vb = &Vt[(d8 * 16 + l16) * VT_LD + ks2 * 32 + quad * 8];
                bf16x4 b0 = *(const bf16x4*)vb;
                bf16x4 b1 = *(const bf16x4*)(vb + 4);
                bf16x8 b;
                b[0] = b0[0]; b[1] = b0[1]; b[2] = b0[2]; b[3] = b0[3];
                b[4] = b1[0]; b[5] = b1[1]; b[6] = b1[2]; b[7] = b1[3];
                o[d8] = __builtin_amdgcn_mfma_f32_16x16x32_bf16(a, b, o[d8], 0, 0, 0);
            }
        }
    }

#pragma unroll
    for (int r = 0; r < 4; ++r) {
        float inv = 1.0f / l_i[r];
        size_t rowoff = (size_t)(t0 + wave * 16 + quad * 4 + r) * QKV_LD + h * HD;
#pragma unroll
        for (int d8 = 0; d8 < 8; ++d8)
            qkv[rowoff + d8 * 16 + l16] = o[d8][r] * inv;
    }
}

// ---------------------------------------------------------------------------
// Gated global low-rank branch (early-exit when gate==0)
// ---------------------------------------------------------------------------
__device__ __forceinline__ float block_reduce_max512(float v, float* red, int tid) {
    red[tid] = v; __syncthreads();
    for (int s = 256; s > 0; s >>= 1) {
        if (tid < s) red[tid] = fmaxf(red[tid], red[tid + s]);
        __syncthreads();
    }
    float r = red[0]; __syncthreads();
    return r;
}
__device__ __forceinline__ float block_reduce_sum512(float v, float* red, int tid) {
    red[tid] = v; __syncthreads();
    for (int s = 256; s > 0; s >>= 1) {
        if (tid < s) red[tid] = red[tid] + red[tid + s];
        __syncthreads();
    }
    float r = red[0]; __syncthreads();
    return r;
}

__global__ __launch_bounds__(512)
void global_attn_kernel(float* __restrict__ qkv, const float* __restrict__ kr,
                        const float* __restrict__ vr, const bf16_t* __restrict__ qr,
                        const float* __restrict__ uo, const float* __restrict__ gate) {
    const int t = blockIdx.x, h = blockIdx.y;
    if (gate[t] <= 0.5f) return;

    __shared__ float qrs[64];
    __shared__ float red[512];
    __shared__ float cgr[64];
    __shared__ float sg[2048];
    const int tid = threadIdx.x;

    if (tid < 64) qrs[tid] = (float)qr[((size_t)h * T_LEN + t) * RANK + tid];
    __syncthreads();

    const float* krh = kr + (size_t)h * T_LEN * RANK;
    const float* vrh = vr + (size_t)h * T_LEN * RANK;
    float lmax = -INFINITY;
    for (int s = tid; s < T_LEN; s += 512) {
        const float* krr = krh + (size_t)s * RANK;
        float acc = 0.f;
#pragma unroll
        for (int r = 0; r < RANK; r += 4) {
            float4 k4 = *(const float4*)(krr + r);
            acc += qrs[r] * k4.x + qrs[r + 1] * k4.y + qrs[r + 2] * k4.z + qrs[r + 3] * k4.w;
        }
        float sc = acc * SCALE_G;
        sg[s] = sc;
        lmax = fmaxf(lmax, sc);
    }
    float gmx = block_reduce_max512(lmax, red, tid);
    float lsum = 0.f;
    for (int s = tid; s < T_LEN; s += 512) {
        float pp = expf(sg[s] - gmx);
        sg[s] = pp;
        lsum += pp;
    }
    float gsum = block_reduce_sum512(lsum, red, tid);

    {
        const int r = tid & 63, part = tid >> 6;
        float pacc = 0.f;
        for (int s = part; s < T_LEN; s += 8) pacc += sg[s] * vrh[(size_t)s * RANK + r];
        red[tid] = pacc;
        __syncthreads();
        if (tid < 64) {
            float c = 0.f;
#pragma unroll
            for (int pp = 0; pp < 8; ++pp) c += red[pp * 64 + tid];
            cgr[tid] = c / gsum;
        }
        __syncthreads();
    }

    if (tid < 128) {
        float cg = 0.f;
#pragma unroll
        for (int r = 0; r < RANK; ++r) cg += cgr[r] * uo[tid * RANK + r];
        qkv[(size_t)t * QKV_LD + h * HD + tid] += cg;
    }
}

// ---------------------------------------------------------------------------
extern "C" void kernel_launch(void* const* d_in, const int* in_sizes, int n_in,
                              void* d_out, int out_size, void* d_ws, size_t ws_size,
                              hipStream_t stream) {
    const float* x     = (const float*)d_in[0];
    const float* w_qkv = (const float*)d_in[1];
    const float* w_o   = (const float*)d_in[2];
    const float* pk    = (const float*)d_in[3];
    const float* pv    = (const float*)d_in[4];
    const float* uo    = (const float*)d_in[5];
    const float* w1    = (const float*)d_in[6];
    const float* w2    = (const float*)d_in[7];
    float* out = (float*)d_out;

    // Workspace layout (floats), lifetime-aliased (~84 MB):
    float* ws = (float*)d_ws;
    float* qkv   = ws;                        // 12,582,912 f (first 4.2M: info partials)
    float* hinfo = qkv + (size_t)12582912;    // 1,048,576 f (later qr bf16)
    float* gatep = hinfo + (size_t)1048576;   // 2048 f
    bf16_t* xb   = (bf16_t*)(gatep + 2048);   // 2048*2048 bf16 (later ctx_bf)
    float* wqbf  = gatep + 2048 + 2097152;    // 6,291,456 f region:
    bf16_t* wqb  = (bf16_t*)wqbf;             //   w_qkv bf16 (6144*2048)
    float* krp   = wqbf;                      //   later: kr (2,097,152 f)
    float* vrp   = wqbf + (size_t)2097152;    //   later: vr (2,097,152 f)
    float* tabp  = wqbf + (size_t)4194304;    //   later: rope tables (262,144 f)
    bf16_t* wob  = (bf16_t*)krp;              //   later still: w_o bf16
    bf16_t* qrp  = (bf16_t*)hinfo;            // qr bf16
    bf16_t* cxb  = xb;                        // ctx bf16
    float* ipart = qkv;                       // info partials 4×2048×512 (dead before qkv GEMM)

    // 1) info MLP (fp32, gate-critical): split-K partials -> reduce+gelu -> gate
    info_gemm_splitk<<<dim3(4, 16, 4), 256, 0, stream>>>(x, w1, ipart);
    info_reduce_kernel<<<1024, 256, 0, stream>>>(ipart, hinfo);
    gate_kernel<<<T_LEN, 64, 0, stream>>>(hinfo, w2, gatep);
    // 2) convert x, w_qkv to bf16
    conv_f32_bf16<<<2048, 256, 0, stream>>>(x, xb, 2048, 2048, 2048);
    conv_f32_bf16<<<6144, 256, 0, stream>>>(w_qkv, wqb, 2048, 2048, 6144);
    // 3) qkv = x @ w_qkv^T  (bf16 MFMA; overwrites dead info partials)
    gemm_bf16_nt<<<dim3(48, 16), 256, 0, stream>>>(xb, wqb, qkv, 2048, 2048, 2048, QKV_LD);
    // 4) RoPE: table (aliases dead wqb tail), then apply
    rope_table_kernel<<<512, 256, 0, stream>>>(tabp);
    rope_apply_kernel<<<4096, 256, 0, stream>>>(qkv, tabp);
    // 5) k_r, v_r, q_r via MFMA (kr/vr overwrite dead wqb; qr overwrites dead hinfo)
    kvr_mfma_kernel<<<dim3(T_LEN / 64, NH), 256, 0, stream>>>(qkv, pk, pv, krp, vrp, qrp);
    // 6) flash local attention -> ctx (over q region)
    local_attn_kernel<<<dim3(T_LEN / QTI, NH), 256, 0, stream>>>(qkv);
    // 7) gated global branch (adds into ctx)
    global_attn_kernel<<<dim3(T_LEN, NH), 512, 0, stream>>>(qkv, krp, vrp, qrp, uo, gatep);
    // 8) convert ctx -> bf16, w_o -> bf16
    conv_f32_bf16<<<2048, 256, 0, stream>>>(qkv, cxb, QKV_LD, 2048, 2048);
    conv_f32_bf16<<<2048, 256, 0, stream>>>(w_o, wob, 2048, 2048, 2048);
    // 9) out = ctx @ w_o^T  (bf16 MFMA)
    gemm_bf16_nt<<<dim3(16, 16), 256, 0, stream>>>(cxb, wob, out, 2048, 2048, 2048, 2048);
}

// Round 6
// 394.313 us; speedup vs baseline: 9.8531x; 1.1161x over previous
//
#include <hip/hip_runtime.h>
#include <hip/hip_bf16.h>
#include <math.h>

// Problem constants
#define T_LEN 2048
#define C_DIM 2048
#define NH 16
#define HD 128
#define RANK 64
#define W_LOCAL 512
#define QKV_LD 6144
#define SCALE 0.08838834764831845f    // 1/sqrt(128)
#define SCALE_G 0.17677669529663687f  // scale * 128/64
#define LOG1E4_OVER_64 0.14391156831212787f

typedef __bf16 bf16_t;
typedef __bf16 bf16x8 __attribute__((ext_vector_type(8)));
typedef __bf16 bf16x4 __attribute__((ext_vector_type(4)));
typedef float f32x4 __attribute__((ext_vector_type(4)));

// ---------------------------------------------------------------------------
// async 16B global -> LDS (gfx950)
// ---------------------------------------------------------------------------
__device__ __forceinline__ void async_copy16(const bf16_t* g, bf16_t* l) {
    __builtin_amdgcn_global_load_lds(
        (const __attribute__((address_space(1))) unsigned int*)g,
        (__attribute__((address_space(3))) unsigned int*)l, 16, 0, 0);
}

// ---------------------------------------------------------------------------
// fp32 -> bf16 conversion, 8 elems/thread
// ---------------------------------------------------------------------------
__global__ __launch_bounds__(256)
void conv_f32_bf16(const float* __restrict__ in, bf16_t* __restrict__ out,
                   int ld_in, int cols, int rows) {
    int per_row = cols >> 3;
    int idx = blockIdx.x * 256 + threadIdx.x;
    if (idx >= rows * per_row) return;
    int row = idx / per_row, c = (idx - row * per_row) << 3;
    const float* p = in + (size_t)row * ld_in + c;
    float4 v0 = *(const float4*)p;
    float4 v1 = *(const float4*)(p + 4);
    bf16x8 o;
    o[0] = (bf16_t)v0.x; o[1] = (bf16_t)v0.y; o[2] = (bf16_t)v0.z; o[3] = (bf16_t)v0.w;
    o[4] = (bf16_t)v1.x; o[5] = (bf16_t)v1.y; o[6] = (bf16_t)v1.z; o[7] = (bf16_t)v1.w;
    *(bf16x8*)(out + (size_t)row * cols + c) = o;
}

// fp32 -> (hi, lo) split-bf16: hi = bf16(v), lo = bf16(v - hi). Flat array.
__global__ __launch_bounds__(256)
void conv_split_bf16(const float* __restrict__ in, bf16_t* __restrict__ hi,
                     bf16_t* __restrict__ lo, int n8) {
    int idx = blockIdx.x * 256 + threadIdx.x;
    if (idx >= n8) return;
    const float* p = in + (size_t)idx * 8;
    float4 v0 = *(const float4*)p;
    float4 v1 = *(const float4*)(p + 4);
    float v[8] = {v0.x, v0.y, v0.z, v0.w, v1.x, v1.y, v1.z, v1.w};
    bf16x8 h, l;
#pragma unroll
    for (int i = 0; i < 8; ++i) {
        bf16_t hb = (bf16_t)v[i];
        h[i] = hb;
        l[i] = (bf16_t)(v[i] - (float)hb);
    }
    *(bf16x8*)(hi + (size_t)idx * 8) = h;
    *(bf16x8*)(lo + (size_t)idx * 8) = l;
}

// ---------------------------------------------------------------------------
// bf16 MFMA GEMM (m97 recipe)
// ---------------------------------------------------------------------------
#define GBK 32

__global__ __launch_bounds__(256)
void gemm_bf16_nt(const bf16_t* __restrict__ A, const bf16_t* __restrict__ B,
                  float* __restrict__ C, int K, int lda, int ldb, int ldc) {
    __shared__ bf16_t As[128 * GBK];
    __shared__ bf16_t Bs[128 * GBK];
    const int tid = threadIdx.x;
    const int wave = tid >> 6, lane = tid & 63;
    const int quad = lane >> 4, l16 = lane & 15;
    const int bm = blockIdx.y * 128, bn = blockIdx.x * 128;
    const int wm = (wave >> 1) * 64, wn = (wave & 1) * 64;
    const int lrow = lane >> 2;
    const int lkb = (lane & 3) * 8;

    f32x4 acc[4][4];
#pragma unroll
    for (int i = 0; i < 4; ++i)
#pragma unroll
        for (int j = 0; j < 4; ++j) acc[i][j] = (f32x4){0.f, 0.f, 0.f, 0.f};

    const bf16_t* gA = A + (size_t)(bm + wave * 16 + lrow) * lda + lkb;
    const bf16_t* gB = B + (size_t)(bn + wave * 16 + lrow) * ldb + lkb;
    bf16_t* lA = &As[(wave * 16 + lrow) * GBK + lkb];
    bf16_t* lB = &Bs[(wave * 16 + lrow) * GBK + lkb];

    for (int k0 = 0; k0 < K; k0 += GBK) {
        __syncthreads();
        async_copy16(gA + k0, lA);
        async_copy16(gA + (size_t)64 * lda + k0, lA + 64 * GBK);
        async_copy16(gB + k0, lB);
        async_copy16(gB + (size_t)64 * ldb + k0, lB + 64 * GBK);
        __syncthreads();

        bf16x8 a[4], b[4];
#pragma unroll
        for (int mt = 0; mt < 4; ++mt)
            a[mt] = *(const bf16x8*)&As[(wm + mt * 16 + l16) * GBK + quad * 8];
#pragma unroll
        for (int nt = 0; nt < 4; ++nt)
            b[nt] = *(const bf16x8*)&Bs[(wn + nt * 16 + l16) * GBK + quad * 8];
#pragma unroll
        for (int mt = 0; mt < 4; ++mt)
#pragma unroll
            for (int nt = 0; nt < 4; ++nt)
                acc[mt][nt] = __builtin_amdgcn_mfma_f32_16x16x32_bf16(a[mt], b[nt], acc[mt][nt], 0, 0, 0);
    }

#pragma unroll
    for (int mt = 0; mt < 4; ++mt)
#pragma unroll
        for (int r = 0; r < 4; ++r) {
            int row = bm + wm + mt * 16 + quad * 4 + r;
            float* crow = C + (size_t)row * ldc + bn + wn;
#pragma unroll
            for (int nt = 0; nt < 4; ++nt)
                crow[nt * 16 + l16] = acc[mt][nt][r];
        }
}

// ---------------------------------------------------------------------------
// Split-bf16 (3x bf16-MFMA) GEMM for the gate-critical info MLP.
// C = A@B^T with A = Ahi+Alo, B = Bhi+Blo; computes hi*hi + hi*lo + lo*hi
// (lo*lo dropped: ~2^-16 relative — far below gate-flip risk).
// Split-K=4 (grid z), partials to Cpart[ks][2048][512], fp32.
// ---------------------------------------------------------------------------
__global__ __launch_bounds__(256)
void info_gemm_mfma(const bf16_t* __restrict__ Ahi, const bf16_t* __restrict__ Alo,
                    const bf16_t* __restrict__ Bhi, const bf16_t* __restrict__ Blo,
                    float* __restrict__ Cpart) {
    __shared__ bf16_t Ah[128 * GBK];
    __shared__ bf16_t Al[128 * GBK];
    __shared__ bf16_t Bh[128 * GBK];
    __shared__ bf16_t Bl[128 * GBK];
    const int tid = threadIdx.x;
    const int wave = tid >> 6, lane = tid & 63;
    const int quad = lane >> 4, l16 = lane & 15;
    const int bm = blockIdx.y * 128, bn = blockIdx.x * 128;
    const int ks = blockIdx.z;
    const int wm = (wave >> 1) * 64, wn = (wave & 1) * 64;
    const int lrow = lane >> 2;
    const int lkb = (lane & 3) * 8;
    const int kbeg = ks * 512;

    f32x4 acc[4][4];
#pragma unroll
    for (int i = 0; i < 4; ++i)
#pragma unroll
        for (int j = 0; j < 4; ++j) acc[i][j] = (f32x4){0.f, 0.f, 0.f, 0.f};

    const size_t aoff = (size_t)(bm + wave * 16 + lrow) * 2048 + lkb + kbeg;
    const size_t boff = (size_t)(bn + wave * 16 + lrow) * 2048 + lkb + kbeg;
    bf16_t* lAh = &Ah[(wave * 16 + lrow) * GBK + lkb];
    bf16_t* lAl = &Al[(wave * 16 + lrow) * GBK + lkb];
    bf16_t* lBh = &Bh[(wave * 16 + lrow) * GBK + lkb];
    bf16_t* lBl = &Bl[(wave * 16 + lrow) * GBK + lkb];

    for (int k0 = 0; k0 < 512; k0 += GBK) {
        __syncthreads();
        async_copy16(Ahi + aoff + k0, lAh);
        async_copy16(Ahi + aoff + (size_t)64 * 2048 + k0, lAh + 64 * GBK);
        async_copy16(Alo + aoff + k0, lAl);
        async_copy16(Alo + aoff + (size_t)64 * 2048 + k0, lAl + 64 * GBK);
        async_copy16(Bhi + boff + k0, lBh);
        async_copy16(Bhi + boff + (size_t)64 * 2048 + k0, lBh + 64 * GBK);
        async_copy16(Blo + boff + k0, lBl);
        async_copy16(Blo + boff + (size_t)64 * 2048 + k0, lBl + 64 * GBK);
        __syncthreads();

        bf16x8 ah[4], al[4], bh[4], bl[4];
#pragma unroll
        for (int mt = 0; mt < 4; ++mt) {
            ah[mt] = *(const bf16x8*)&Ah[(wm + mt * 16 + l16) * GBK + quad * 8];
            al[mt] = *(const bf16x8*)&Al[(wm + mt * 16 + l16) * GBK + quad * 8];
        }
#pragma unroll
        for (int nt = 0; nt < 4; ++nt) {
            bh[nt] = *(const bf16x8*)&Bh[(wn + nt * 16 + l16) * GBK + quad * 8];
            bl[nt] = *(const bf16x8*)&Bl[(wn + nt * 16 + l16) * GBK + quad * 8];
        }
#pragma unroll
        for (int mt = 0; mt < 4; ++mt)
#pragma unroll
            for (int nt = 0; nt < 4; ++nt) {
                acc[mt][nt] = __builtin_amdgcn_mfma_f32_16x16x32_bf16(ah[mt], bh[nt], acc[mt][nt], 0, 0, 0);
                acc[mt][nt] = __builtin_amdgcn_mfma_f32_16x16x32_bf16(ah[mt], bl[nt], acc[mt][nt], 0, 0, 0);
                acc[mt][nt] = __builtin_amdgcn_mfma_f32_16x16x32_bf16(al[mt], bh[nt], acc[mt][nt], 0, 0, 0);
            }
    }

    float* cp = Cpart + (size_t)ks * 2048 * 512;
#pragma unroll
    for (int mt = 0; mt < 4; ++mt)
#pragma unroll
        for (int r = 0; r < 4; ++r) {
            int row = bm + wm + mt * 16 + quad * 4 + r;
            float* crow = cp + (size_t)row * 512 + bn + wn;
#pragma unroll
            for (int nt = 0; nt < 4; ++nt)
                crow[nt * 16 + l16] = acc[mt][nt][r];
        }
}

__device__ __forceinline__ float gelu_exact(float v) {
    return 0.5f * v * (1.0f + erff(v * 0.70710678118654752f));
}

// reduce 4 partials + gelu -> h_info. Fixed order (deterministic).
__global__ __launch_bounds__(256)
void info_reduce_kernel(const float* __restrict__ Cpart, float* __restrict__ h) {
    int idx = blockIdx.x * 256 + threadIdx.x;   // over 1048576/4 float4s
    const f32x4* p = (const f32x4*)Cpart;
    f32x4 a = p[idx];
    f32x4 b = p[idx + 262144];
    f32x4 c = p[idx + 524288];
    f32x4 d = p[idx + 786432];
    f32x4 r;
#pragma unroll
    for (int i = 0; i < 4; ++i) r[i] = gelu_exact(((a[i] + b[i]) + c[i]) + d[i]);
    ((f32x4*)h)[idx] = r;
}

// ---------------------------------------------------------------------------
// RoPE tables: tab[t*128 + j] = cos(t*invf[j]), tab[t*128 + 64 + j] = sin(...)
// ---------------------------------------------------------------------------
__global__ __launch_bounds__(256)
void rope_table_kernel(float* __restrict__ tab) {
    int idx = blockIdx.x * 256 + threadIdx.x;   // 2048*64
    int t = idx >> 6, j = idx & 63;
    float inv = expf(-(float)j * LOG1E4_OVER_64);
    float s, c;
    sincosf((float)t * inv, &s, &c);
    tab[t * 128 + j] = c;
    tab[t * 128 + 64 + j] = s;
}

// RoPE apply on cols [0,4096) of qkv (q and k regions), 8 elems/thread.
__global__ __launch_bounds__(256)
void rope_apply_kernel(float* __restrict__ qkv, const float* __restrict__ tab) {
    int idx = blockIdx.x * 256 + threadIdx.x;   // 2048 rows * 512 thr/row
    int t = idx >> 9;
    int c = (idx & 511) << 3;
    float* row = qkv + (size_t)t * QKV_LD + c;
    const float* tr = tab + t * 128;
    float4 a = *(const float4*)row;
    float4 b = *(const float4*)(row + 4);
    float xs[8] = {a.x, a.y, a.z, a.w, b.x, b.y, b.z, b.w};
    int d0 = c & 127;
    float ys[8];
#pragma unroll
    for (int m = 0; m < 4; ++m) {
        int j0 = (d0 + 2 * m) & 63;
        float c0 = tr[j0], s0 = tr[64 + j0];
        float c1 = tr[j0 + 1], s1 = tr[64 + j0 + 1];
        float x0 = xs[2 * m], x1 = xs[2 * m + 1];
        ys[2 * m]     = x0 * c0 - x1 * s0;
        ys[2 * m + 1] = x1 * c1 + x0 * s1;
    }
    *(float4*)row       = make_float4(ys[0], ys[1], ys[2], ys[3]);
    *(float4*)(row + 4) = make_float4(ys[4], ys[5], ys[6], ys[7]);
}

// ---------------------------------------------------------------------------
// Gate (fp32 path, exact)
// ---------------------------------------------------------------------------
__global__ void gate_kernel(const float* __restrict__ h_info,
                            const float* __restrict__ w2,
                            float* __restrict__ gate) {
    const int t = blockIdx.x;
    const int lane = threadIdx.x;
    float s = 0.f;
    for (int i = lane; i < 512; i += 64) s += h_info[(size_t)t * 512 + i] * w2[i];
#pragma unroll
    for (int off = 32; off > 0; off >>= 1) s += __shfl_down(s, off);
    if (lane == 0) {
        float sig = 1.f / (1.f + expf(-s));
        gate[t] = (sig > 0.75f) ? 1.f : 0.f;
    }
}

// ---------------------------------------------------------------------------
// MFMA kvr: per block (64 s x head h): kr = K pk^T, vr = V pv^T, qr = Q pk^T.
// ---------------------------------------------------------------------------
#define KV_LD 136

__global__ __launch_bounds__(256)
void kvr_mfma_kernel(const float* __restrict__ qkv,
                     const float* __restrict__ pk, const float* __restrict__ pv,
                     float* __restrict__ kr, float* __restrict__ vr,
                     bf16_t* __restrict__ qr) {
    __shared__ bf16_t Kt[64 * KV_LD];
    __shared__ bf16_t Vt[64 * KV_LD];
    __shared__ bf16_t Qt[64 * KV_LD];
    __shared__ bf16_t Pk[64 * KV_LD];
    __shared__ bf16_t Pv[64 * KV_LD];

    const int h = blockIdx.y;
    const int s0 = blockIdx.x * 64;
    const int tid = threadIdx.x;
    const int wave = tid >> 6, lane = tid & 63;
    const int quad = lane >> 4, l16 = lane & 15;

#pragma unroll
    for (int i = 0; i < 8; ++i) {
        int gid = i * 256 + tid;
        int row = gid >> 5, c = (gid & 31) << 2;
        const float* base = qkv + (size_t)(s0 + row) * QKV_LD + h * HD + c;
        float4 vq = *(const float4*)base;
        float4 vk = *(const float4*)(base + 2048);
        float4 vv = *(const float4*)(base + 4096);
        bf16x4 pq, pkk, pvv;
        pq[0] = (bf16_t)vq.x; pq[1] = (bf16_t)vq.y; pq[2] = (bf16_t)vq.z; pq[3] = (bf16_t)vq.w;
        pkk[0] = (bf16_t)vk.x; pkk[1] = (bf16_t)vk.y; pkk[2] = (bf16_t)vk.z; pkk[3] = (bf16_t)vk.w;
        pvv[0] = (bf16_t)vv.x; pvv[1] = (bf16_t)vv.y; pvv[2] = (bf16_t)vv.z; pvv[3] = (bf16_t)vv.w;
        *(bf16x4*)&Qt[row * KV_LD + c] = pq;
        *(bf16x4*)&Kt[row * KV_LD + c] = pkk;
        *(bf16x4*)&Vt[row * KV_LD + c] = pvv;
        float4 wk = *(const float4*)(pk + (size_t)row * HD + c);
        float4 wv = *(const float4*)(pv + (size_t)row * HD + c);
        bf16x4 qk4, qv4;
        qk4[0] = (bf16_t)wk.x; qk4[1] = (bf16_t)wk.y; qk4[2] = (bf16_t)wk.z; qk4[3] = (bf16_t)wk.w;
        qv4[0] = (bf16_t)wv.x; qv4[1] = (bf16_t)wv.y; qv4[2] = (bf16_t)wv.z; qv4[3] = (bf16_t)wv.w;
        *(bf16x4*)&Pk[row * KV_LD + c] = qk4;
        *(bf16x4*)&Pv[row * KV_LD + c] = qv4;
    }
    __syncthreads();

    f32x4 ak[4], av[4], aq[4];
#pragma unroll
    for (int nt = 0; nt < 4; ++nt) {
        ak[nt] = (f32x4){0.f, 0.f, 0.f, 0.f};
        av[nt] = (f32x4){0.f, 0.f, 0.f, 0.f};
        aq[nt] = (f32x4){0.f, 0.f, 0.f, 0.f};
    }

#pragma unroll
    for (int ks = 0; ks < 4; ++ks) {
        const int ao = (wave * 16 + l16) * KV_LD + ks * 32 + quad * 8;
        bf16x8 a_k = *(const bf16x8*)&Kt[ao];
        bf16x8 a_v = *(const bf16x8*)&Vt[ao];
        bf16x8 a_q = *(const bf16x8*)&Qt[ao];
#pragma unroll
        for (int nt = 0; nt < 4; ++nt) {
            const int bo = (nt * 16 + l16) * KV_LD + ks * 32 + quad * 8;
            bf16x8 bk = *(const bf16x8*)&Pk[bo];
            bf16x8 bv = *(const bf16x8*)&Pv[bo];
            ak[nt] = __builtin_amdgcn_mfma_f32_16x16x32_bf16(a_k, bk, ak[nt], 0, 0, 0);
            av[nt] = __builtin_amdgcn_mfma_f32_16x16x32_bf16(a_v, bv, av[nt], 0, 0, 0);
            aq[nt] = __builtin_amdgcn_mfma_f32_16x16x32_bf16(a_q, bk, aq[nt], 0, 0, 0);
        }
    }

#pragma unroll
    for (int nt = 0; nt < 4; ++nt)
#pragma unroll
        for (int r = 0; r < 4; ++r) {
            int s = s0 + wave * 16 + quad * 4 + r;
            size_t idx = ((size_t)h * T_LEN + s) * RANK + nt * 16 + l16;
            kr[idx] = ak[nt][r];
            vr[idx] = av[nt][r];
            qr[idx] = (bf16_t)aq[nt][r];
        }
}

// ---------------------------------------------------------------------------
// MFMA bf16 flash local attention (unchanged, verified)
// ---------------------------------------------------------------------------
#define QTI 64
#define KTI 64
#define QS_LD 136
#define VT_LD 68
#define PS_LD 72

__global__ __launch_bounds__(256)
void local_attn_kernel(float* __restrict__ qkv) {
    __shared__ bf16_t Qs[QTI * QS_LD];
    __shared__ bf16_t Ks[KTI * QS_LD];
    __shared__ bf16_t Vt[HD * VT_LD];
    __shared__ bf16_t Ps[4][16 * PS_LD];

    const int h = blockIdx.y;
    const int t0 = blockIdx.x * QTI;
    const int tid = threadIdx.x;
    const int wave = tid >> 6, lane = tid & 63;
    const int quad = lane >> 4, l16 = lane & 15;

#pragma unroll
    for (int i = 0; i < 8; ++i) {
        int gid = i * 256 + tid;
        int row = gid >> 5, c4 = (gid & 31) << 2;
        const float4 v = *(const float4*)(qkv + (size_t)(t0 + row) * QKV_LD + h * HD + c4);
        bf16x4 p;
        p[0] = (bf16_t)(v.x * SCALE); p[1] = (bf16_t)(v.y * SCALE);
        p[2] = (bf16_t)(v.z * SCALE); p[3] = (bf16_t)(v.w * SCALE);
        *(bf16x4*)&Qs[row * QS_LD + c4] = p;
    }

    f32x4 o[8];
#pragma unroll
    for (int d8 = 0; d8 < 8; ++d8) o[d8] = (f32x4){0.f, 0.f, 0.f, 0.f};
    float m_i[4] = {-1e30f, -1e30f, -1e30f, -1e30f};
    float l_i[4] = {0.f, 0.f, 0.f, 0.f};

    __syncthreads();

    for (int kt = 0; kt < 9; ++kt) {
        const int sbase = t0 - 512 + kt * KTI;
        if (sbase < 0) continue;
        __syncthreads();
#pragma unroll
        for (int i = 0; i < 8; ++i) {
            int gid = i * 256 + tid;
            int row = gid >> 5, c4 = (gid & 31) << 2;
            const float* base = qkv + (size_t)(sbase + row) * QKV_LD + h * HD + c4;
            const float4 kv = *(const float4*)(base + 2048);
            bf16x4 pk4;
            pk4[0] = (bf16_t)kv.x; pk4[1] = (bf16_t)kv.y;
            pk4[2] = (bf16_t)kv.z; pk4[3] = (bf16_t)kv.w;
            *(bf16x4*)&Ks[row * QS_LD + c4] = pk4;
            const float4 vv = *(const float4*)(base + 4096);
            Vt[(c4 + 0) * VT_LD + row] = (bf16_t)vv.x;
            Vt[(c4 + 1) * VT_LD + row] = (bf16_t)vv.y;
            Vt[(c4 + 2) * VT_LD + row] = (bf16_t)vv.z;
            Vt[(c4 + 3) * VT_LD + row] = (bf16_t)vv.w;
        }
        __syncthreads();

        f32x4 sacc[4];
#pragma unroll
        for (int nt = 0; nt < 4; ++nt) sacc[nt] = (f32x4){0.f, 0.f, 0.f, 0.f};
#pragma unroll
        for (int ks = 0; ks < 4; ++ks) {
            bf16x8 a = *(const bf16x8*)&Qs[(wave * 16 + l16) * QS_LD + ks * 32 + quad * 8];
#pragma unroll
            for (int nt = 0; nt < 4; ++nt) {
                bf16x8 b = *(const bf16x8*)&Ks[(nt * 16 + l16) * QS_LD + ks * 32 + quad * 8];
                sacc[nt] = __builtin_amdgcn_mfma_f32_16x16x32_bf16(a, b, sacc[nt], 0, 0, 0);
            }
        }

#pragma unroll
        for (int nt = 0; nt < 4; ++nt) {
            int s_g = sbase + nt * 16 + l16;
#pragma unroll
            for (int r = 0; r < 4; ++r) {
                int t_g = t0 + wave * 16 + quad * 4 + r;
                bool valid = (s_g <= t_g) && (s_g + W_LOCAL > t_g);
                if (!valid) sacc[nt][r] = -1e30f;
            }
        }

#pragma unroll
        for (int r = 0; r < 4; ++r) {
            float mx = fmaxf(fmaxf(sacc[0][r], sacc[1][r]), fmaxf(sacc[2][r], sacc[3][r]));
            mx = fmaxf(mx, __shfl_xor(mx, 1));
            mx = fmaxf(mx, __shfl_xor(mx, 2));
            mx = fmaxf(mx, __shfl_xor(mx, 4));
            mx = fmaxf(mx, __shfl_xor(mx, 8));
            float mnew = fmaxf(m_i[r], mx);
            float alpha = __expf(m_i[r] - mnew);
            m_i[r] = mnew;
            float rs = 0.f;
#pragma unroll
            for (int nt = 0; nt < 4; ++nt) {
                float p = __expf(sacc[nt][r] - mnew);
                sacc[nt][r] = p;
                rs += p;
            }
            rs += __shfl_xor(rs, 1);
            rs += __shfl_xor(rs, 2);
            rs += __shfl_xor(rs, 4);
            rs += __shfl_xor(rs, 8);
            l_i[r] = l_i[r] * alpha + rs;
#pragma unroll
            for (int d8 = 0; d8 < 8; ++d8) o[d8][r] *= alpha;
        }

#pragma unroll
        for (int r = 0; r < 4; ++r)
#pragma unroll
            for (int nt = 0; nt < 4; ++nt)
                Ps[wave][(quad * 4 + r) * PS_LD + nt * 16 + l16] = (bf16_t)sacc[nt][r];

#pragma unroll
        for (int ks2 = 0; ks2 < 2; ++ks2) {
            bf16x8 a = *(const bf16x8*)&Ps[wave][l16 * PS_LD + ks2 * 32 + quad * 8];
#pragma unroll
            for (int d8 = 0; d8 < 8; ++d8) {
                const bf16_t* vb = &Vt[(d8 * 16 + l16) * VT_LD + ks2 * 32 + quad * 8];
                bf16x4 b0 = *(const bf16x4*)vb;
                bf16x4 b1 = *(const bf16x4*)(vb + 4);
                bf16x8 b;
                b[0] = b0[0]; b[1] = b0[1]; b[2] = b0[2]; b[3] = b0[3];
                b[4] = b1[0]; b[5] = b1[1]; b[6] = b1[2]; b[7] = b1[3];
                o[d8] = __builtin_amdgcn_mfma_f32_16x16x32_bf16(a, b, o[d8], 0, 0, 0);
            }
        }
    }

#pragma unroll
    for (int r = 0; r < 4; ++r) {
        float inv = 1.0f / l_i[r];
        size_t rowoff = (size_t)(t0 + wave * 16 + quad * 4 + r) * QKV_LD + h * HD;
#pragma unroll
        for (int d8 = 0; d8 < 8; ++d8)
            qkv[rowoff + d8 * 16 + l16] = o[d8][r] * inv;
    }
}

// ---------------------------------------------------------------------------
// Gated global low-rank branch (early-exit when gate==0)
// ---------------------------------------------------------------------------
__device__ __forceinline__ float block_reduce_max512(float v, float* red, int tid) {
    red[tid] = v; __syncthreads();
    for (int s = 256; s > 0; s >>= 1) {
        if (tid < s) red[tid] = fmaxf(red[tid], red[tid + s]);
        __syncthreads();
    }
    float r = red[0]; __syncthreads();
    return r;
}
__device__ __forceinline__ float block_reduce_sum512(float v, float* red, int tid) {
    red[tid] = v; __syncthreads();
    for (int s = 256; s > 0; s >>= 1) {
        if (tid < s) red[tid] = red[tid] + red[tid + s];
        __syncthreads();
    }
    float r = red[0]; __syncthreads();
    return r;
}

__global__ __launch_bounds__(512)
void global_attn_kernel(float* __restrict__ qkv, const float* __restrict__ kr,
                        const float* __restrict__ vr, const bf16_t* __restrict__ qr,
                        const float* __restrict__ uo, const float* __restrict__ gate) {
    const int t = blockIdx.x, h = blockIdx.y;
    if (gate[t] <= 0.5f) return;

    __shared__ float qrs[64];
    __shared__ float red[512];
    __shared__ float cgr[64];
    __shared__ float sg[2048];
    const int tid = threadIdx.x;

    if (tid < 64) qrs[tid] = (float)qr[((size_t)h * T_LEN + t) * RANK + tid];
    __syncthreads();

    const float* krh = kr + (size_t)h * T_LEN * RANK;
    const float* vrh = vr + (size_t)h * T_LEN * RANK;
    float lmax = -INFINITY;
    for (int s = tid; s < T_LEN; s += 512) {
        const float* krr = krh + (size_t)s * RANK;
        float acc = 0.f;
#pragma unroll
        for (int r = 0; r < RANK; r += 4) {
            float4 k4 = *(const float4*)(krr + r);
            acc += qrs[r] * k4.x + qrs[r + 1] * k4.y + qrs[r + 2] * k4.z + qrs[r + 3] * k4.w;
        }
        float sc = acc * SCALE_G;
        sg[s] = sc;
        lmax = fmaxf(lmax, sc);
    }
    float gmx = block_reduce_max512(lmax, red, tid);
    float lsum = 0.f;
    for (int s = tid; s < T_LEN; s += 512) {
        float pp = expf(sg[s] - gmx);
        sg[s] = pp;
        lsum += pp;
    }
    float gsum = block_reduce_sum512(lsum, red, tid);

    {
        const int r = tid & 63, part = tid >> 6;
        float pacc = 0.f;
        for (int s = part; s < T_LEN; s += 8) pacc += sg[s] * vrh[(size_t)s * RANK + r];
        red[tid] = pacc;
        __syncthreads();
        if (tid < 64) {
            float c = 0.f;
#pragma unroll
            for (int pp = 0; pp < 8; ++pp) c += red[pp * 64 + tid];
            cgr[tid] = c / gsum;
        }
        __syncthreads();
    }

    if (tid < 128) {
        float cg = 0.f;
#pragma unroll
        for (int r = 0; r < RANK; ++r) cg += cgr[r] * uo[tid * RANK + r];
        qkv[(size_t)t * QKV_LD + h * HD + tid] += cg;
    }
}

// ---------------------------------------------------------------------------
extern "C" void kernel_launch(void* const* d_in, const int* in_sizes, int n_in,
                              void* d_out, int out_size, void* d_ws, size_t ws_size,
                              hipStream_t stream) {
    const float* x     = (const float*)d_in[0];
    const float* w_qkv = (const float*)d_in[1];
    const float* w_o   = (const float*)d_in[2];
    const float* pk    = (const float*)d_in[3];
    const float* pv    = (const float*)d_in[4];
    const float* uo    = (const float*)d_in[5];
    const float* w1    = (const float*)d_in[6];
    const float* w2    = (const float*)d_in[7];
    float* out = (float*)d_out;

    // Workspace layout (floats), lifetime-aliased (~84 MB):
    float* ws = (float*)d_ws;
    float* qkv   = ws;                        // 12,582,912 f (pre-GEMM: info scratch)
    float* hinfo = qkv + (size_t)12582912;    // 1,048,576 f (later qr bf16)
    float* gatep = hinfo + (size_t)1048576;   // 2048 f
    bf16_t* xb   = (bf16_t*)(gatep + 2048);   // 2048*2048 bf16 = x_hi (later ctx_bf)
    float* wqbf  = gatep + 2048 + 2097152;    // 6,291,456 f region:
    bf16_t* wqb  = (bf16_t*)wqbf;             //   w_qkv bf16 (6144*2048)
    float* krp   = wqbf;                      //   later: kr (2,097,152 f)
    float* vrp   = wqbf + (size_t)2097152;    //   later: vr (2,097,152 f)
    float* tabp  = wqbf + (size_t)4194304;    //   later: rope tables (262,144 f)
    bf16_t* wob  = (bf16_t*)krp;              //   later still: w_o bf16
    bf16_t* qrp  = (bf16_t*)hinfo;            // qr bf16
    bf16_t* cxb  = xb;                        // ctx bf16
    // Info-MLP scratch inside the pre-GEMM qkv region (all dead before step 3):
    float* ipart  = qkv;                          // 4×2048×512 f = 4,194,304 f
    bf16_t* xlo   = (bf16_t*)(qkv + 4194304);     // 4,194,304 bf16
    bf16_t* w1hi  = (bf16_t*)(qkv + 6291456);     // 1,048,576 bf16
    bf16_t* w1lo  = (bf16_t*)(qkv + 6815744);     // 1,048,576 bf16

    // 1) split-bf16 conversions: x -> (xb, xlo); w1 -> (w1hi, w1lo)
    conv_split_bf16<<<2048, 256, 0, stream>>>(x, xb, xlo, 524288);
    conv_split_bf16<<<512, 256, 0, stream>>>(w1, w1hi, w1lo, 131072);
    // 2) info MLP via 3x bf16 MFMA split-K -> reduce+gelu -> gate (fp32-accurate)
    info_gemm_mfma<<<dim3(4, 16, 4), 256, 0, stream>>>(xb, xlo, w1hi, w1lo, ipart);
    info_reduce_kernel<<<1024, 256, 0, stream>>>(ipart, hinfo);
    gate_kernel<<<T_LEN, 64, 0, stream>>>(hinfo, w2, gatep);
    // 3) convert w_qkv; qkv = x @ w_qkv^T (bf16 MFMA; overwrites info scratch)
    conv_f32_bf16<<<6144, 256, 0, stream>>>(w_qkv, wqb, 2048, 2048, 6144);
    gemm_bf16_nt<<<dim3(48, 16), 256, 0, stream>>>(xb, wqb, qkv, 2048, 2048, 2048, QKV_LD);
    // 4) RoPE: table (aliases dead wqb tail), then apply
    rope_table_kernel<<<512, 256, 0, stream>>>(tabp);
    rope_apply_kernel<<<4096, 256, 0, stream>>>(qkv, tabp);
    // 5) k_r, v_r, q_r via MFMA (kr/vr overwrite dead wqb; qr overwrites dead hinfo)
    kvr_mfma_kernel<<<dim3(T_LEN / 64, NH), 256, 0, stream>>>(qkv, pk, pv, krp, vrp, qrp);
    // 6) flash local attention -> ctx (over q region)
    local_attn_kernel<<<dim3(T_LEN / QTI, NH), 256, 0, stream>>>(qkv);
    // 7) gated global branch (adds into ctx)
    global_attn_kernel<<<dim3(T_LEN, NH), 512, 0, stream>>>(qkv, krp, vrp, qrp, uo, gatep);
    // 8) convert ctx -> bf16, w_o -> bf16
    conv_f32_bf16<<<2048, 256, 0, stream>>>(qkv, cxb, QKV_LD, 2048, 2048);
    conv_f32_bf16<<<2048, 256, 0, stream>>>(w_o, wob, 2048, 2048, 2048);
    // 9) out = ctx @ w_o^T  (bf16 MFMA)
    gemm_bf16_nt<<<dim3(16, 16), 256, 0, stream>>>(cxb, wob, out, 2048, 2048, 2048, 2048);
}

// Round 7
// 384.222 us; speedup vs baseline: 10.1119x; 1.0263x over previous
//
#include <hip/hip_runtime.h>
#include <hip/hip_bf16.h>
#include <math.h>

// Problem constants
#define T_LEN 2048
#define C_DIM 2048
#define NH 16
#define HD 128
#define RANK 64
#define W_LOCAL 512
#define QKV_LD 6144
#define ROW_BF 12288          // qkv row stride in bf16 elems (6144 f32)
#define KB_OFF 4096           // bf16-elem offset of packed K overlay within row
#define VB_OFF 8192           // bf16-elem offset of packed V overlay within row
#define SCALE 0.08838834764831845f    // 1/sqrt(128)
#define SCALE_G 0.17677669529663687f  // scale * 128/64
#define LOG1E4_OVER_64 0.14391156831212787f

typedef __bf16 bf16_t;
typedef __bf16 bf16x8 __attribute__((ext_vector_type(8)));
typedef __bf16 bf16x4 __attribute__((ext_vector_type(4)));
typedef float f32x4 __attribute__((ext_vector_type(4)));

// ---------------------------------------------------------------------------
// async 16B global -> LDS (gfx950). LDS dst must be wave-uniform base+lane*16.
// ---------------------------------------------------------------------------
__device__ __forceinline__ void async_copy16(const bf16_t* g, bf16_t* l) {
    __builtin_amdgcn_global_load_lds(
        (const __attribute__((address_space(1))) unsigned int*)g,
        (__attribute__((address_space(3))) unsigned int*)l, 16, 0, 0);
}

// ---------------------------------------------------------------------------
// fp32 -> bf16 conversion, 8 elems/thread
// ---------------------------------------------------------------------------
__global__ __launch_bounds__(256)
void conv_f32_bf16(const float* __restrict__ in, bf16_t* __restrict__ out,
                   int ld_in, int cols, int rows) {
    int per_row = cols >> 3;
    int idx = blockIdx.x * 256 + threadIdx.x;
    if (idx >= rows * per_row) return;
    int row = idx / per_row, c = (idx - row * per_row) << 3;
    const float* p = in + (size_t)row * ld_in + c;
    float4 v0 = *(const float4*)p;
    float4 v1 = *(const float4*)(p + 4);
    bf16x8 o;
    o[0] = (bf16_t)v0.x; o[1] = (bf16_t)v0.y; o[2] = (bf16_t)v0.z; o[3] = (bf16_t)v0.w;
    o[4] = (bf16_t)v1.x; o[5] = (bf16_t)v1.y; o[6] = (bf16_t)v1.z; o[7] = (bf16_t)v1.w;
    *(bf16x8*)(out + (size_t)row * cols + c) = o;
}

// fp32 -> (hi, lo) split-bf16: hi = bf16(v), lo = bf16(v - hi). Flat array.
__global__ __launch_bounds__(256)
void conv_split_bf16(const float* __restrict__ in, bf16_t* __restrict__ hi,
                     bf16_t* __restrict__ lo, int n8) {
    int idx = blockIdx.x * 256 + threadIdx.x;
    if (idx >= n8) return;
    const float* p = in + (size_t)idx * 8;
    float4 v0 = *(const float4*)p;
    float4 v1 = *(const float4*)(p + 4);
    float v[8] = {v0.x, v0.y, v0.z, v0.w, v1.x, v1.y, v1.z, v1.w};
    bf16x8 h, l;
#pragma unroll
    for (int i = 0; i < 8; ++i) {
        bf16_t hb = (bf16_t)v[i];
        h[i] = hb;
        l[i] = (bf16_t)(v[i] - (float)hb);
    }
    *(bf16x8*)(hi + (size_t)idx * 8) = h;
    *(bf16x8*)(lo + (size_t)idx * 8) = l;
}

// ---------------------------------------------------------------------------
// bf16 MFMA GEMM (m97 recipe)
// ---------------------------------------------------------------------------
#define GBK 32

__global__ __launch_bounds__(256)
void gemm_bf16_nt(const bf16_t* __restrict__ A, const bf16_t* __restrict__ B,
                  float* __restrict__ C, int K, int lda, int ldb, int ldc) {
    __shared__ bf16_t As[128 * GBK];
    __shared__ bf16_t Bs[128 * GBK];
    const int tid = threadIdx.x;
    const int wave = tid >> 6, lane = tid & 63;
    const int quad = lane >> 4, l16 = lane & 15;
    const int bm = blockIdx.y * 128, bn = blockIdx.x * 128;
    const int wm = (wave >> 1) * 64, wn = (wave & 1) * 64;
    const int lrow = lane >> 2;
    const int lkb = (lane & 3) * 8;

    f32x4 acc[4][4];
#pragma unroll
    for (int i = 0; i < 4; ++i)
#pragma unroll
        for (int j = 0; j < 4; ++j) acc[i][j] = (f32x4){0.f, 0.f, 0.f, 0.f};

    const bf16_t* gA = A + (size_t)(bm + wave * 16 + lrow) * lda + lkb;
    const bf16_t* gB = B + (size_t)(bn + wave * 16 + lrow) * ldb + lkb;
    bf16_t* lA = &As[(wave * 16 + lrow) * GBK + lkb];
    bf16_t* lB = &Bs[(wave * 16 + lrow) * GBK + lkb];

    for (int k0 = 0; k0 < K; k0 += GBK) {
        __syncthreads();
        async_copy16(gA + k0, lA);
        async_copy16(gA + (size_t)64 * lda + k0, lA + 64 * GBK);
        async_copy16(gB + k0, lB);
        async_copy16(gB + (size_t)64 * ldb + k0, lB + 64 * GBK);
        __syncthreads();

        bf16x8 a[4], b[4];
#pragma unroll
        for (int mt = 0; mt < 4; ++mt)
            a[mt] = *(const bf16x8*)&As[(wm + mt * 16 + l16) * GBK + quad * 8];
#pragma unroll
        for (int nt = 0; nt < 4; ++nt)
            b[nt] = *(const bf16x8*)&Bs[(wn + nt * 16 + l16) * GBK + quad * 8];
#pragma unroll
        for (int mt = 0; mt < 4; ++mt)
#pragma unroll
            for (int nt = 0; nt < 4; ++nt)
                acc[mt][nt] = __builtin_amdgcn_mfma_f32_16x16x32_bf16(a[mt], b[nt], acc[mt][nt], 0, 0, 0);
    }

#pragma unroll
    for (int mt = 0; mt < 4; ++mt)
#pragma unroll
        for (int r = 0; r < 4; ++r) {
            int row = bm + wm + mt * 16 + quad * 4 + r;
            float* crow = C + (size_t)row * ldc + bn + wn;
#pragma unroll
            for (int nt = 0; nt < 4; ++nt)
                crow[nt * 16 + l16] = acc[mt][nt][r];
        }
}

// ---------------------------------------------------------------------------
// Split-bf16 (3x bf16-MFMA) GEMM for the gate-critical info MLP.
// ---------------------------------------------------------------------------
__global__ __launch_bounds__(256)
void info_gemm_mfma(const bf16_t* __restrict__ Ahi, const bf16_t* __restrict__ Alo,
                    const bf16_t* __restrict__ Bhi, const bf16_t* __restrict__ Blo,
                    float* __restrict__ Cpart) {
    __shared__ bf16_t Ah[128 * GBK];
    __shared__ bf16_t Al[128 * GBK];
    __shared__ bf16_t Bh[128 * GBK];
    __shared__ bf16_t Bl[128 * GBK];
    const int tid = threadIdx.x;
    const int wave = tid >> 6, lane = tid & 63;
    const int quad = lane >> 4, l16 = lane & 15;
    const int bm = blockIdx.y * 128, bn = blockIdx.x * 128;
    const int ks = blockIdx.z;
    const int wm = (wave >> 1) * 64, wn = (wave & 1) * 64;
    const int lrow = lane >> 2;
    const int lkb = (lane & 3) * 8;
    const int kbeg = ks * 512;

    f32x4 acc[4][4];
#pragma unroll
    for (int i = 0; i < 4; ++i)
#pragma unroll
        for (int j = 0; j < 4; ++j) acc[i][j] = (f32x4){0.f, 0.f, 0.f, 0.f};

    const size_t aoff = (size_t)(bm + wave * 16 + lrow) * 2048 + lkb + kbeg;
    const size_t boff = (size_t)(bn + wave * 16 + lrow) * 2048 + lkb + kbeg;
    bf16_t* lAh = &Ah[(wave * 16 + lrow) * GBK + lkb];
    bf16_t* lAl = &Al[(wave * 16 + lrow) * GBK + lkb];
    bf16_t* lBh = &Bh[(wave * 16 + lrow) * GBK + lkb];
    bf16_t* lBl = &Bl[(wave * 16 + lrow) * GBK + lkb];

    for (int k0 = 0; k0 < 512; k0 += GBK) {
        __syncthreads();
        async_copy16(Ahi + aoff + k0, lAh);
        async_copy16(Ahi + aoff + (size_t)64 * 2048 + k0, lAh + 64 * GBK);
        async_copy16(Alo + aoff + k0, lAl);
        async_copy16(Alo + aoff + (size_t)64 * 2048 + k0, lAl + 64 * GBK);
        async_copy16(Bhi + boff + k0, lBh);
        async_copy16(Bhi + boff + (size_t)64 * 2048 + k0, lBh + 64 * GBK);
        async_copy16(Blo + boff + k0, lBl);
        async_copy16(Blo + boff + (size_t)64 * 2048 + k0, lBl + 64 * GBK);
        __syncthreads();

        bf16x8 ah[4], al[4], bh[4], bl[4];
#pragma unroll
        for (int mt = 0; mt < 4; ++mt) {
            ah[mt] = *(const bf16x8*)&Ah[(wm + mt * 16 + l16) * GBK + quad * 8];
            al[mt] = *(const bf16x8*)&Al[(wm + mt * 16 + l16) * GBK + quad * 8];
        }
#pragma unroll
        for (int nt = 0; nt < 4; ++nt) {
            bh[nt] = *(const bf16x8*)&Bh[(wn + nt * 16 + l16) * GBK + quad * 8];
            bl[nt] = *(const bf16x8*)&Bl[(wn + nt * 16 + l16) * GBK + quad * 8];
        }
#pragma unroll
        for (int mt = 0; mt < 4; ++mt)
#pragma unroll
            for (int nt = 0; nt < 4; ++nt) {
                acc[mt][nt] = __builtin_amdgcn_mfma_f32_16x16x32_bf16(ah[mt], bh[nt], acc[mt][nt], 0, 0, 0);
                acc[mt][nt] = __builtin_amdgcn_mfma_f32_16x16x32_bf16(ah[mt], bl[nt], acc[mt][nt], 0, 0, 0);
                acc[mt][nt] = __builtin_amdgcn_mfma_f32_16x16x32_bf16(al[mt], bh[nt], acc[mt][nt], 0, 0, 0);
            }
    }

    float* cp = Cpart + (size_t)ks * 2048 * 512;
#pragma unroll
    for (int mt = 0; mt < 4; ++mt)
#pragma unroll
        for (int r = 0; r < 4; ++r) {
            int row = bm + wm + mt * 16 + quad * 4 + r;
            float* crow = cp + (size_t)row * 512 + bn + wn;
#pragma unroll
            for (int nt = 0; nt < 4; ++nt)
                crow[nt * 16 + l16] = acc[mt][nt][r];
        }
}

__device__ __forceinline__ float gelu_exact(float v) {
    return 0.5f * v * (1.0f + erff(v * 0.70710678118654752f));
}

__global__ __launch_bounds__(256)
void info_reduce_kernel(const float* __restrict__ Cpart, float* __restrict__ h) {
    int idx = blockIdx.x * 256 + threadIdx.x;
    const f32x4* p = (const f32x4*)Cpart;
    f32x4 a = p[idx];
    f32x4 b = p[idx + 262144];
    f32x4 c = p[idx + 524288];
    f32x4 d = p[idx + 786432];
    f32x4 r;
#pragma unroll
    for (int i = 0; i < 4; ++i) r[i] = gelu_exact(((a[i] + b[i]) + c[i]) + d[i]);
    ((f32x4*)h)[idx] = r;
}

// ---------------------------------------------------------------------------
// RoPE tables: tab[t*128 + j] = cos(t*invf[j]); +64: sin
// ---------------------------------------------------------------------------
__global__ __launch_bounds__(256)
void rope_table_kernel(float* __restrict__ tab) {
    int idx = blockIdx.x * 256 + threadIdx.x;
    int t = idx >> 6, j = idx & 63;
    float inv = expf(-(float)j * LOG1E4_OVER_64);
    float s, c;
    sincosf((float)t * inv, &s, &c);
    tab[t * 128 + j] = c;
    tab[t * 128 + 64 + j] = s;
}

// ---------------------------------------------------------------------------
// Fused RoPE + bf16 packing. One block per token t, 256 threads x 8 cols.
// - ropes q in place (fp32)
// - ropes k -> bf16 overlay at row start of k region (elem KB_OFF + c)
// - converts v -> bf16 overlay at row start of v region (elem VB_OFF + c)
// The bf16 writes alias the fp32 k/v storage -> read everything, sync, write.
// ---------------------------------------------------------------------------
__global__ __launch_bounds__(256)
void rope_fuse_kernel(float* __restrict__ qkv, bf16_t* __restrict__ qkv_bf,
                      const float* __restrict__ tab) {
    const int t = blockIdx.x;
    const int c = threadIdx.x * 8;           // 0..2040, within-region col
    float* row = qkv + (size_t)t * QKV_LD;
    bf16_t* rowb = qkv_bf + (size_t)t * ROW_BF;
    const float* tr = tab + t * 128;
    const int d0 = c & 127;

    float cs[8], sn[8];
#pragma unroll
    for (int m = 0; m < 4; ++m) {
        int j0 = (d0 + 2 * m) & 63;
        cs[2 * m] = tr[j0];         sn[2 * m] = tr[64 + j0];
        cs[2 * m + 1] = tr[j0 + 1]; sn[2 * m + 1] = tr[64 + j0 + 1];
    }

    // q: rope in place (no cross-thread alias)
    {
        float4 a = *(const float4*)(row + c);
        float4 b = *(const float4*)(row + c + 4);
        float xs[8] = {a.x, a.y, a.z, a.w, b.x, b.y, b.z, b.w};
        float ys[8];
#pragma unroll
        for (int m = 0; m < 4; ++m) {
            ys[2 * m]     = xs[2 * m] * cs[2 * m] - xs[2 * m + 1] * sn[2 * m];
            ys[2 * m + 1] = xs[2 * m + 1] * cs[2 * m + 1] + xs[2 * m] * sn[2 * m + 1];
        }
        *(float4*)(row + c)     = make_float4(ys[0], ys[1], ys[2], ys[3]);
        *(float4*)(row + c + 4) = make_float4(ys[4], ys[5], ys[6], ys[7]);
    }

    // k, v: read fp32 into regs
    float4 ka = *(const float4*)(row + 2048 + c);
    float4 kb4 = *(const float4*)(row + 2048 + c + 4);
    float4 va = *(const float4*)(row + 4096 + c);
    float4 vb4 = *(const float4*)(row + 4096 + c + 4);
    __syncthreads();   // all k/v reads of this row done before aliasing writes

    float kx[8] = {ka.x, ka.y, ka.z, ka.w, kb4.x, kb4.y, kb4.z, kb4.w};
    bf16x8 ko, vo;
#pragma unroll
    for (int m = 0; m < 4; ++m) {
        ko[2 * m]     = (bf16_t)(kx[2 * m] * cs[2 * m] - kx[2 * m + 1] * sn[2 * m]);
        ko[2 * m + 1] = (bf16_t)(kx[2 * m + 1] * cs[2 * m + 1] + kx[2 * m] * sn[2 * m + 1]);
    }
    vo[0] = (bf16_t)va.x; vo[1] = (bf16_t)va.y; vo[2] = (bf16_t)va.z; vo[3] = (bf16_t)va.w;
    vo[4] = (bf16_t)vb4.x; vo[5] = (bf16_t)vb4.y; vo[6] = (bf16_t)vb4.z; vo[7] = (bf16_t)vb4.w;
    *(bf16x8*)(rowb + KB_OFF + c) = ko;
    *(bf16x8*)(rowb + VB_OFF + c) = vo;
}

// ---------------------------------------------------------------------------
// Gate (fp32 path, exact)
// ---------------------------------------------------------------------------
__global__ void gate_kernel(const float* __restrict__ h_info,
                            const float* __restrict__ w2,
                            float* __restrict__ gate) {
    const int t = blockIdx.x;
    const int lane = threadIdx.x;
    float s = 0.f;
    for (int i = lane; i < 512; i += 64) s += h_info[(size_t)t * 512 + i] * w2[i];
#pragma unroll
    for (int off = 32; off > 0; off >>= 1) s += __shfl_down(s, off);
    if (lane == 0) {
        float sig = 1.f / (1.f + expf(-s));
        gate[t] = (sig > 0.75f) ? 1.f : 0.f;
    }
}

// ---------------------------------------------------------------------------
// MFMA kvr v2: K/V from bf16 overlays (no convert), Q from fp32.
// ---------------------------------------------------------------------------
#define KV_LD 136

__global__ __launch_bounds__(256)
void kvr_mfma_kernel(const float* __restrict__ qkv, const bf16_t* __restrict__ qkv_bf,
                     const float* __restrict__ pk, const float* __restrict__ pv,
                     float* __restrict__ kr, float* __restrict__ vr,
                     bf16_t* __restrict__ qr) {
    __shared__ bf16_t Kt[64 * KV_LD];
    __shared__ bf16_t Vt[64 * KV_LD];
    __shared__ bf16_t Qt[64 * KV_LD];
    __shared__ bf16_t Pk[64 * KV_LD];
    __shared__ bf16_t Pv[64 * KV_LD];

    const int h = blockIdx.y;
    const int s0 = blockIdx.x * 64;
    const int tid = threadIdx.x;
    const int wave = tid >> 6, lane = tid & 63;
    const int quad = lane >> 4, l16 = lane & 15;

    // K/V: 64 rows x 16 chunks(16B) each, bf16 direct moves
#pragma unroll
    for (int i = 0; i < 4; ++i) {
        int gid = i * 256 + tid;             // 1024 chunk-slots
        int row = gid >> 4, ch = (gid & 15) << 3;
        const bf16_t* rb = qkv_bf + (size_t)(s0 + row) * ROW_BF + h * HD + ch;
        *(bf16x8*)&Kt[row * KV_LD + ch] = *(const bf16x8*)(rb + KB_OFF);
        *(bf16x8*)&Vt[row * KV_LD + ch] = *(const bf16x8*)(rb + VB_OFF);
    }
    // Q (fp32 -> bf16) and pk/pv (fp32 -> bf16)
#pragma unroll
    for (int i = 0; i < 8; ++i) {
        int gid = i * 256 + tid;             // 2048 float4-slots
        int row = gid >> 5, c = (gid & 31) << 2;
        float4 vq = *(const float4*)(qkv + (size_t)(s0 + row) * QKV_LD + h * HD + c);
        bf16x4 pq;
        pq[0] = (bf16_t)vq.x; pq[1] = (bf16_t)vq.y; pq[2] = (bf16_t)vq.z; pq[3] = (bf16_t)vq.w;
        *(bf16x4*)&Qt[row * KV_LD + c] = pq;
        float4 wk = *(const float4*)(pk + (size_t)row * HD + c);
        float4 wv = *(const float4*)(pv + (size_t)row * HD + c);
        bf16x4 qk4, qv4;
        qk4[0] = (bf16_t)wk.x; qk4[1] = (bf16_t)wk.y; qk4[2] = (bf16_t)wk.z; qk4[3] = (bf16_t)wk.w;
        qv4[0] = (bf16_t)wv.x; qv4[1] = (bf16_t)wv.y; qv4[2] = (bf16_t)wv.z; qv4[3] = (bf16_t)wv.w;
        *(bf16x4*)&Pk[row * KV_LD + c] = qk4;
        *(bf16x4*)&Pv[row * KV_LD + c] = qv4;
    }
    __syncthreads();

    f32x4 ak[4], av[4], aq[4];
#pragma unroll
    for (int nt = 0; nt < 4; ++nt) {
        ak[nt] = (f32x4){0.f, 0.f, 0.f, 0.f};
        av[nt] = (f32x4){0.f, 0.f, 0.f, 0.f};
        aq[nt] = (f32x4){0.f, 0.f, 0.f, 0.f};
    }

#pragma unroll
    for (int ks = 0; ks < 4; ++ks) {
        const int ao = (wave * 16 + l16) * KV_LD + ks * 32 + quad * 8;
        bf16x8 a_k = *(const bf16x8*)&Kt[ao];
        bf16x8 a_v = *(const bf16x8*)&Vt[ao];
        bf16x8 a_q = *(const bf16x8*)&Qt[ao];
#pragma unroll
        for (int nt = 0; nt < 4; ++nt) {
            const int bo = (nt * 16 + l16) * KV_LD + ks * 32 + quad * 8;
            bf16x8 bk = *(const bf16x8*)&Pk[bo];
            bf16x8 bv = *(const bf16x8*)&Pv[bo];
            ak[nt] = __builtin_amdgcn_mfma_f32_16x16x32_bf16(a_k, bk, ak[nt], 0, 0, 0);
            av[nt] = __builtin_amdgcn_mfma_f32_16x16x32_bf16(a_v, bv, av[nt], 0, 0, 0);
            aq[nt] = __builtin_amdgcn_mfma_f32_16x16x32_bf16(a_q, bk, aq[nt], 0, 0, 0);
        }
    }

#pragma unroll
    for (int nt = 0; nt < 4; ++nt)
#pragma unroll
        for (int r = 0; r < 4; ++r) {
            int s = s0 + wave * 16 + quad * 4 + r;
            size_t idx = ((size_t)h * T_LEN + s) * RANK + nt * 16 + l16;
            kr[idx] = ak[nt][r];
            vr[idx] = av[nt][r];
            qr[idx] = (bf16_t)aq[nt][r];
        }
}

// ---------------------------------------------------------------------------
// MFMA bf16 flash local attention v2:
// - K staged via async DMA from bf16 overlay, XOR chunk swizzle (ch^=row&7)
//   -> B-frag ds_read_b128 conflict-free (2 lanes per 4-bank group)
// - V staged from bf16 overlay (scalar transpose, padded rows)
// - ctx written bf16 directly to cxb [t][h*128+d]
// ---------------------------------------------------------------------------
#define QTI 64
#define KTI 64
#define QS_LD 136
#define VT_LD 68
#define PS_LD 72

__global__ __launch_bounds__(256)
void local_attn_kernel(const float* __restrict__ qkv, const bf16_t* __restrict__ qkv_bf,
                       bf16_t* __restrict__ cxb) {
    __shared__ bf16_t Qs[QTI * QS_LD];
    __shared__ bf16_t Ks[KTI * HD];          // swizzled, no pad (async dst)
    __shared__ bf16_t Vt[HD * VT_LD];
    __shared__ bf16_t Ps[4][16 * PS_LD];

    const int h = blockIdx.y;
    const int t0 = blockIdx.x * QTI;
    const int tid = threadIdx.x;
    const int wave = tid >> 6, lane = tid & 63;
    const int quad = lane >> 4, l16 = lane & 15;

    // stage Q (scale folded) fp32 -> bf16
#pragma unroll
    for (int i = 0; i < 8; ++i) {
        int gid = i * 256 + tid;
        int row = gid >> 5, c4 = (gid & 31) << 2;
        const float4 v = *(const float4*)(qkv + (size_t)(t0 + row) * QKV_LD + h * HD + c4);
        bf16x4 p;
        p[0] = (bf16_t)(v.x * SCALE); p[1] = (bf16_t)(v.y * SCALE);
        p[2] = (bf16_t)(v.z * SCALE); p[3] = (bf16_t)(v.w * SCALE);
        *(bf16x4*)&Qs[row * QS_LD + c4] = p;
    }

    f32x4 o[8];
#pragma unroll
    for (int d8 = 0; d8 < 8; ++d8) o[d8] = (f32x4){0.f, 0.f, 0.f, 0.f};
    float m_i[4] = {-1e30f, -1e30f, -1e30f, -1e30f};
    float l_i[4] = {0.f, 0.f, 0.f, 0.f};

    __syncthreads();

    for (int kt = 0; kt < 9; ++kt) {
        const int sbase = t0 - 512 + kt * KTI;
        if (sbase < 0) continue;
        __syncthreads();
        // K: async DMA, swizzled chunks. slot s -> (row=s>>4, ch=s&15),
        // fetches global chunk ch^(row&7). LDS dst = base + lane*16. ✓
#pragma unroll
        for (int i = 0; i < 4; ++i) {
            int s = i * 256 + tid;
            int row = s >> 4, ch = s & 15;
            int gch = ch ^ (row & 7);
            const bf16_t* src = qkv_bf + (size_t)(sbase + row) * ROW_BF + KB_OFF + h * HD + gch * 8;
            async_copy16(src, &Ks[s * 8]);
        }
        // V: bf16 loads + scalar transpose into padded Vt
#pragma unroll
        for (int i = 0; i < 8; ++i) {
            int gid = i * 256 + tid;
            int row = gid >> 5, c4 = (gid & 31) << 2;
            bf16x4 vv = *(const bf16x4*)(qkv_bf + (size_t)(sbase + row) * ROW_BF + VB_OFF + h * HD + c4);
            Vt[(c4 + 0) * VT_LD + row] = vv[0];
            Vt[(c4 + 1) * VT_LD + row] = vv[1];
            Vt[(c4 + 2) * VT_LD + row] = vv[2];
            Vt[(c4 + 3) * VT_LD + row] = vv[3];
        }
        __syncthreads();

        f32x4 sacc[4];
#pragma unroll
        for (int nt = 0; nt < 4; ++nt) sacc[nt] = (f32x4){0.f, 0.f, 0.f, 0.f};
#pragma unroll
        for (int ks = 0; ks < 4; ++ks) {
            bf16x8 a = *(const bf16x8*)&Qs[(wave * 16 + l16) * QS_LD + ks * 32 + quad * 8];
#pragma unroll
            for (int nt = 0; nt < 4; ++nt) {
                int r = nt * 16 + l16;
                int ch = (ks * 4 + quad) ^ (r & 7);
                bf16x8 b = *(const bf16x8*)&Ks[r * HD + ch * 8];
                sacc[nt] = __builtin_amdgcn_mfma_f32_16x16x32_bf16(a, b, sacc[nt], 0, 0, 0);
            }
        }

#pragma unroll
        for (int nt = 0; nt < 4; ++nt) {
            int s_g = sbase + nt * 16 + l16;
#pragma unroll
            for (int r = 0; r < 4; ++r) {
                int t_g = t0 + wave * 16 + quad * 4 + r;
                bool valid = (s_g <= t_g) && (s_g + W_LOCAL > t_g);
                if (!valid) sacc[nt][r] = -1e30f;
            }
        }

#pragma unroll
        for (int r = 0; r < 4; ++r) {
            float mx = fmaxf(fmaxf(sacc[0][r], sacc[1][r]), fmaxf(sacc[2][r], sacc[3][r]));
            mx = fmaxf(mx, __shfl_xor(mx, 1));
            mx = fmaxf(mx, __shfl_xor(mx, 2));
            mx = fmaxf(mx, __shfl_xor(mx, 4));
            mx = fmaxf(mx, __shfl_xor(mx, 8));
            float mnew = fmaxf(m_i[r], mx);
            float alpha = __expf(m_i[r] - mnew);
            m_i[r] = mnew;
            float rs = 0.f;
#pragma unroll
            for (int nt = 0; nt < 4; ++nt) {
                float p = __expf(sacc[nt][r] - mnew);
                sacc[nt][r] = p;
                rs += p;
            }
            rs += __shfl_xor(rs, 1);
            rs += __shfl_xor(rs, 2);
            rs += __shfl_xor(rs, 4);
            rs += __shfl_xor(rs, 8);
            l_i[r] = l_i[r] * alpha + rs;
#pragma unroll
            for (int d8 = 0; d8 < 8; ++d8) o[d8][r] *= alpha;
        }

#pragma unroll
        for (int r = 0; r < 4; ++r)
#pragma unroll
            for (int nt = 0; nt < 4; ++nt)
                Ps[wave][(quad * 4 + r) * PS_LD + nt * 16 + l16] = (bf16_t)sacc[nt][r];

#pragma unroll
        for (int ks2 = 0; ks2 < 2; ++ks2) {
            bf16x8 a = *(const bf16x8*)&Ps[wave][l16 * PS_LD + ks2 * 32 + quad * 8];
#pragma unroll
            for (int d8 = 0; d8 < 8; ++d8) {
                const bf16_t* vb = &Vt[(d8 * 16 + l16) * VT_LD + ks2 * 32 + quad * 8];
                bf16x4 b0 = *(const bf16x4*)vb;
                bf16x4 b1 = *(const bf16x4*)(vb + 4);
                bf16x8 b;
                b[0] = b0[0]; b[1] = b0[1]; b[2] = b0[2]; b[3] = b0[3];
                b[4] = b1[0]; b[5] = b1[1]; b[6] = b1[2]; b[7] = b1[3];
                o[d8] = __builtin_amdgcn_mfma_f32_16x16x32_bf16(a, b, o[d8], 0, 0, 0);
            }
        }
    }

    // normalize, write ctx bf16 to cxb[t][h*128+d]
#pragma unroll
    for (int r = 0; r < 4; ++r) {
        float inv = 1.0f / l_i[r];
        size_t rowoff = (size_t)(t0 + wave * 16 + quad * 4 + r) * 2048 + h * HD;
#pragma unroll
        for (int d8 = 0; d8 < 8; ++d8)
            cxb[rowoff + d8 * 16 + l16] = (bf16_t)(o[d8][r] * inv);
    }
}

// ---------------------------------------------------------------------------
// Gated global low-rank branch (early-exit when gate==0); bf16 RMW into cxb
// ---------------------------------------------------------------------------
__device__ __forceinline__ float block_reduce_max512(float v, float* red, int tid) {
    red[tid] = v; __syncthreads();
    for (int s = 256; s > 0; s >>= 1) {
        if (tid < s) red[tid] = fmaxf(red[tid], red[tid + s]);
        __syncthreads();
    }
    float r = red[0]; __syncthreads();
    return r;
}
__device__ __forceinline__ float block_reduce_sum512(float v, float* red, int tid) {
    red[tid] = v; __syncthreads();
    for (int s = 256; s > 0; s >>= 1) {
        if (tid < s) red[tid] = red[tid] + red[tid + s];
        __syncthreads();
    }
    float r = red[0]; __syncthreads();
    return r;
}

__global__ __launch_bounds__(512)
void global_attn_kernel(bf16_t* __restrict__ cxb, const float* __restrict__ kr,
                        const float* __restrict__ vr, const bf16_t* __restrict__ qr,
                        const float* __restrict__ uo, const float* __restrict__ gate) {
    const int t = blockIdx.x, h = blockIdx.y;
    if (gate[t] <= 0.5f) return;

    __shared__ float qrs[64];
    __shared__ float red[512];
    __shared__ float cgr[64];
    __shared__ float sg[2048];
    const int tid = threadIdx.x;

    if (tid < 64) qrs[tid] = (float)qr[((size_t)h * T_LEN + t) * RANK + tid];
    __syncthreads();

    const float* krh = kr + (size_t)h * T_LEN * RANK;
    const float* vrh = vr + (size_t)h * T_LEN * RANK;
    float lmax = -INFINITY;
    for (int s = tid; s < T_LEN; s += 512) {
        const float* krr = krh + (size_t)s * RANK;
        float acc = 0.f;
#pragma unroll
        for (int r = 0; r < RANK; r += 4) {
            float4 k4 = *(const float4*)(krr + r);
            acc += qrs[r] * k4.x + qrs[r + 1] * k4.y + qrs[r + 2] * k4.z + qrs[r + 3] * k4.w;
        }
        float sc = acc * SCALE_G;
        sg[s] = sc;
        lmax = fmaxf(lmax, sc);
    }
    float gmx = block_reduce_max512(lmax, red, tid);
    float lsum = 0.f;
    for (int s = tid; s < T_LEN; s += 512) {
        float pp = expf(sg[s] - gmx);
        sg[s] = pp;
        lsum += pp;
    }
    float gsum = block_reduce_sum512(lsum, red, tid);

    {
        const int r = tid & 63, part = tid >> 6;
        float pacc = 0.f;
        for (int s = part; s < T_LEN; s += 8) pacc += sg[s] * vrh[(size_t)s * RANK + r];
        red[tid] = pacc;
        __syncthreads();
        if (tid < 64) {
            float c = 0.f;
#pragma unroll
            for (int pp = 0; pp < 8; ++pp) c += red[pp * 64 + tid];
            cgr[tid] = c / gsum;
        }
        __syncthreads();
    }

    if (tid < 128) {
        float cg = 0.f;
#pragma unroll
        for (int r = 0; r < RANK; ++r) cg += cgr[r] * uo[tid * RANK + r];
        size_t off = (size_t)t * 2048 + h * HD + tid;
        cxb[off] = (bf16_t)((float)cxb[off] + cg);
    }
}

// ---------------------------------------------------------------------------
extern "C" void kernel_launch(void* const* d_in, const int* in_sizes, int n_in,
                              void* d_out, int out_size, void* d_ws, size_t ws_size,
                              hipStream_t stream) {
    const float* x     = (const float*)d_in[0];
    const float* w_qkv = (const float*)d_in[1];
    const float* w_o   = (const float*)d_in[2];
    const float* pk    = (const float*)d_in[3];
    const float* pv    = (const float*)d_in[4];
    const float* uo    = (const float*)d_in[5];
    const float* w1    = (const float*)d_in[6];
    const float* w2    = (const float*)d_in[7];
    float* out = (float*)d_out;

    // Workspace layout (floats), lifetime-aliased (~84 MB):
    float* ws = (float*)d_ws;
    float* qkv   = ws;                        // 12,582,912 f (pre-GEMM: info scratch;
                                              //  k/v rows later carry bf16 overlays)
    float* hinfo = qkv + (size_t)12582912;    // 1,048,576 f (later qr bf16)
    float* gatep = hinfo + (size_t)1048576;   // 2048 f
    bf16_t* xb   = (bf16_t*)(gatep + 2048);   // x_hi bf16 (later ctx bf16)
    float* wqbf  = gatep + 2048 + 2097152;    // 6,291,456 f region:
    bf16_t* wqb  = (bf16_t*)wqbf;             //   w_qkv bf16 (6144*2048)
    float* krp   = wqbf;                      //   later: kr
    float* vrp   = wqbf + (size_t)2097152;    //   later: vr
    float* tabp  = wqbf + (size_t)4194304;    //   later: rope tables
    bf16_t* wob  = (bf16_t*)krp;              //   later still: w_o bf16 (after global_attn)
    bf16_t* qrp  = (bf16_t*)hinfo;            // qr bf16
    bf16_t* cxb  = xb;                        // ctx bf16 (x_hi dead after qkv gemm)
    bf16_t* qkvb = (bf16_t*)qkv;              // bf16 overlay view of qkv rows
    // Info-MLP scratch inside the pre-GEMM qkv region:
    float* ipart  = qkv;                          // 4x2048x512 f
    bf16_t* xlo   = (bf16_t*)(qkv + 4194304);
    bf16_t* w1hi  = (bf16_t*)(qkv + 6291456);
    bf16_t* w1lo  = (bf16_t*)(qkv + 6815744);

    // 1) split-bf16 conversions
    conv_split_bf16<<<2048, 256, 0, stream>>>(x, xb, xlo, 524288);
    conv_split_bf16<<<512, 256, 0, stream>>>(w1, w1hi, w1lo, 131072);
    // 2) info MLP (3x bf16 MFMA split-K) -> reduce+gelu -> gate
    info_gemm_mfma<<<dim3(4, 16, 4), 256, 0, stream>>>(xb, xlo, w1hi, w1lo, ipart);
    info_reduce_kernel<<<1024, 256, 0, stream>>>(ipart, hinfo);
    gate_kernel<<<T_LEN, 64, 0, stream>>>(hinfo, w2, gatep);
    // 3) qkv = x @ w_qkv^T (bf16 MFMA; overwrites info scratch)
    conv_f32_bf16<<<6144, 256, 0, stream>>>(w_qkv, wqb, 2048, 2048, 6144);
    gemm_bf16_nt<<<dim3(48, 16), 256, 0, stream>>>(xb, wqb, qkv, 2048, 2048, 2048, QKV_LD);
    // 4) RoPE table, then fused rope + bf16 K/V packing (in-place overlays)
    rope_table_kernel<<<512, 256, 0, stream>>>(tabp);
    rope_fuse_kernel<<<T_LEN, 256, 0, stream>>>(qkv, qkvb, tabp);
    // 5) k_r, v_r, q_r via MFMA (reads bf16 overlays + fp32 q)
    kvr_mfma_kernel<<<dim3(T_LEN / 64, NH), 256, 0, stream>>>(qkv, qkvb, pk, pv, krp, vrp, qrp);
    // 6) flash local attention -> ctx bf16 (cxb)
    local_attn_kernel<<<dim3(T_LEN / QTI, NH), 256, 0, stream>>>(qkv, qkvb, cxb);
    // 7) gated global branch (bf16 RMW into cxb)
    global_attn_kernel<<<dim3(T_LEN, NH), 512, 0, stream>>>(cxb, krp, vrp, qrp, uo, gatep);
    // 8) w_o -> bf16 (aliases kr: must follow global_attn), out = ctx @ w_o^T
    conv_f32_bf16<<<2048, 256, 0, stream>>>(w_o, wob, 2048, 2048, 2048);
    gemm_bf16_nt<<<dim3(16, 16), 256, 0, stream>>>(cxb, wob, out, 2048, 2048, 2048, 2048);
}

// Round 8
// 372.419 us; speedup vs baseline: 10.4323x; 1.0317x over previous
//
#include <hip/hip_runtime.h>
#include <hip/hip_bf16.h>
#include <math.h>

// Problem constants
#define T_LEN 2048
#define C_DIM 2048
#define NH 16
#define HD 128
#define RANK 64
#define W_LOCAL 512
#define QKV_LD 6144
#define ROW_BF 12288          // qkv row stride in bf16 elems
#define KB_OFF 4096           // bf16-elem offset of packed K overlay within row
#define VB_OFF 8192           // bf16-elem offset of packed V overlay within row
#define SCALE 0.08838834764831845f    // 1/sqrt(128)
#define SCALE_G 0.17677669529663687f  // scale * 128/64
#define LOG1E4_OVER_64 0.14391156831212787f

typedef __bf16 bf16_t;
typedef __bf16 bf16x8 __attribute__((ext_vector_type(8)));
typedef __bf16 bf16x4 __attribute__((ext_vector_type(4)));
typedef float f32x4 __attribute__((ext_vector_type(4)));

// ---------------------------------------------------------------------------
// async 16B global -> LDS (gfx950). LDS dst must be wave-uniform base+lane*16.
// ---------------------------------------------------------------------------
__device__ __forceinline__ void async_copy16(const bf16_t* g, bf16_t* l) {
    __builtin_amdgcn_global_load_lds(
        (const __attribute__((address_space(1))) unsigned int*)g,
        (__attribute__((address_space(3))) unsigned int*)l, 16, 0, 0);
}

// ---------------------------------------------------------------------------
// fp32 -> bf16 conversion, 8 elems/thread
// ---------------------------------------------------------------------------
__global__ __launch_bounds__(256)
void conv_f32_bf16(const float* __restrict__ in, bf16_t* __restrict__ out,
                   int ld_in, int cols, int rows) {
    int per_row = cols >> 3;
    int idx = blockIdx.x * 256 + threadIdx.x;
    if (idx >= rows * per_row) return;
    int row = idx / per_row, c = (idx - row * per_row) << 3;
    const float* p = in + (size_t)row * ld_in + c;
    float4 v0 = *(const float4*)p;
    float4 v1 = *(const float4*)(p + 4);
    bf16x8 o;
    o[0] = (bf16_t)v0.x; o[1] = (bf16_t)v0.y; o[2] = (bf16_t)v0.z; o[3] = (bf16_t)v0.w;
    o[4] = (bf16_t)v1.x; o[5] = (bf16_t)v1.y; o[6] = (bf16_t)v1.z; o[7] = (bf16_t)v1.w;
    *(bf16x8*)(out + (size_t)row * cols + c) = o;
}

// fp32 -> (hi, lo) split-bf16
__global__ __launch_bounds__(256)
void conv_split_bf16(const float* __restrict__ in, bf16_t* __restrict__ hi,
                     bf16_t* __restrict__ lo, int n8) {
    int idx = blockIdx.x * 256 + threadIdx.x;
    if (idx >= n8) return;
    const float* p = in + (size_t)idx * 8;
    float4 v0 = *(const float4*)p;
    float4 v1 = *(const float4*)(p + 4);
    float v[8] = {v0.x, v0.y, v0.z, v0.w, v1.x, v1.y, v1.z, v1.w};
    bf16x8 h, l;
#pragma unroll
    for (int i = 0; i < 8; ++i) {
        bf16_t hb = (bf16_t)v[i];
        h[i] = hb;
        l[i] = (bf16_t)(v[i] - (float)hb);
    }
    *(bf16x8*)(hi + (size_t)idx * 8) = h;
    *(bf16x8*)(lo + (size_t)idx * 8) = l;
}

// ---------------------------------------------------------------------------
// bf16 MFMA GEMM (m97 recipe) — used for out = ctx @ w_o^T
// ---------------------------------------------------------------------------
#define GBK 32

__global__ __launch_bounds__(256)
void gemm_bf16_nt(const bf16_t* __restrict__ A, const bf16_t* __restrict__ B,
                  float* __restrict__ C, int K, int lda, int ldb, int ldc) {
    __shared__ bf16_t As[128 * GBK];
    __shared__ bf16_t Bs[128 * GBK];
    const int tid = threadIdx.x;
    const int wave = tid >> 6, lane = tid & 63;
    const int quad = lane >> 4, l16 = lane & 15;
    const int bm = blockIdx.y * 128, bn = blockIdx.x * 128;
    const int wm = (wave >> 1) * 64, wn = (wave & 1) * 64;
    const int lrow = lane >> 2;
    const int lkb = (lane & 3) * 8;

    f32x4 acc[4][4];
#pragma unroll
    for (int i = 0; i < 4; ++i)
#pragma unroll
        for (int j = 0; j < 4; ++j) acc[i][j] = (f32x4){0.f, 0.f, 0.f, 0.f};

    const bf16_t* gA = A + (size_t)(bm + wave * 16 + lrow) * lda + lkb;
    const bf16_t* gB = B + (size_t)(bn + wave * 16 + lrow) * ldb + lkb;
    bf16_t* lA = &As[(wave * 16 + lrow) * GBK + lkb];
    bf16_t* lB = &Bs[(wave * 16 + lrow) * GBK + lkb];

    for (int k0 = 0; k0 < K; k0 += GBK) {
        __syncthreads();
        async_copy16(gA + k0, lA);
        async_copy16(gA + (size_t)64 * lda + k0, lA + 64 * GBK);
        async_copy16(gB + k0, lB);
        async_copy16(gB + (size_t)64 * ldb + k0, lB + 64 * GBK);
        __syncthreads();

        bf16x8 a[4], b[4];
#pragma unroll
        for (int mt = 0; mt < 4; ++mt)
            a[mt] = *(const bf16x8*)&As[(wm + mt * 16 + l16) * GBK + quad * 8];
#pragma unroll
        for (int nt = 0; nt < 4; ++nt)
            b[nt] = *(const bf16x8*)&Bs[(wn + nt * 16 + l16) * GBK + quad * 8];
#pragma unroll
        for (int mt = 0; mt < 4; ++mt)
#pragma unroll
            for (int nt = 0; nt < 4; ++nt)
                acc[mt][nt] = __builtin_amdgcn_mfma_f32_16x16x32_bf16(a[mt], b[nt], acc[mt][nt], 0, 0, 0);
    }

#pragma unroll
    for (int mt = 0; mt < 4; ++mt)
#pragma unroll
        for (int r = 0; r < 4; ++r) {
            int row = bm + wm + mt * 16 + quad * 4 + r;
            float* crow = C + (size_t)row * ldc + bn + wn;
#pragma unroll
            for (int nt = 0; nt < 4; ++nt)
                crow[nt * 16 + l16] = acc[mt][nt][r];
        }
}

// ---------------------------------------------------------------------------
// qkv GEMM with fused RoPE epilogue.
// C-layout pair (col 2i, 2i+1) sits in lanes l16^1 -> __shfl_xor(acc,1).
// q region (bn<2048): rope -> fp32 qkv.  k region: rope -> bf16 overlay.
// v region: -> bf16 overlay. fp32 k/v never written.
// ---------------------------------------------------------------------------
__global__ __launch_bounds__(256)
void gemm_qkv_rope(const bf16_t* __restrict__ A, const bf16_t* __restrict__ B,
                   float* __restrict__ qkv, bf16_t* __restrict__ qkv_bf,
                   const float* __restrict__ tab) {
    __shared__ bf16_t As[128 * GBK];
    __shared__ bf16_t Bs[128 * GBK];
    const int tid = threadIdx.x;
    const int wave = tid >> 6, lane = tid & 63;
    const int quad = lane >> 4, l16 = lane & 15;
    const int bm = blockIdx.y * 128, bn = blockIdx.x * 128;
    const int wm = (wave >> 1) * 64, wn = (wave & 1) * 64;
    const int lrow = lane >> 2;
    const int lkb = (lane & 3) * 8;

    f32x4 acc[4][4];
#pragma unroll
    for (int i = 0; i < 4; ++i)
#pragma unroll
        for (int j = 0; j < 4; ++j) acc[i][j] = (f32x4){0.f, 0.f, 0.f, 0.f};

    const bf16_t* gA = A + (size_t)(bm + wave * 16 + lrow) * 2048 + lkb;
    const bf16_t* gB = B + (size_t)(bn + wave * 16 + lrow) * 2048 + lkb;
    bf16_t* lA = &As[(wave * 16 + lrow) * GBK + lkb];
    bf16_t* lB = &Bs[(wave * 16 + lrow) * GBK + lkb];

    for (int k0 = 0; k0 < 2048; k0 += GBK) {
        __syncthreads();
        async_copy16(gA + k0, lA);
        async_copy16(gA + (size_t)64 * 2048 + k0, lA + 64 * GBK);
        async_copy16(gB + k0, lB);
        async_copy16(gB + (size_t)64 * 2048 + k0, lB + 64 * GBK);
        __syncthreads();

        bf16x8 a[4], b[4];
#pragma unroll
        for (int mt = 0; mt < 4; ++mt)
            a[mt] = *(const bf16x8*)&As[(wm + mt * 16 + l16) * GBK + quad * 8];
#pragma unroll
        for (int nt = 0; nt < 4; ++nt)
            b[nt] = *(const bf16x8*)&Bs[(wn + nt * 16 + l16) * GBK + quad * 8];
#pragma unroll
        for (int mt = 0; mt < 4; ++mt)
#pragma unroll
            for (int nt = 0; nt < 4; ++nt)
                acc[mt][nt] = __builtin_amdgcn_mfma_f32_16x16x32_bf16(a[mt], b[nt], acc[mt][nt], 0, 0, 0);
    }

    const int colbase = bn + wn;            // block-uniform region
    const int region = colbase >> 11;       // 0=q, 1=k, 2=v
    const bool odd = (l16 & 1);

    if (region == 2) {
        // v: straight bf16 overlay store
#pragma unroll
        for (int mt = 0; mt < 4; ++mt)
#pragma unroll
            for (int r = 0; r < 4; ++r) {
                int t = bm + wm + mt * 16 + quad * 4 + r;
                bf16_t* brow = qkv_bf + (size_t)t * ROW_BF + VB_OFF + (colbase - 4096) + wn * 0;
#pragma unroll
                for (int nt = 0; nt < 4; ++nt)
                    brow[nt * 16 + l16] = (bf16_t)acc[mt][nt][r];
            }
    } else {
#pragma unroll
        for (int mt = 0; mt < 4; ++mt)
#pragma unroll
            for (int r = 0; r < 4; ++r) {
                int t = bm + wm + mt * 16 + quad * 4 + r;
                const float* trow = tab + t * 128;
#pragma unroll
                for (int nt = 0; nt < 4; ++nt) {
                    float v = acc[mt][nt][r];
                    float vp = __shfl_xor(v, 1);    // pair column value
                    int col = colbase + nt * 16 + l16;
                    int j = col & 63;
                    float c = trow[j], s = trow[64 + j];
                    float y = odd ? (v * c + vp * s) : (v * c - vp * s);
                    if (region == 0)
                        qkv[(size_t)t * QKV_LD + col] = y;
                    else
                        qkv_bf[(size_t)t * ROW_BF + KB_OFF + (col - 2048)] = (bf16_t)y;
                }
            }
    }
}

// ---------------------------------------------------------------------------
// Split-bf16 (3x bf16-MFMA) GEMM for the gate-critical info MLP.
// ---------------------------------------------------------------------------
__global__ __launch_bounds__(256)
void info_gemm_mfma(const bf16_t* __restrict__ Ahi, const bf16_t* __restrict__ Alo,
                    const bf16_t* __restrict__ Bhi, const bf16_t* __restrict__ Blo,
                    float* __restrict__ Cpart) {
    __shared__ bf16_t Ah[128 * GBK];
    __shared__ bf16_t Al[128 * GBK];
    __shared__ bf16_t Bh[128 * GBK];
    __shared__ bf16_t Bl[128 * GBK];
    const int tid = threadIdx.x;
    const int wave = tid >> 6, lane = tid & 63;
    const int quad = lane >> 4, l16 = lane & 15;
    const int bm = blockIdx.y * 128, bn = blockIdx.x * 128;
    const int ks = blockIdx.z;
    const int wm = (wave >> 1) * 64, wn = (wave & 1) * 64;
    const int lrow = lane >> 2;
    const int lkb = (lane & 3) * 8;
    const int kbeg = ks * 512;

    f32x4 acc[4][4];
#pragma unroll
    for (int i = 0; i < 4; ++i)
#pragma unroll
        for (int j = 0; j < 4; ++j) acc[i][j] = (f32x4){0.f, 0.f, 0.f, 0.f};

    const size_t aoff = (size_t)(bm + wave * 16 + lrow) * 2048 + lkb + kbeg;
    const size_t boff = (size_t)(bn + wave * 16 + lrow) * 2048 + lkb + kbeg;
    bf16_t* lAh = &Ah[(wave * 16 + lrow) * GBK + lkb];
    bf16_t* lAl = &Al[(wave * 16 + lrow) * GBK + lkb];
    bf16_t* lBh = &Bh[(wave * 16 + lrow) * GBK + lkb];
    bf16_t* lBl = &Bl[(wave * 16 + lrow) * GBK + lkb];

    for (int k0 = 0; k0 < 512; k0 += GBK) {
        __syncthreads();
        async_copy16(Ahi + aoff + k0, lAh);
        async_copy16(Ahi + aoff + (size_t)64 * 2048 + k0, lAh + 64 * GBK);
        async_copy16(Alo + aoff + k0, lAl);
        async_copy16(Alo + aoff + (size_t)64 * 2048 + k0, lAl + 64 * GBK);
        async_copy16(Bhi + boff + k0, lBh);
        async_copy16(Bhi + boff + (size_t)64 * 2048 + k0, lBh + 64 * GBK);
        async_copy16(Blo + boff + k0, lBl);
        async_copy16(Blo + boff + (size_t)64 * 2048 + k0, lBl + 64 * GBK);
        __syncthreads();

        bf16x8 ah[4], al[4], bh[4], bl[4];
#pragma unroll
        for (int mt = 0; mt < 4; ++mt) {
            ah[mt] = *(const bf16x8*)&Ah[(wm + mt * 16 + l16) * GBK + quad * 8];
            al[mt] = *(const bf16x8*)&Al[(wm + mt * 16 + l16) * GBK + quad * 8];
        }
#pragma unroll
        for (int nt = 0; nt < 4; ++nt) {
            bh[nt] = *(const bf16x8*)&Bh[(wn + nt * 16 + l16) * GBK + quad * 8];
            bl[nt] = *(const bf16x8*)&Bl[(wn + nt * 16 + l16) * GBK + quad * 8];
        }
#pragma unroll
        for (int mt = 0; mt < 4; ++mt)
#pragma unroll
            for (int nt = 0; nt < 4; ++nt) {
                acc[mt][nt] = __builtin_amdgcn_mfma_f32_16x16x32_bf16(ah[mt], bh[nt], acc[mt][nt], 0, 0, 0);
                acc[mt][nt] = __builtin_amdgcn_mfma_f32_16x16x32_bf16(ah[mt], bl[nt], acc[mt][nt], 0, 0, 0);
                acc[mt][nt] = __builtin_amdgcn_mfma_f32_16x16x32_bf16(al[mt], bh[nt], acc[mt][nt], 0, 0, 0);
            }
    }

    float* cp = Cpart + (size_t)ks * 2048 * 512;
#pragma unroll
    for (int mt = 0; mt < 4; ++mt)
#pragma unroll
        for (int r = 0; r < 4; ++r) {
            int row = bm + wm + mt * 16 + quad * 4 + r;
            float* crow = cp + (size_t)row * 512 + bn + wn;
#pragma unroll
            for (int nt = 0; nt < 4; ++nt)
                crow[nt * 16 + l16] = acc[mt][nt][r];
        }
}

__device__ __forceinline__ float gelu_exact(float v) {
    return 0.5f * v * (1.0f + erff(v * 0.70710678118654752f));
}

// ---------------------------------------------------------------------------
// Fused: reduce 4 split-K partials + gelu + dot(w2) + sigmoid -> gate[t].
// One wave per token; fixed summation order (deterministic, fp32).
// ---------------------------------------------------------------------------
__global__ __launch_bounds__(64)
void info_gate_kernel(const float* __restrict__ Cpart, const float* __restrict__ w2,
                      float* __restrict__ gate) {
    const int t = blockIdx.x;
    const int lane = threadIdx.x;
    const float* p0 = Cpart + (size_t)t * 512;
    float s = 0.f;
#pragma unroll
    for (int i = lane; i < 512; i += 64) {
        float v = ((p0[i] + p0[i + 1048576]) + p0[i + 2097152]) + p0[i + 3145728];
        s += gelu_exact(v) * w2[i];
    }
#pragma unroll
    for (int off = 32; off > 0; off >>= 1) s += __shfl_down(s, off);
    if (lane == 0) {
        float sig = 1.f / (1.f + expf(-s));
        gate[t] = (sig > 0.75f) ? 1.f : 0.f;
    }
}

// ---------------------------------------------------------------------------
// RoPE tables: tab[t*128 + j] = cos(t*invf[j]); +64: sin
// ---------------------------------------------------------------------------
__global__ __launch_bounds__(256)
void rope_table_kernel(float* __restrict__ tab) {
    int idx = blockIdx.x * 256 + threadIdx.x;
    int t = idx >> 6, j = idx & 63;
    float inv = expf(-(float)j * LOG1E4_OVER_64);
    float s, c;
    sincosf((float)t * inv, &s, &c);
    tab[t * 128 + j] = c;
    tab[t * 128 + 64 + j] = s;
}

// ---------------------------------------------------------------------------
// MFMA kvr: K/V from bf16 overlays, Q from fp32 (roped by gemm epilogue).
// ---------------------------------------------------------------------------
#define KV_LD 136

__global__ __launch_bounds__(256)
void kvr_mfma_kernel(const float* __restrict__ qkv, const bf16_t* __restrict__ qkv_bf,
                     const float* __restrict__ pk, const float* __restrict__ pv,
                     float* __restrict__ kr, float* __restrict__ vr,
                     bf16_t* __restrict__ qr) {
    __shared__ bf16_t Kt[64 * KV_LD];
    __shared__ bf16_t Vt[64 * KV_LD];
    __shared__ bf16_t Qt[64 * KV_LD];
    __shared__ bf16_t Pk[64 * KV_LD];
    __shared__ bf16_t Pv[64 * KV_LD];

    const int h = blockIdx.y;
    const int s0 = blockIdx.x * 64;
    const int tid = threadIdx.x;
    const int wave = tid >> 6, lane = tid & 63;
    const int quad = lane >> 4, l16 = lane & 15;

#pragma unroll
    for (int i = 0; i < 4; ++i) {
        int gid = i * 256 + tid;
        int row = gid >> 4, ch = (gid & 15) << 3;
        const bf16_t* rb = qkv_bf + (size_t)(s0 + row) * ROW_BF + h * HD + ch;
        *(bf16x8*)&Kt[row * KV_LD + ch] = *(const bf16x8*)(rb + KB_OFF);
        *(bf16x8*)&Vt[row * KV_LD + ch] = *(const bf16x8*)(rb + VB_OFF);
    }
#pragma unroll
    for (int i = 0; i < 8; ++i) {
        int gid = i * 256 + tid;
        int row = gid >> 5, c = (gid & 31) << 2;
        float4 vq = *(const float4*)(qkv + (size_t)(s0 + row) * QKV_LD + h * HD + c);
        bf16x4 pq;
        pq[0] = (bf16_t)vq.x; pq[1] = (bf16_t)vq.y; pq[2] = (bf16_t)vq.z; pq[3] = (bf16_t)vq.w;
        *(bf16x4*)&Qt[row * KV_LD + c] = pq;
        float4 wk = *(const float4*)(pk + (size_t)row * HD + c);
        float4 wv = *(const float4*)(pv + (size_t)row * HD + c);
        bf16x4 qk4, qv4;
        qk4[0] = (bf16_t)wk.x; qk4[1] = (bf16_t)wk.y; qk4[2] = (bf16_t)wk.z; qk4[3] = (bf16_t)wk.w;
        qv4[0] = (bf16_t)wv.x; qv4[1] = (bf16_t)wv.y; qv4[2] = (bf16_t)wv.z; qv4[3] = (bf16_t)wv.w;
        *(bf16x4*)&Pk[row * KV_LD + c] = qk4;
        *(bf16x4*)&Pv[row * KV_LD + c] = qv4;
    }
    __syncthreads();

    f32x4 ak[4], av[4], aq[4];
#pragma unroll
    for (int nt = 0; nt < 4; ++nt) {
        ak[nt] = (f32x4){0.f, 0.f, 0.f, 0.f};
        av[nt] = (f32x4){0.f, 0.f, 0.f, 0.f};
        aq[nt] = (f32x4){0.f, 0.f, 0.f, 0.f};
    }

#pragma unroll
    for (int ks = 0; ks < 4; ++ks) {
        const int ao = (wave * 16 + l16) * KV_LD + ks * 32 + quad * 8;
        bf16x8 a_k = *(const bf16x8*)&Kt[ao];
        bf16x8 a_v = *(const bf16x8*)&Vt[ao];
        bf16x8 a_q = *(const bf16x8*)&Qt[ao];
#pragma unroll
        for (int nt = 0; nt < 4; ++nt) {
            const int bo = (nt * 16 + l16) * KV_LD + ks * 32 + quad * 8;
            bf16x8 bk = *(const bf16x8*)&Pk[bo];
            bf16x8 bv = *(const bf16x8*)&Pv[bo];
            ak[nt] = __builtin_amdgcn_mfma_f32_16x16x32_bf16(a_k, bk, ak[nt], 0, 0, 0);
            av[nt] = __builtin_amdgcn_mfma_f32_16x16x32_bf16(a_v, bv, av[nt], 0, 0, 0);
            aq[nt] = __builtin_amdgcn_mfma_f32_16x16x32_bf16(a_q, bk, aq[nt], 0, 0, 0);
        }
    }

#pragma unroll
    for (int nt = 0; nt < 4; ++nt)
#pragma unroll
        for (int r = 0; r < 4; ++r) {
            int s = s0 + wave * 16 + quad * 4 + r;
            size_t idx = ((size_t)h * T_LEN + s) * RANK + nt * 16 + l16;
            kr[idx] = ak[nt][r];
            vr[idx] = av[nt][r];
            qr[idx] = (bf16_t)aq[nt][r];
        }
}

// ---------------------------------------------------------------------------
// MFMA bf16 flash local attention (R7-verified v2)
// ---------------------------------------------------------------------------
#define QTI 64
#define KTI 64
#define QS_LD 136
#define VT_LD 68
#define PS_LD 72

__global__ __launch_bounds__(256)
void local_attn_kernel(const float* __restrict__ qkv, const bf16_t* __restrict__ qkv_bf,
                       bf16_t* __restrict__ cxb) {
    __shared__ bf16_t Qs[QTI * QS_LD];
    __shared__ bf16_t Ks[KTI * HD];
    __shared__ bf16_t Vt[HD * VT_LD];
    __shared__ bf16_t Ps[4][16 * PS_LD];

    const int h = blockIdx.y;
    const int t0 = blockIdx.x * QTI;
    const int tid = threadIdx.x;
    const int wave = tid >> 6, lane = tid & 63;
    const int quad = lane >> 4, l16 = lane & 15;

#pragma unroll
    for (int i = 0; i < 8; ++i) {
        int gid = i * 256 + tid;
        int row = gid >> 5, c4 = (gid & 31) << 2;
        const float4 v = *(const float4*)(qkv + (size_t)(t0 + row) * QKV_LD + h * HD + c4);
        bf16x4 p;
        p[0] = (bf16_t)(v.x * SCALE); p[1] = (bf16_t)(v.y * SCALE);
        p[2] = (bf16_t)(v.z * SCALE); p[3] = (bf16_t)(v.w * SCALE);
        *(bf16x4*)&Qs[row * QS_LD + c4] = p;
    }

    f32x4 o[8];
#pragma unroll
    for (int d8 = 0; d8 < 8; ++d8) o[d8] = (f32x4){0.f, 0.f, 0.f, 0.f};
    float m_i[4] = {-1e30f, -1e30f, -1e30f, -1e30f};
    float l_i[4] = {0.f, 0.f, 0.f, 0.f};

    __syncthreads();

    for (int kt = 0; kt < 9; ++kt) {
        const int sbase = t0 - 512 + kt * KTI;
        if (sbase < 0) continue;
        __syncthreads();
#pragma unroll
        for (int i = 0; i < 4; ++i) {
            int s = i * 256 + tid;
            int row = s >> 4, ch = s & 15;
            int gch = ch ^ (row & 7);
            const bf16_t* src = qkv_bf + (size_t)(sbase + row) * ROW_BF + KB_OFF + h * HD + gch * 8;
            async_copy16(src, &Ks[s * 8]);
        }
#pragma unroll
        for (int i = 0; i < 8; ++i) {
            int gid = i * 256 + tid;
            int row = gid >> 5, c4 = (gid & 31) << 2;
            bf16x4 vv = *(const bf16x4*)(qkv_bf + (size_t)(sbase + row) * ROW_BF + VB_OFF + h * HD + c4);
            Vt[(c4 + 0) * VT_LD + row] = vv[0];
            Vt[(c4 + 1) * VT_LD + row] = vv[1];
            Vt[(c4 + 2) * VT_LD + row] = vv[2];
            Vt[(c4 + 3) * VT_LD + row] = vv[3];
        }
        __syncthreads();

        f32x4 sacc[4];
#pragma unroll
        for (int nt = 0; nt < 4; ++nt) sacc[nt] = (f32x4){0.f, 0.f, 0.f, 0.f};
#pragma unroll
        for (int ks = 0; ks < 4; ++ks) {
            bf16x8 a = *(const bf16x8*)&Qs[(wave * 16 + l16) * QS_LD + ks * 32 + quad * 8];
#pragma unroll
            for (int nt = 0; nt < 4; ++nt) {
                int r = nt * 16 + l16;
                int ch = (ks * 4 + quad) ^ (r & 7);
                bf16x8 b = *(const bf16x8*)&Ks[r * HD + ch * 8];
                sacc[nt] = __builtin_amdgcn_mfma_f32_16x16x32_bf16(a, b, sacc[nt], 0, 0, 0);
            }
        }

#pragma unroll
        for (int nt = 0; nt < 4; ++nt) {
            int s_g = sbase + nt * 16 + l16;
#pragma unroll
            for (int r = 0; r < 4; ++r) {
                int t_g = t0 + wave * 16 + quad * 4 + r;
                bool valid = (s_g <= t_g) && (s_g + W_LOCAL > t_g);
                if (!valid) sacc[nt][r] = -1e30f;
            }
        }

#pragma unroll
        for (int r = 0; r < 4; ++r) {
            float mx = fmaxf(fmaxf(sacc[0][r], sacc[1][r]), fmaxf(sacc[2][r], sacc[3][r]));
            mx = fmaxf(mx, __shfl_xor(mx, 1));
            mx = fmaxf(mx, __shfl_xor(mx, 2));
            mx = fmaxf(mx, __shfl_xor(mx, 4));
            mx = fmaxf(mx, __shfl_xor(mx, 8));
            float mnew = fmaxf(m_i[r], mx);
            float alpha = __expf(m_i[r] - mnew);
            m_i[r] = mnew;
            float rs = 0.f;
#pragma unroll
            for (int nt = 0; nt < 4; ++nt) {
                float p = __expf(sacc[nt][r] - mnew);
                sacc[nt][r] = p;
                rs += p;
            }
            rs += __shfl_xor(rs, 1);
            rs += __shfl_xor(rs, 2);
            rs += __shfl_xor(rs, 4);
            rs += __shfl_xor(rs, 8);
            l_i[r] = l_i[r] * alpha + rs;
#pragma unroll
            for (int d8 = 0; d8 < 8; ++d8) o[d8][r] *= alpha;
        }

#pragma unroll
        for (int r = 0; r < 4; ++r)
#pragma unroll
            for (int nt = 0; nt < 4; ++nt)
                Ps[wave][(quad * 4 + r) * PS_LD + nt * 16 + l16] = (bf16_t)sacc[nt][r];

#pragma unroll
        for (int ks2 = 0; ks2 < 2; ++ks2) {
            bf16x8 a = *(const bf16x8*)&Ps[wave][l16 * PS_LD + ks2 * 32 + quad * 8];
#pragma unroll
            for (int d8 = 0; d8 < 8; ++d8) {
                const bf16_t* vb = &Vt[(d8 * 16 + l16) * VT_LD + ks2 * 32 + quad * 8];
                bf16x4 b0 = *(const bf16x4*)vb;
                bf16x4 b1 = *(const bf16x4*)(vb + 4);
                bf16x8 b;
                b[0] = b0[0]; b[1] = b0[1]; b[2] = b0[2]; b[3] = b0[3];
                b[4] = b1[0]; b[5] = b1[1]; b[6] = b1[2]; b[7] = b1[3];
                o[d8] = __builtin_amdgcn_mfma_f32_16x16x32_bf16(a, b, o[d8], 0, 0, 0);
            }
        }
    }

#pragma unroll
    for (int r = 0; r < 4; ++r) {
        float inv = 1.0f / l_i[r];
        size_t rowoff = (size_t)(t0 + wave * 16 + quad * 4 + r) * 2048 + h * HD;
#pragma unroll
        for (int d8 = 0; d8 < 8; ++d8)
            cxb[rowoff + d8 * 16 + l16] = (bf16_t)(o[d8][r] * inv);
    }
}

// ---------------------------------------------------------------------------
// Gated global low-rank branch (early-exit when gate==0); bf16 RMW into cxb
// ---------------------------------------------------------------------------
__device__ __forceinline__ float block_reduce_max512(float v, float* red, int tid) {
    red[tid] = v; __syncthreads();
    for (int s = 256; s > 0; s >>= 1) {
        if (tid < s) red[tid] = fmaxf(red[tid], red[tid + s]);
        __syncthreads();
    }
    float r = red[0]; __syncthreads();
    return r;
}
__device__ __forceinline__ float block_reduce_sum512(float v, float* red, int tid) {
    red[tid] = v; __syncthreads();
    for (int s = 256; s > 0; s >>= 1) {
        if (tid < s) red[tid] = red[tid] + red[tid + s];
        __syncthreads();
    }
    float r = red[0]; __syncthreads();
    return r;
}

__global__ __launch_bounds__(512)
void global_attn_kernel(bf16_t* __restrict__ cxb, const float* __restrict__ kr,
                        const float* __restrict__ vr, const bf16_t* __restrict__ qr,
                        const float* __restrict__ uo, const float* __restrict__ gate) {
    const int t = blockIdx.x, h = blockIdx.y;
    if (gate[t] <= 0.5f) return;

    __shared__ float qrs[64];
    __shared__ float red[512];
    __shared__ float cgr[64];
    __shared__ float sg[2048];
    const int tid = threadIdx.x;

    if (tid < 64) qrs[tid] = (float)qr[((size_t)h * T_LEN + t) * RANK + tid];
    __syncthreads();

    const float* krh = kr + (size_t)h * T_LEN * RANK;
    const float* vrh = vr + (size_t)h * T_LEN * RANK;
    float lmax = -INFINITY;
    for (int s = tid; s < T_LEN; s += 512) {
        const float* krr = krh + (size_t)s * RANK;
        float acc = 0.f;
#pragma unroll
        for (int r = 0; r < RANK; r += 4) {
            float4 k4 = *(const float4*)(krr + r);
            acc += qrs[r] * k4.x + qrs[r + 1] * k4.y + qrs[r + 2] * k4.z + qrs[r + 3] * k4.w;
        }
        float sc = acc * SCALE_G;
        sg[s] = sc;
        lmax = fmaxf(lmax, sc);
    }
    float gmx = block_reduce_max512(lmax, red, tid);
    float lsum = 0.f;
    for (int s = tid; s < T_LEN; s += 512) {
        float pp = expf(sg[s] - gmx);
        sg[s] = pp;
        lsum += pp;
    }
    float gsum = block_reduce_sum512(lsum, red, tid);

    {
        const int r = tid & 63, part = tid >> 6;
        float pacc = 0.f;
        for (int s = part; s < T_LEN; s += 8) pacc += sg[s] * vrh[(size_t)s * RANK + r];
        red[tid] = pacc;
        __syncthreads();
        if (tid < 64) {
            float c = 0.f;
#pragma unroll
            for (int pp = 0; pp < 8; ++pp) c += red[pp * 64 + tid];
            cgr[tid] = c / gsum;
        }
        __syncthreads();
    }

    if (tid < 128) {
        float cg = 0.f;
#pragma unroll
        for (int r = 0; r < RANK; ++r) cg += cgr[r] * uo[tid * RANK + r];
        size_t off = (size_t)t * 2048 + h * HD + tid;
        cxb[off] = (bf16_t)((float)cxb[off] + cg);
    }
}

// ---------------------------------------------------------------------------
extern "C" void kernel_launch(void* const* d_in, const int* in_sizes, int n_in,
                              void* d_out, int out_size, void* d_ws, size_t ws_size,
                              hipStream_t stream) {
    const float* x     = (const float*)d_in[0];
    const float* w_qkv = (const float*)d_in[1];
    const float* w_o   = (const float*)d_in[2];
    const float* pk    = (const float*)d_in[3];
    const float* pv    = (const float*)d_in[4];
    const float* uo    = (const float*)d_in[5];
    const float* w1    = (const float*)d_in[6];
    const float* w2    = (const float*)d_in[7];
    float* out = (float*)d_out;

    // Workspace layout (floats), lifetime-aliased (~84 MB):
    float* ws = (float*)d_ws;
    float* qkv   = ws;                        // 12,582,912 f (pre-GEMM: info scratch;
                                              //  k/v rows carry bf16 overlays post-GEMM)
    float* hinfo = qkv + (size_t)12582912;    // 1,048,576 f: rope tab, later qr bf16
    float* gatep = hinfo + (size_t)1048576;   // 2048 f
    bf16_t* xb   = (bf16_t*)(gatep + 2048);   // x_hi bf16 (later ctx bf16)
    float* wqbf  = gatep + 2048 + 2097152;    // 6,291,456 f region:
    bf16_t* wqb  = (bf16_t*)wqbf;             //   w_qkv bf16 (entire region)
    float* krp   = wqbf;                      //   later: kr
    float* vrp   = wqbf + (size_t)2097152;    //   later: vr
    bf16_t* wob  = (bf16_t*)krp;              //   later still: w_o bf16 (after global_attn)
    float* tabp  = hinfo;                     // rope tables (262,144 f; dead before qr)
    bf16_t* qrp  = (bf16_t*)hinfo;            // qr bf16 (written by kvr, after gemm)
    bf16_t* cxb  = xb;                        // ctx bf16
    bf16_t* qkvb = (bf16_t*)qkv;              // bf16 overlay view of qkv rows
    // Info-MLP scratch inside the pre-GEMM qkv region:
    float* ipart  = qkv;                          // 4x2048x512 f
    bf16_t* xlo   = (bf16_t*)(qkv + 4194304);
    bf16_t* w1hi  = (bf16_t*)(qkv + 6291456);
    bf16_t* w1lo  = (bf16_t*)(qkv + 6815744);

    // 1) split-bf16 conversions
    conv_split_bf16<<<2048, 256, 0, stream>>>(x, xb, xlo, 524288);
    conv_split_bf16<<<512, 256, 0, stream>>>(w1, w1hi, w1lo, 131072);
    // 2) info MLP (3x bf16 MFMA split-K) -> fused reduce+gelu+gate
    info_gemm_mfma<<<dim3(4, 16, 4), 256, 0, stream>>>(xb, xlo, w1hi, w1lo, ipart);
    info_gate_kernel<<<T_LEN, 64, 0, stream>>>(ipart, w2, gatep);
    // 3) rope table (into hinfo region), w_qkv -> bf16
    rope_table_kernel<<<512, 256, 0, stream>>>(tabp);
    conv_f32_bf16<<<6144, 256, 0, stream>>>(w_qkv, wqb, 2048, 2048, 6144);
    // 4) qkv GEMM with fused RoPE epilogue: q fp32 roped, k/v bf16 overlays
    gemm_qkv_rope<<<dim3(48, 16), 256, 0, stream>>>(xb, wqb, qkv, qkvb, tabp);
    // 5) k_r, v_r, q_r via MFMA (qr overwrites dead tab region)
    kvr_mfma_kernel<<<dim3(T_LEN / 64, NH), 256, 0, stream>>>(qkv, qkvb, pk, pv, krp, vrp, qrp);
    // 6) flash local attention -> ctx bf16 (cxb)
    local_attn_kernel<<<dim3(T_LEN / QTI, NH), 256, 0, stream>>>(qkv, qkvb, cxb);
    // 7) gated global branch (bf16 RMW into cxb)
    global_attn_kernel<<<dim3(T_LEN, NH), 512, 0, stream>>>(cxb, krp, vrp, qrp, uo, gatep);
    // 8) w_o -> bf16 (aliases kr: after global_attn), out = ctx @ w_o^T
    conv_f32_bf16<<<2048, 256, 0, stream>>>(w_o, wob, 2048, 2048, 2048);
    gemm_bf16_nt<<<dim3(16, 16), 256, 0, stream>>>(cxb, wob, out, 2048, 2048, 2048, 2048);
}

// Round 9
// 358.116 us; speedup vs baseline: 10.8490x; 1.0399x over previous
//
#include <hip/hip_runtime.h>
#include <hip/hip_bf16.h>
#include <math.h>

// Problem constants
#define T_LEN 2048
#define C_DIM 2048
#define NH 16
#define HD 128
#define RANK 64
#define W_LOCAL 512
#define QKV_LD 6144
#define ROW_BF 12288          // qkv row stride in bf16 elems
#define KB_OFF 4096           // bf16-elem offset of packed K overlay within row
#define VB_OFF 8192           // bf16-elem offset of packed V overlay within row
#define WO_OFF 6144           // bf16-elem offset of packed w_o row within qkv row
#define SCALE 0.08838834764831845f    // 1/sqrt(128)
#define SCALE_G 0.17677669529663687f  // scale * 128/64
#define LOG1E4_OVER_64 0.14391156831212787f

typedef __bf16 bf16_t;
typedef __bf16 bf16x8 __attribute__((ext_vector_type(8)));
typedef __bf16 bf16x4 __attribute__((ext_vector_type(4)));
typedef float f32x4 __attribute__((ext_vector_type(4)));

// ---------------------------------------------------------------------------
// async 16B global -> LDS (gfx950). LDS dst must be wave-uniform base+lane*16.
// ---------------------------------------------------------------------------
__device__ __forceinline__ void async_copy16(const bf16_t* g, bf16_t* l) {
    __builtin_amdgcn_global_load_lds(
        (const __attribute__((address_space(1))) unsigned int*)g,
        (__attribute__((address_space(3))) unsigned int*)l, 16, 0, 0);
}

// ---------------------------------------------------------------------------
// Merged prep kernel (block-range dispatch):
//  [0,2048):    x -> (xb, xlo) split-bf16
//  [2048,2560): w1 -> (w1hi, w1lo) split-bf16
//  [2560,8704): w_qkv -> wqb bf16
//  [8704,9216): rope tables
// ---------------------------------------------------------------------------
__global__ __launch_bounds__(256)
void prep_kernel(const float* __restrict__ x, bf16_t* __restrict__ xb,
                 bf16_t* __restrict__ xlo,
                 const float* __restrict__ w1, bf16_t* __restrict__ w1hi,
                 bf16_t* __restrict__ w1lo,
                 const float* __restrict__ w_qkv, bf16_t* __restrict__ wqb,
                 float* __restrict__ tab) {
    const int bid = blockIdx.x;
    const int tid = threadIdx.x;
    if (bid < 2560) {
        // split-bf16: x (blocks [0,2048)) or w1 (blocks [2048,2560))
        const float* in;
        bf16_t *hi, *lo;
        int idx;
        if (bid < 2048) { in = x; hi = xb; lo = xlo; idx = bid * 256 + tid; }
        else            { in = w1; hi = w1hi; lo = w1lo; idx = (bid - 2048) * 256 + tid; }
        const float* p = in + (size_t)idx * 8;
        float4 v0 = *(const float4*)p;
        float4 v1 = *(const float4*)(p + 4);
        float v[8] = {v0.x, v0.y, v0.z, v0.w, v1.x, v1.y, v1.z, v1.w};
        bf16x8 h, l;
#pragma unroll
        for (int i = 0; i < 8; ++i) {
            bf16_t hb = (bf16_t)v[i];
            h[i] = hb;
            l[i] = (bf16_t)(v[i] - (float)hb);
        }
        *(bf16x8*)(hi + (size_t)idx * 8) = h;
        *(bf16x8*)(lo + (size_t)idx * 8) = l;
    } else if (bid < 8704) {
        // w_qkv fp32 -> bf16 (6144x2048)
        int idx = (bid - 2560) * 256 + tid;          // 8 elems each
        const float* p = w_qkv + (size_t)idx * 8;
        float4 v0 = *(const float4*)p;
        float4 v1 = *(const float4*)(p + 4);
        bf16x8 o;
        o[0] = (bf16_t)v0.x; o[1] = (bf16_t)v0.y; o[2] = (bf16_t)v0.z; o[3] = (bf16_t)v0.w;
        o[4] = (bf16_t)v1.x; o[5] = (bf16_t)v1.y; o[6] = (bf16_t)v1.z; o[7] = (bf16_t)v1.w;
        *(bf16x8*)(wqb + (size_t)idx * 8) = o;
    } else {
        // rope tables
        int idx = (bid - 8704) * 256 + tid;          // 2048*64
        int t = idx >> 6, j = idx & 63;
        float inv = expf(-(float)j * LOG1E4_OVER_64);
        float s, c;
        sincosf((float)t * inv, &s, &c);
        tab[t * 128 + j] = c;
        tab[t * 128 + 64 + j] = s;
    }
}

// ---------------------------------------------------------------------------
// bf16 MFMA GEMM (m97 recipe) — used for out = ctx @ w_o^T
// ---------------------------------------------------------------------------
#define GBK 32

__global__ __launch_bounds__(256)
void gemm_bf16_nt(const bf16_t* __restrict__ A, const bf16_t* __restrict__ B,
                  float* __restrict__ C, int K, int lda, int ldb, int ldc) {
    __shared__ bf16_t As[128 * GBK];
    __shared__ bf16_t Bs[128 * GBK];
    const int tid = threadIdx.x;
    const int wave = tid >> 6, lane = tid & 63;
    const int quad = lane >> 4, l16 = lane & 15;
    const int bm = blockIdx.y * 128, bn = blockIdx.x * 128;
    const int wm = (wave >> 1) * 64, wn = (wave & 1) * 64;
    const int lrow = lane >> 2;
    const int lkb = (lane & 3) * 8;

    f32x4 acc[4][4];
#pragma unroll
    for (int i = 0; i < 4; ++i)
#pragma unroll
        for (int j = 0; j < 4; ++j) acc[i][j] = (f32x4){0.f, 0.f, 0.f, 0.f};

    const bf16_t* gA = A + (size_t)(bm + wave * 16 + lrow) * lda + lkb;
    const bf16_t* gB = B + (size_t)(bn + wave * 16 + lrow) * ldb + lkb;
    bf16_t* lA = &As[(wave * 16 + lrow) * GBK + lkb];
    bf16_t* lB = &Bs[(wave * 16 + lrow) * GBK + lkb];

    for (int k0 = 0; k0 < K; k0 += GBK) {
        __syncthreads();
        async_copy16(gA + k0, lA);
        async_copy16(gA + (size_t)64 * lda + k0, lA + 64 * GBK);
        async_copy16(gB + k0, lB);
        async_copy16(gB + (size_t)64 * ldb + k0, lB + 64 * GBK);
        __syncthreads();

        bf16x8 a[4], b[4];
#pragma unroll
        for (int mt = 0; mt < 4; ++mt)
            a[mt] = *(const bf16x8*)&As[(wm + mt * 16 + l16) * GBK + quad * 8];
#pragma unroll
        for (int nt = 0; nt < 4; ++nt)
            b[nt] = *(const bf16x8*)&Bs[(wn + nt * 16 + l16) * GBK + quad * 8];
#pragma unroll
        for (int mt = 0; mt < 4; ++mt)
#pragma unroll
            for (int nt = 0; nt < 4; ++nt)
                acc[mt][nt] = __builtin_amdgcn_mfma_f32_16x16x32_bf16(a[mt], b[nt], acc[mt][nt], 0, 0, 0);
    }

#pragma unroll
    for (int mt = 0; mt < 4; ++mt)
#pragma unroll
        for (int r = 0; r < 4; ++r) {
            int row = bm + wm + mt * 16 + quad * 4 + r;
            float* crow = C + (size_t)row * ldc + bn + wn;
#pragma unroll
            for (int nt = 0; nt < 4; ++nt)
                crow[nt * 16 + l16] = acc[mt][nt][r];
        }
}

// ---------------------------------------------------------------------------
// qkv GEMM with fused RoPE epilogue + piggy-backed w_o conversion blocks.
// Blocks [0,768): GEMM (bx=id%48, by=id/48).
// Blocks [768,2816): convert w_o row (id-768) -> bf16 at qkv row free chunk
//   [WO_OFF, WO_OFF+2048) (never touched by gemm epilogue or attention).
// ---------------------------------------------------------------------------
__global__ __launch_bounds__(256)
void gemm_qkv_rope(const bf16_t* __restrict__ A, const bf16_t* __restrict__ B,
                   float* __restrict__ qkv, bf16_t* __restrict__ qkv_bf,
                   const float* __restrict__ tab, const float* __restrict__ w_o) {
    const int bid = blockIdx.x;
    const int tid = threadIdx.x;
    if (bid >= 768) {
        // w_o conversion: one row per block
        int row = bid - 768;
        int c = tid * 8;
        const float* p = w_o + (size_t)row * 2048 + c;
        float4 v0 = *(const float4*)p;
        float4 v1 = *(const float4*)(p + 4);
        bf16x8 o;
        o[0] = (bf16_t)v0.x; o[1] = (bf16_t)v0.y; o[2] = (bf16_t)v0.z; o[3] = (bf16_t)v0.w;
        o[4] = (bf16_t)v1.x; o[5] = (bf16_t)v1.y; o[6] = (bf16_t)v1.z; o[7] = (bf16_t)v1.w;
        *(bf16x8*)(qkv_bf + (size_t)row * ROW_BF + WO_OFF + c) = o;
        return;
    }

    __shared__ bf16_t As[128 * GBK];
    __shared__ bf16_t Bs[128 * GBK];
    const int wave = tid >> 6, lane = tid & 63;
    const int quad = lane >> 4, l16 = lane & 15;
    const int bm = (bid / 48) * 128, bn = (bid % 48) * 128;
    const int wm = (wave >> 1) * 64, wn = (wave & 1) * 64;
    const int lrow = lane >> 2;
    const int lkb = (lane & 3) * 8;

    f32x4 acc[4][4];
#pragma unroll
    for (int i = 0; i < 4; ++i)
#pragma unroll
        for (int j = 0; j < 4; ++j) acc[i][j] = (f32x4){0.f, 0.f, 0.f, 0.f};

    const bf16_t* gA = A + (size_t)(bm + wave * 16 + lrow) * 2048 + lkb;
    const bf16_t* gB = B + (size_t)(bn + wave * 16 + lrow) * 2048 + lkb;
    bf16_t* lA = &As[(wave * 16 + lrow) * GBK + lkb];
    bf16_t* lB = &Bs[(wave * 16 + lrow) * GBK + lkb];

    for (int k0 = 0; k0 < 2048; k0 += GBK) {
        __syncthreads();
        async_copy16(gA + k0, lA);
        async_copy16(gA + (size_t)64 * 2048 + k0, lA + 64 * GBK);
        async_copy16(gB + k0, lB);
        async_copy16(gB + (size_t)64 * 2048 + k0, lB + 64 * GBK);
        __syncthreads();

        bf16x8 a[4], b[4];
#pragma unroll
        for (int mt = 0; mt < 4; ++mt)
            a[mt] = *(const bf16x8*)&As[(wm + mt * 16 + l16) * GBK + quad * 8];
#pragma unroll
        for (int nt = 0; nt < 4; ++nt)
            b[nt] = *(const bf16x8*)&Bs[(wn + nt * 16 + l16) * GBK + quad * 8];
#pragma unroll
        for (int mt = 0; mt < 4; ++mt)
#pragma unroll
            for (int nt = 0; nt < 4; ++nt)
                acc[mt][nt] = __builtin_amdgcn_mfma_f32_16x16x32_bf16(a[mt], b[nt], acc[mt][nt], 0, 0, 0);
    }

    const int colbase = bn + wn;            // block-uniform region
    const int region = colbase >> 11;       // 0=q, 1=k, 2=v
    const bool odd = (l16 & 1);

    if (region == 2) {
#pragma unroll
        for (int mt = 0; mt < 4; ++mt)
#pragma unroll
            for (int r = 0; r < 4; ++r) {
                int t = bm + wm + mt * 16 + quad * 4 + r;
                bf16_t* brow = qkv_bf + (size_t)t * ROW_BF + VB_OFF + (colbase - 4096);
#pragma unroll
                for (int nt = 0; nt < 4; ++nt)
                    brow[nt * 16 + l16] = (bf16_t)acc[mt][nt][r];
            }
    } else {
#pragma unroll
        for (int mt = 0; mt < 4; ++mt)
#pragma unroll
            for (int r = 0; r < 4; ++r) {
                int t = bm + wm + mt * 16 + quad * 4 + r;
                const float* trow = tab + t * 128;
#pragma unroll
                for (int nt = 0; nt < 4; ++nt) {
                    float v = acc[mt][nt][r];
                    float vp = __shfl_xor(v, 1);    // pair column value
                    int col = colbase + nt * 16 + l16;
                    int j = col & 63;
                    float c = trow[j], s = trow[64 + j];
                    float y = odd ? (v * c + vp * s) : (v * c - vp * s);
                    if (region == 0)
                        qkv[(size_t)t * QKV_LD + col] = y;
                    else
                        qkv_bf[(size_t)t * ROW_BF + KB_OFF + (col - 2048)] = (bf16_t)y;
                }
            }
    }
}

// ---------------------------------------------------------------------------
// Split-bf16 (3x bf16-MFMA) GEMM for the gate-critical info MLP.
// ---------------------------------------------------------------------------
__global__ __launch_bounds__(256)
void info_gemm_mfma(const bf16_t* __restrict__ Ahi, const bf16_t* __restrict__ Alo,
                    const bf16_t* __restrict__ Bhi, const bf16_t* __restrict__ Blo,
                    float* __restrict__ Cpart) {
    __shared__ bf16_t Ah[128 * GBK];
    __shared__ bf16_t Al[128 * GBK];
    __shared__ bf16_t Bh[128 * GBK];
    __shared__ bf16_t Bl[128 * GBK];
    const int tid = threadIdx.x;
    const int wave = tid >> 6, lane = tid & 63;
    const int quad = lane >> 4, l16 = lane & 15;
    const int bm = blockIdx.y * 128, bn = blockIdx.x * 128;
    const int ks = blockIdx.z;
    const int wm = (wave >> 1) * 64, wn = (wave & 1) * 64;
    const int lrow = lane >> 2;
    const int lkb = (lane & 3) * 8;
    const int kbeg = ks * 512;

    f32x4 acc[4][4];
#pragma unroll
    for (int i = 0; i < 4; ++i)
#pragma unroll
        for (int j = 0; j < 4; ++j) acc[i][j] = (f32x4){0.f, 0.f, 0.f, 0.f};

    const size_t aoff = (size_t)(bm + wave * 16 + lrow) * 2048 + lkb + kbeg;
    const size_t boff = (size_t)(bn + wave * 16 + lrow) * 2048 + lkb + kbeg;
    bf16_t* lAh = &Ah[(wave * 16 + lrow) * GBK + lkb];
    bf16_t* lAl = &Al[(wave * 16 + lrow) * GBK + lkb];
    bf16_t* lBh = &Bh[(wave * 16 + lrow) * GBK + lkb];
    bf16_t* lBl = &Bl[(wave * 16 + lrow) * GBK + lkb];

    for (int k0 = 0; k0 < 512; k0 += GBK) {
        __syncthreads();
        async_copy16(Ahi + aoff + k0, lAh);
        async_copy16(Ahi + aoff + (size_t)64 * 2048 + k0, lAh + 64 * GBK);
        async_copy16(Alo + aoff + k0, lAl);
        async_copy16(Alo + aoff + (size_t)64 * 2048 + k0, lAl + 64 * GBK);
        async_copy16(Bhi + boff + k0, lBh);
        async_copy16(Bhi + boff + (size_t)64 * 2048 + k0, lBh + 64 * GBK);
        async_copy16(Blo + boff + k0, lBl);
        async_copy16(Blo + boff + (size_t)64 * 2048 + k0, lBl + 64 * GBK);
        __syncthreads();

        bf16x8 ah[4], al[4], bh[4], bl[4];
#pragma unroll
        for (int mt = 0; mt < 4; ++mt) {
            ah[mt] = *(const bf16x8*)&Ah[(wm + mt * 16 + l16) * GBK + quad * 8];
            al[mt] = *(const bf16x8*)&Al[(wm + mt * 16 + l16) * GBK + quad * 8];
        }
#pragma unroll
        for (int nt = 0; nt < 4; ++nt) {
            bh[nt] = *(const bf16x8*)&Bh[(wn + nt * 16 + l16) * GBK + quad * 8];
            bl[nt] = *(const bf16x8*)&Bl[(wn + nt * 16 + l16) * GBK + quad * 8];
        }
#pragma unroll
        for (int mt = 0; mt < 4; ++mt)
#pragma unroll
            for (int nt = 0; nt < 4; ++nt) {
                acc[mt][nt] = __builtin_amdgcn_mfma_f32_16x16x32_bf16(ah[mt], bh[nt], acc[mt][nt], 0, 0, 0);
                acc[mt][nt] = __builtin_amdgcn_mfma_f32_16x16x32_bf16(ah[mt], bl[nt], acc[mt][nt], 0, 0, 0);
                acc[mt][nt] = __builtin_amdgcn_mfma_f32_16x16x32_bf16(al[mt], bh[nt], acc[mt][nt], 0, 0, 0);
            }
    }

    float* cp = Cpart + (size_t)ks * 2048 * 512;
#pragma unroll
    for (int mt = 0; mt < 4; ++mt)
#pragma unroll
        for (int r = 0; r < 4; ++r) {
            int row = bm + wm + mt * 16 + quad * 4 + r;
            float* crow = cp + (size_t)row * 512 + bn + wn;
#pragma unroll
            for (int nt = 0; nt < 4; ++nt)
                crow[nt * 16 + l16] = acc[mt][nt][r];
        }
}

__device__ __forceinline__ float gelu_exact(float v) {
    return 0.5f * v * (1.0f + erff(v * 0.70710678118654752f));
}

// ---------------------------------------------------------------------------
// Fused: reduce 4 split-K partials + gelu + dot(w2) + sigmoid -> gate[t].
// ---------------------------------------------------------------------------
__global__ __launch_bounds__(64)
void info_gate_kernel(const float* __restrict__ Cpart, const float* __restrict__ w2,
                      float* __restrict__ gate) {
    const int t = blockIdx.x;
    const int lane = threadIdx.x;
    const float* p0 = Cpart + (size_t)t * 512;
    float s = 0.f;
#pragma unroll
    for (int i = lane; i < 512; i += 64) {
        float v = ((p0[i] + p0[i + 1048576]) + p0[i + 2097152]) + p0[i + 3145728];
        s += gelu_exact(v) * w2[i];
    }
#pragma unroll
    for (int off = 32; off > 0; off >>= 1) s += __shfl_down(s, off);
    if (lane == 0) {
        float sig = 1.f / (1.f + expf(-s));
        gate[t] = (sig > 0.75f) ? 1.f : 0.f;
    }
}

// ---------------------------------------------------------------------------
// MFMA kvr: K/V from bf16 overlays, Q from fp32 (roped by gemm epilogue).
// ---------------------------------------------------------------------------
#define KV_LD 136

__global__ __launch_bounds__(256)
void kvr_mfma_kernel(const float* __restrict__ qkv, const bf16_t* __restrict__ qkv_bf,
                     const float* __restrict__ pk, const float* __restrict__ pv,
                     float* __restrict__ kr, float* __restrict__ vr,
                     bf16_t* __restrict__ qr) {
    __shared__ bf16_t Kt[64 * KV_LD];
    __shared__ bf16_t Vt[64 * KV_LD];
    __shared__ bf16_t Qt[64 * KV_LD];
    __shared__ bf16_t Pk[64 * KV_LD];
    __shared__ bf16_t Pv[64 * KV_LD];

    const int h = blockIdx.y;
    const int s0 = blockIdx.x * 64;
    const int tid = threadIdx.x;
    const int wave = tid >> 6, lane = tid & 63;
    const int quad = lane >> 4, l16 = lane & 15;

#pragma unroll
    for (int i = 0; i < 4; ++i) {
        int gid = i * 256 + tid;
        int row = gid >> 4, ch = (gid & 15) << 3;
        const bf16_t* rb = qkv_bf + (size_t)(s0 + row) * ROW_BF + h * HD + ch;
        *(bf16x8*)&Kt[row * KV_LD + ch] = *(const bf16x8*)(rb + KB_OFF);
        *(bf16x8*)&Vt[row * KV_LD + ch] = *(const bf16x8*)(rb + VB_OFF);
    }
#pragma unroll
    for (int i = 0; i < 8; ++i) {
        int gid = i * 256 + tid;
        int row = gid >> 5, c = (gid & 31) << 2;
        float4 vq = *(const float4*)(qkv + (size_t)(s0 + row) * QKV_LD + h * HD + c);
        bf16x4 pq;
        pq[0] = (bf16_t)vq.x; pq[1] = (bf16_t)vq.y; pq[2] = (bf16_t)vq.z; pq[3] = (bf16_t)vq.w;
        *(bf16x4*)&Qt[row * KV_LD + c] = pq;
        float4 wk = *(const float4*)(pk + (size_t)row * HD + c);
        float4 wv = *(const float4*)(pv + (size_t)row * HD + c);
        bf16x4 qk4, qv4;
        qk4[0] = (bf16_t)wk.x; qk4[1] = (bf16_t)wk.y; qk4[2] = (bf16_t)wk.z; qk4[3] = (bf16_t)wk.w;
        qv4[0] = (bf16_t)wv.x; qv4[1] = (bf16_t)wv.y; qv4[2] = (bf16_t)wv.z; qv4[3] = (bf16_t)wv.w;
        *(bf16x4*)&Pk[row * KV_LD + c] = qk4;
        *(bf16x4*)&Pv[row * KV_LD + c] = qv4;
    }
    __syncthreads();

    f32x4 ak[4], av[4], aq[4];
#pragma unroll
    for (int nt = 0; nt < 4; ++nt) {
        ak[nt] = (f32x4){0.f, 0.f, 0.f, 0.f};
        av[nt] = (f32x4){0.f, 0.f, 0.f, 0.f};
        aq[nt] = (f32x4){0.f, 0.f, 0.f, 0.f};
    }

#pragma unroll
    for (int ks = 0; ks < 4; ++ks) {
        const int ao = (wave * 16 + l16) * KV_LD + ks * 32 + quad * 8;
        bf16x8 a_k = *(const bf16x8*)&Kt[ao];
        bf16x8 a_v = *(const bf16x8*)&Vt[ao];
        bf16x8 a_q = *(const bf16x8*)&Qt[ao];
#pragma unroll
        for (int nt = 0; nt < 4; ++nt) {
            const int bo = (nt * 16 + l16) * KV_LD + ks * 32 + quad * 8;
            bf16x8 bk = *(const bf16x8*)&Pk[bo];
            bf16x8 bv = *(const bf16x8*)&Pv[bo];
            ak[nt] = __builtin_amdgcn_mfma_f32_16x16x32_bf16(a_k, bk, ak[nt], 0, 0, 0);
            av[nt] = __builtin_amdgcn_mfma_f32_16x16x32_bf16(a_v, bv, av[nt], 0, 0, 0);
            aq[nt] = __builtin_amdgcn_mfma_f32_16x16x32_bf16(a_q, bk, aq[nt], 0, 0, 0);
        }
    }

#pragma unroll
    for (int nt = 0; nt < 4; ++nt)
#pragma unroll
        for (int r = 0; r < 4; ++r) {
            int s = s0 + wave * 16 + quad * 4 + r;
            size_t idx = ((size_t)h * T_LEN + s) * RANK + nt * 16 + l16;
            kr[idx] = ak[nt][r];
            vr[idx] = av[nt][r];
            qr[idx] = (bf16_t)aq[nt][r];
        }
}

// ---------------------------------------------------------------------------
// MFMA bf16 flash local attention (v2 + mask elision on interior tiles).
// Masking provably needed only for kt==0 (window lower edge) and kt==8
// (causal diagonal): interior tiles satisfy s<=t and s>t-512 for all t0.
// ---------------------------------------------------------------------------
#define QTI 64
#define KTI 64
#define QS_LD 136
#define VT_LD 68
#define PS_LD 72

__global__ __launch_bounds__(256)
void local_attn_kernel(const float* __restrict__ qkv, const bf16_t* __restrict__ qkv_bf,
                       bf16_t* __restrict__ cxb) {
    __shared__ bf16_t Qs[QTI * QS_LD];
    __shared__ bf16_t Ks[KTI * HD];
    __shared__ bf16_t Vt[HD * VT_LD];
    __shared__ bf16_t Ps[4][16 * PS_LD];

    const int h = blockIdx.y;
    const int t0 = blockIdx.x * QTI;
    const int tid = threadIdx.x;
    const int wave = tid >> 6, lane = tid & 63;
    const int quad = lane >> 4, l16 = lane & 15;

#pragma unroll
    for (int i = 0; i < 8; ++i) {
        int gid = i * 256 + tid;
        int row = gid >> 5, c4 = (gid & 31) << 2;
        const float4 v = *(const float4*)(qkv + (size_t)(t0 + row) * QKV_LD + h * HD + c4);
        bf16x4 p;
        p[0] = (bf16_t)(v.x * SCALE); p[1] = (bf16_t)(v.y * SCALE);
        p[2] = (bf16_t)(v.z * SCALE); p[3] = (bf16_t)(v.w * SCALE);
        *(bf16x4*)&Qs[row * QS_LD + c4] = p;
    }

    f32x4 o[8];
#pragma unroll
    for (int d8 = 0; d8 < 8; ++d8) o[d8] = (f32x4){0.f, 0.f, 0.f, 0.f};
    float m_i[4] = {-1e30f, -1e30f, -1e30f, -1e30f};
    float l_i[4] = {0.f, 0.f, 0.f, 0.f};

    __syncthreads();

    for (int kt = 0; kt < 9; ++kt) {
        const int sbase = t0 - 512 + kt * KTI;
        if (sbase < 0) continue;
        __syncthreads();
#pragma unroll
        for (int i = 0; i < 4; ++i) {
            int s = i * 256 + tid;
            int row = s >> 4, ch = s & 15;
            int gch = ch ^ (row & 7);
            const bf16_t* src = qkv_bf + (size_t)(sbase + row) * ROW_BF + KB_OFF + h * HD + gch * 8;
            async_copy16(src, &Ks[s * 8]);
        }
#pragma unroll
        for (int i = 0; i < 8; ++i) {
            int gid = i * 256 + tid;
            int row = gid >> 5, c4 = (gid & 31) << 2;
            bf16x4 vv = *(const bf16x4*)(qkv_bf + (size_t)(sbase + row) * ROW_BF + VB_OFF + h * HD + c4);
            Vt[(c4 + 0) * VT_LD + row] = vv[0];
            Vt[(c4 + 1) * VT_LD + row] = vv[1];
            Vt[(c4 + 2) * VT_LD + row] = vv[2];
            Vt[(c4 + 3) * VT_LD + row] = vv[3];
        }
        __syncthreads();

        f32x4 sacc[4];
#pragma unroll
        for (int nt = 0; nt < 4; ++nt) sacc[nt] = (f32x4){0.f, 0.f, 0.f, 0.f};
#pragma unroll
        for (int ks = 0; ks < 4; ++ks) {
            bf16x8 a = *(const bf16x8*)&Qs[(wave * 16 + l16) * QS_LD + ks * 32 + quad * 8];
#pragma unroll
            for (int nt = 0; nt < 4; ++nt) {
                int r = nt * 16 + l16;
                int ch = (ks * 4 + quad) ^ (r & 7);
                bf16x8 b = *(const bf16x8*)&Ks[r * HD + ch * 8];
                sacc[nt] = __builtin_amdgcn_mfma_f32_16x16x32_bf16(a, b, sacc[nt], 0, 0, 0);
            }
        }

        if (kt == 0 || kt == 8) {   // uniform branch; interior tiles need no mask
#pragma unroll
            for (int nt = 0; nt < 4; ++nt) {
                int s_g = sbase + nt * 16 + l16;
#pragma unroll
                for (int r = 0; r < 4; ++r) {
                    int t_g = t0 + wave * 16 + quad * 4 + r;
                    bool valid = (s_g <= t_g) && (s_g + W_LOCAL > t_g);
                    if (!valid) sacc[nt][r] = -1e30f;
                }
            }
        }

#pragma unroll
        for (int r = 0; r < 4; ++r) {
            float mx = fmaxf(fmaxf(sacc[0][r], sacc[1][r]), fmaxf(sacc[2][r], sacc[3][r]));
            mx = fmaxf(mx, __shfl_xor(mx, 1));
            mx = fmaxf(mx, __shfl_xor(mx, 2));
            mx = fmaxf(mx, __shfl_xor(mx, 4));
            mx = fmaxf(mx, __shfl_xor(mx, 8));
            float mnew = fmaxf(m_i[r], mx);
            float alpha = __expf(m_i[r] - mnew);
            m_i[r] = mnew;
            float rs = 0.f;
#pragma unroll
            for (int nt = 0; nt < 4; ++nt) {
                float p = __expf(sacc[nt][r] - mnew);
                sacc[nt][r] = p;
                rs += p;
            }
            rs += __shfl_xor(rs, 1);
            rs += __shfl_xor(rs, 2);
            rs += __shfl_xor(rs, 4);
            rs += __shfl_xor(rs, 8);
            l_i[r] = l_i[r] * alpha + rs;
#pragma unroll
            for (int d8 = 0; d8 < 8; ++d8) o[d8][r] *= alpha;
        }

#pragma unroll
        for (int r = 0; r < 4; ++r)
#pragma unroll
            for (int nt = 0; nt < 4; ++nt)
                Ps[wave][(quad * 4 + r) * PS_LD + nt * 16 + l16] = (bf16_t)sacc[nt][r];

#pragma unroll
        for (int ks2 = 0; ks2 < 2; ++ks2) {
            bf16x8 a = *(const bf16x8*)&Ps[wave][l16 * PS_LD + ks2 * 32 + quad * 8];
#pragma unroll
            for (int d8 = 0; d8 < 8; ++d8) {
                const bf16_t* vb = &Vt[(d8 * 16 + l16) * VT_LD + ks2 * 32 + quad * 8];
                bf16x4 b0 = *(const bf16x4*)vb;
                bf16x4 b1 = *(const bf16x4*)(vb + 4);
                bf16x8 b;
                b[0] = b0[0]; b[1] = b0[1]; b[2] = b0[2]; b[3] = b0[3];
                b[4] = b1[0]; b[5] = b1[1]; b[6] = b1[2]; b[7] = b1[3];
                o[d8] = __builtin_amdgcn_mfma_f32_16x16x32_bf16(a, b, o[d8], 0, 0, 0);
            }
        }
    }

#pragma unroll
    for (int r = 0; r < 4; ++r) {
        float inv = 1.0f / l_i[r];
        size_t rowoff = (size_t)(t0 + wave * 16 + quad * 4 + r) * 2048 + h * HD;
#pragma unroll
        for (int d8 = 0; d8 < 8; ++d8)
            cxb[rowoff + d8 * 16 + l16] = (bf16_t)(o[d8][r] * inv);
    }
}

// ---------------------------------------------------------------------------
// Gated global low-rank branch (early-exit when gate==0); bf16 RMW into cxb
// ---------------------------------------------------------------------------
__device__ __forceinline__ float block_reduce_max512(float v, float* red, int tid) {
    red[tid] = v; __syncthreads();
    for (int s = 256; s > 0; s >>= 1) {
        if (tid < s) red[tid] = fmaxf(red[tid], red[tid + s]);
        __syncthreads();
    }
    float r = red[0]; __syncthreads();
    return r;
}
__device__ __forceinline__ float block_reduce_sum512(float v, float* red, int tid) {
    red[tid] = v; __syncthreads();
    for (int s = 256; s > 0; s >>= 1) {
        if (tid < s) red[tid] = red[tid] + red[tid + s];
        __syncthreads();
    }
    float r = red[0]; __syncthreads();
    return r;
}

__global__ __launch_bounds__(512)
void global_attn_kernel(bf16_t* __restrict__ cxb, const float* __restrict__ kr,
                        const float* __restrict__ vr, const bf16_t* __restrict__ qr,
                        const float* __restrict__ uo, const float* __restrict__ gate) {
    const int t = blockIdx.x, h = blockIdx.y;
    if (gate[t] <= 0.5f) return;

    __shared__ float qrs[64];
    __shared__ float red[512];
    __shared__ float cgr[64];
    __shared__ float sg[2048];
    const int tid = threadIdx.x;

    if (tid < 64) qrs[tid] = (float)qr[((size_t)h * T_LEN + t) * RANK + tid];
    __syncthreads();

    const float* krh = kr + (size_t)h * T_LEN * RANK;
    const float* vrh = vr + (size_t)h * T_LEN * RANK;
    float lmax = -INFINITY;
    for (int s = tid; s < T_LEN; s += 512) {
        const float* krr = krh + (size_t)s * RANK;
        float acc = 0.f;
#pragma unroll
        for (int r = 0; r < RANK; r += 4) {
            float4 k4 = *(const float4*)(krr + r);
            acc += qrs[r] * k4.x + qrs[r + 1] * k4.y + qrs[r + 2] * k4.z + qrs[r + 3] * k4.w;
        }
        float sc = acc * SCALE_G;
        sg[s] = sc;
        lmax = fmaxf(lmax, sc);
    }
    float gmx = block_reduce_max512(lmax, red, tid);
    float lsum = 0.f;
    for (int s = tid; s < T_LEN; s += 512) {
        float pp = expf(sg[s] - gmx);
        sg[s] = pp;
        lsum += pp;
    }
    float gsum = block_reduce_sum512(lsum, red, tid);

    {
        const int r = tid & 63, part = tid >> 6;
        float pacc = 0.f;
        for (int s = part; s < T_LEN; s += 8) pacc += sg[s] * vrh[(size_t)s * RANK + r];
        red[tid] = pacc;
        __syncthreads();
        if (tid < 64) {
            float c = 0.f;
#pragma unroll
            for (int pp = 0; pp < 8; ++pp) c += red[pp * 64 + tid];
            cgr[tid] = c / gsum;
        }
        __syncthreads();
    }

    if (tid < 128) {
        float cg = 0.f;
#pragma unroll
        for (int r = 0; r < RANK; ++r) cg += cgr[r] * uo[tid * RANK + r];
        size_t off = (size_t)t * 2048 + h * HD + tid;
        cxb[off] = (bf16_t)((float)cxb[off] + cg);
    }
}

// ---------------------------------------------------------------------------
extern "C" void kernel_launch(void* const* d_in, const int* in_sizes, int n_in,
                              void* d_out, int out_size, void* d_ws, size_t ws_size,
                              hipStream_t stream) {
    const float* x     = (const float*)d_in[0];
    const float* w_qkv = (const float*)d_in[1];
    const float* w_o   = (const float*)d_in[2];
    const float* pk    = (const float*)d_in[3];
    const float* pv    = (const float*)d_in[4];
    const float* uo    = (const float*)d_in[5];
    const float* w1    = (const float*)d_in[6];
    const float* w2    = (const float*)d_in[7];
    float* out = (float*)d_out;

    // Workspace layout (floats), lifetime-aliased (~84 MB):
    float* ws = (float*)d_ws;
    float* qkv   = ws;                        // 12,582,912 f: pre-GEMM info scratch;
                                              //  post-GEMM rows: q fp32 | K bf16 | wo bf16 | V bf16
    float* hinfo = qkv + (size_t)12582912;    // 1,048,576 f: rope tab, later qr bf16
    float* gatep = hinfo + (size_t)1048576;   // 2048 f
    bf16_t* xb   = (bf16_t*)(gatep + 2048);   // x_hi bf16 (later ctx bf16)
    float* wqbf  = gatep + 2048 + 2097152;    // 6,291,456 f region:
    bf16_t* wqb  = (bf16_t*)wqbf;             //   w_qkv bf16 (entire region)
    float* krp   = wqbf;                      //   later: kr
    float* vrp   = wqbf + (size_t)2097152;    //   later: vr
    float* tabp  = hinfo;                     // rope tables (dead before qr)
    bf16_t* qrp  = (bf16_t*)hinfo;            // qr bf16 (written by kvr)
    bf16_t* cxb  = xb;                        // ctx bf16
    bf16_t* qkvb = (bf16_t*)qkv;              // bf16 overlay view of qkv rows
    bf16_t* wob  = qkvb + WO_OFF;             // w_o bf16, row stride ROW_BF
    // Info-MLP scratch inside the pre-GEMM qkv region:
    float* ipart  = qkv;                          // 4x2048x512 f
    bf16_t* xlo   = (bf16_t*)(qkv + 4194304);
    bf16_t* w1hi  = (bf16_t*)(qkv + 6291456);
    bf16_t* w1lo  = (bf16_t*)(qkv + 6815744);

    // 1) merged prep: x/w1 split-bf16, w_qkv->bf16, rope tables
    prep_kernel<<<9216, 256, 0, stream>>>(x, xb, xlo, w1, w1hi, w1lo, w_qkv, wqb, tabp);
    // 2) info MLP (3x bf16 MFMA split-K) -> fused reduce+gelu+gate
    info_gemm_mfma<<<dim3(4, 16, 4), 256, 0, stream>>>(xb, xlo, w1hi, w1lo, ipart);
    info_gate_kernel<<<T_LEN, 64, 0, stream>>>(ipart, w2, gatep);
    // 3) qkv GEMM + fused RoPE epilogue + piggy-backed w_o->bf16 (free chunks)
    gemm_qkv_rope<<<2816, 256, 0, stream>>>(xb, wqb, qkv, qkvb, tabp, w_o);
    // 4) k_r, v_r, q_r via MFMA (kr/vr overwrite dead wqb; qr over dead tab)
    kvr_mfma_kernel<<<dim3(T_LEN / 64, NH), 256, 0, stream>>>(qkv, qkvb, pk, pv, krp, vrp, qrp);
    // 5) flash local attention -> ctx bf16 (cxb)
    local_attn_kernel<<<dim3(T_LEN / QTI, NH), 256, 0, stream>>>(qkv, qkvb, cxb);
    // 6) gated global branch (bf16 RMW into cxb)
    global_attn_kernel<<<dim3(T_LEN, NH), 512, 0, stream>>>(cxb, krp, vrp, qrp, uo, gatep);
    // 7) out = ctx @ w_o^T  (B = wob strided inside qkv rows)
    gemm_bf16_nt<<<dim3(16, 16), 256, 0, stream>>>(cxb, wob, out, 2048, 2048, ROW_BF, 2048);
}